// Round 11
// baseline (197.243 us; speedup 1.0000x reference)
//
#include <hip/hip_runtime.h>
#include <hip/hip_bf16.h>
#include <cstdint>
#include <cstddef>

typedef unsigned int u32;
typedef __attribute__((ext_vector_type(8))) short s16x8;   // 8 bf16 (4 VGPR) MFMA A/B frag
typedef __attribute__((ext_vector_type(4))) short s16x4;   // 4 bf16, 8B pack
typedef __attribute__((ext_vector_type(4))) float f32x4;   // MFMA C/D frag
typedef __attribute__((ext_vector_type(2))) u32   u32x2;

#define MFMA(a,b,c) __builtin_amdgcn_mfma_f32_16x16x32_bf16(a,b,c,0,0,0)

#if __has_builtin(__builtin_amdgcn_mfma_f32_16x16x16bf16_1k)
#define MFMA16(a,b,c) __builtin_amdgcn_mfma_f32_16x16x16bf16_1k(a,b,c,0,0,0)
#else
static __device__ __forceinline__ f32x4 MFMA16(s16x4 a, s16x4 b, f32x4 c){
    f32x4 d;
    asm("v_mfma_f32_16x16x16_bf16 %0, %1, %2, %3"
        : "=v"(d) : "v"(a), "v"(b), "v"(c));
    return d;
}
#endif

__device__ __forceinline__ short f2bf(float f) {
    u32 u = __builtin_bit_cast(u32, f);
    u32 r = (u + 0x7fffu + ((u >> 16) & 1u)) >> 16;   // RNE
    return (short)r;
}
__device__ __forceinline__ float bf2f(short s) {
    return __builtin_bit_cast(float, ((u32)(unsigned short)s) << 16);
}
__device__ __forceinline__ u32 cvtpk(float lo, float hi) {
    u32 r;
    asm("v_cvt_pk_bf16_f32 %0, %1, %2" : "=v"(r) : "v"(lo), "v"(hi));
    return r;
}
__device__ __forceinline__ void async_copy16(void* lds, const void* g) {
    __builtin_amdgcn_global_load_lds((const __attribute__((address_space(1))) u32*)g,
                                     (__attribute__((address_space(3))) u32*)lds, 16, 0, 0);
}

// ---------------------------------------------------------------------------
// Prep: cast x (fp32 -> bf16), 8 elems/thread
// ---------------------------------------------------------------------------
__global__ __launch_bounds__(256) void cast_x(const float* __restrict__ x, short* __restrict__ xb) {
    int i = (blockIdx.x * 256 + threadIdx.x) * 8;
    float4 a = *(const float4*)&x[i];
    float4 b = *(const float4*)&x[i + 4];
    s16x8 v = { f2bf(a.x), f2bf(a.y), f2bf(a.z), f2bf(a.w),
                f2bf(b.x), f2bf(b.y), f2bf(b.z), f2bf(b.w) };
    *(s16x8*)&xb[i] = v;
}

// ---------------------------------------------------------------------------
// Prep: transpose + cast weights. seg 0..2 -> Wtqkv rows [seg*1024, +1024); seg 3 -> Wto.
// ---------------------------------------------------------------------------
__global__ __launch_bounds__(256)
void transpose_w(const float* __restrict__ wq, const float* __restrict__ wk,
                 const float* __restrict__ wv, const float* __restrict__ wo,
                 short* __restrict__ Wtqkv, short* __restrict__ Wto)
{
    __shared__ float sT[64][68];
    const int kt = blockIdx.x, nt = blockIdx.y, seg = blockIdx.z;
    const float* src = seg == 0 ? wq : seg == 1 ? wk : seg == 2 ? wv : wo;
    const int k0 = kt * 64, n0 = nt * 64;
    const int tid = threadIdx.x;
#pragma unroll
    for (int i = 0; i < 4; ++i) {
        int t2 = tid + i * 256;          // 0..1023 -> 64 rows x 16 float4
        int r = t2 >> 4, c4 = t2 & 15;
        *(float4*)&sT[r][c4 * 4] = *(const float4*)&src[(size_t)(k0 + r) * 1024 + n0 + c4 * 4];
    }
    __syncthreads();
#pragma unroll
    for (int i = 0; i < 2; ++i) {
        int t2 = tid + i * 256;
        int rn = t2 >> 3, ch = t2 & 7;
        s16x8 v;
#pragma unroll
        for (int j = 0; j < 8; ++j) v[j] = f2bf(sT[ch * 8 + j][rn]);
        if (seg < 3)
            *(s16x8*)&Wtqkv[(size_t)(seg * 1024 + n0 + rn) * 1024 + k0 + ch * 8] = v;
        else
            *(s16x8*)&Wto[(size_t)(n0 + rn) * 1024 + k0 + ch * 8] = v;
    }
}

// ---------------------------------------------------------------------------
// Prep: relkb [144][64] bf16 zero-padded rows>=129; relvT [64][128] bf16 (r<128).
// ---------------------------------------------------------------------------
__global__ __launch_bounds__(256)
void prep_tables(const float* __restrict__ relk, const float* __restrict__ relv,
                 short* __restrict__ relkb, short* __restrict__ relvT)
{
    int tid = threadIdx.x;
    for (int i = tid; i < 144 * 64; i += 256) {
        int r = i >> 6, d = i & 63;
        relkb[i] = (r < 129) ? f2bf(relk[r * 64 + d]) : (short)0;
    }
    for (int i = tid; i < 64 * 128; i += 256) {
        int d = i >> 7, r = i & 127;
        relvT[i] = f2bf(relv[r * 64 + d]);
    }
}

// ---------------------------------------------------------------------------
// Fused QKV GEMM; V segment stores TRANSPOSED + k-interleaved:
// col(k) = (k>>5)*32 + (k&3) + (((k>>4)&1)<<2) + (((k>>2)&3)<<3)
// ---------------------------------------------------------------------------
__global__ __launch_bounds__(256)
void gemm_qkv(const short* __restrict__ Ab, const short* __restrict__ Wt,
              const float* __restrict__ bq, const float* __restrict__ bk,
              const float* __restrict__ bv,
              short* __restrict__ Qb, short* __restrict__ Kb, short* __restrict__ Vtb)
{
    __shared__ __align__(16) short As[128 * 64];
    __shared__ __align__(16) short Bs[128 * 64];
    const int tid = threadIdx.x;
    const int w = tid >> 6, lane = tid & 63;
    const int lo16 = lane & 15, hi = lane >> 4;
    const int n0g = blockIdx.x * 128;
    const int m0 = blockIdx.y * 128;
    const int wr = w >> 1, wc = w & 1;

    f32x4 acc[4][4] = {};

    for (int t = 0; t < 16; ++t) {
        const int k0 = t * 64;
        __syncthreads();
#pragma unroll
        for (int i = 0; i < 4; ++i) {
            int o = i * 4096 + tid * 16;
            int row = o >> 7;
            int cb = o & 127;
            int sc = cb ^ ((row & 7) << 4);
            async_copy16((char*)As + o, Ab + (size_t)(m0 + row) * 1024 + k0 + (sc >> 1));
            async_copy16((char*)Bs + o, Wt + (size_t)(n0g + row) * 1024 + k0 + (sc >> 1));
        }
        __syncthreads();
#pragma unroll
        for (int ks = 0; ks < 2; ++ks) {
            s16x8 aF[4], bF[4];
#pragma unroll
            for (int mi = 0; mi < 4; ++mi) {
                int row = wr * 64 + mi * 16 + lo16;
                int cb = ks * 64 + hi * 16;
                aF[mi] = *(const s16x8*)((const char*)As + row * 128 + (cb ^ ((row & 7) << 4)));
            }
#pragma unroll
            for (int ni = 0; ni < 4; ++ni) {
                int row = wc * 64 + ni * 16 + lo16;
                int cb = ks * 64 + hi * 16;
                bF[ni] = *(const s16x8*)((const char*)Bs + row * 128 + (cb ^ ((row & 7) << 4)));
            }
#pragma unroll
            for (int mi = 0; mi < 4; ++mi)
#pragma unroll
                for (int ni = 0; ni < 4; ++ni)
                    acc[mi][ni] = MFMA(aF[mi], bF[ni], acc[mi][ni]);
        }
    }

    const int seg = n0g >> 10;
    const int nn = n0g & 1023;
    const float* bias = seg == 0 ? bq : seg == 1 ? bk : bv;
    float bv4[4];
#pragma unroll
    for (int ni = 0; ni < 4; ++ni) bv4[ni] = bias[nn + wc * 64 + ni * 16 + lo16];

    if (seg == 2) {
        // V: store transposed + interleaved, 4 consecutive l per thread -> 8B stores
#pragma unroll
        for (int mi = 0; mi < 4; ++mi)
#pragma unroll
            for (int ni = 0; ni < 4; ++ni) {
                int nl = nn + wc * 64 + ni * 16 + lo16;
                int hh = nl >> 6, d = nl & 63;
                int mbase = m0 + wr * 64 + mi * 16 + hi * 4;
                int bb = mbase >> 10, l0 = mbase & 1023;
                int j0 = l0 & 31;                          // j0 % 4 == 0
                int col = (l0 >> 5) * 32 + (((j0 >> 4) & 1) << 2) + (((j0 >> 2) & 3) << 3);
                s16x4 pk = { f2bf(acc[mi][ni][0] + bv4[ni]),
                             f2bf(acc[mi][ni][1] + bv4[ni]),
                             f2bf(acc[mi][ni][2] + bv4[ni]),
                             f2bf(acc[mi][ni][3] + bv4[ni]) };
                *(s16x4*)&Vtb[((size_t)(bb * 16 + hh) * 64 + d) * 1024 + col] = pk;
            }
    } else {
        short* out = seg == 0 ? Qb : Kb;
#pragma unroll
        for (int mi = 0; mi < 4; ++mi)
#pragma unroll
            for (int ni = 0; ni < 4; ++ni) {
                int nl = nn + wc * 64 + ni * 16 + lo16;
                int hh = nl >> 6, d = nl & 63;
#pragma unroll
                for (int r = 0; r < 4; ++r) {
                    int m = m0 + wr * 64 + mi * 16 + hi * 4 + r;
                    int bb = m >> 10, l = m & 1023;
                    out[(((size_t)bb * 16 + hh) * 1024 + l) * 64 + d] = f2bf(acc[mi][ni][r] + bv4[ni]);
                }
            }
    }
}

// ---------------------------------------------------------------------------
// Flash attention v8: round-10 sync structure (proven), but V moved out of
// LDS to global->register prefetch one 64-k tile ahead. LDS 53.3KB -> 3
// blocks/CU (3 waves/SIMD). K keeps LDS staging + swizzle.
// ---------------------------------------------------------------------------
struct KRegs {
    s16x8 k0, k1, k2, k3;    // K frags (QK A-operand)
    s16x4 m0, m1;            // mask bias
};
struct VRegs {
    s16x8 v0, v1, v2, v3;    // V frags for one 32-k chunk (f0|f1 packed per 16B)
};

__device__ __forceinline__ void prefetch_k(
    const short* __restrict__ sKc, const short* __restrict__ sMaskP,
    int kfm, int lo16, int hi, KRegs& R)
{
    const int km = lo16 & 7;
    R.k0 = *(const s16x8*)(sKc + lo16 * 64 + ((hi ^ km) << 3));
    R.k1 = *(const s16x8*)(sKc + lo16 * 64 + (((hi + 4) ^ km) << 3));
    R.k2 = *(const s16x8*)(sKc + (lo16 + 16) * 64 + ((hi ^ km) << 3));
    R.k3 = *(const s16x8*)(sKc + (lo16 + 16) * 64 + (((hi + 4) ^ km) << 3));
    R.m0 = *(const s16x4*)&sMaskP[kfm + hi * 4];
    R.m1 = *(const s16x4*)&sMaskP[kfm + 16 + hi * 4];
}

// V direct from global (k-interleaved layout): 4x dwordx4 per 32-k chunk
__device__ __forceinline__ void load_vg(
    const short* __restrict__ Vtbase, int kf, int lo16, int hi, VRegs& R)
{
    const short* bp = Vtbase + (size_t)lo16 * 1024 + (kf >> 5) * 32 + hi * 8;
    R.v0 = *(const s16x8*)(bp);
    R.v1 = *(const s16x8*)(bp + 16 * 1024);
    R.v2 = *(const s16x8*)(bp + 32 * 1024);
    R.v3 = *(const s16x8*)(bp + 48 * 1024);
}

__device__ __forceinline__ void process32(
    int kf, int q0, int q_abs, int lo16, int hi,
    const KRegs& K, const VRegs& V,
    const s16x8& qB0, const s16x8& qB1,
    float qrel_lo, float qrel_hi,
    const short (*sQrelw)[144], short (*sBandw)[128],
    f32x4* ctx, float& lsum, float& lov, float& hiv)
{
    const f32x4 z = {0.f, 0.f, 0.f, 0.f};
    __builtin_amdgcn_s_setprio(1);
    f32x4 sa = MFMA(K.k0, qB0, z);
    f32x4 sb = MFMA(K.k1, qB1, z);
    f32x4 sc = MFMA(K.k2, qB0, z);
    f32x4 sd = MFMA(K.k3, qB1, z);
    __builtin_amdgcn_s_setprio(0);
    f32x4 s0 = sa + sb, s1 = sc + sd;

    float p[8];
    if (kf + 95 <= q0 || kf >= q0 + 79) {
        // whole block out of band: rel uniform 0 or 128
        const float qc = (kf < q0) ? qrel_lo : qrel_hi;
        float bs = 0.f;
#pragma unroll
        for (int r = 0; r < 4; ++r) {
            p[r]     = __expf(s0[r] + qc + bf2f(K.m0[r]));
            p[4 + r] = __expf(s1[r] + qc + bf2f(K.m1[r]));
        }
#pragma unroll
        for (int r = 0; r < 8; ++r) bs += p[r];
        lsum += bs;
        if (kf < q0) lov += bs; else hiv += bs;
    } else {
#pragma unroll
        for (int f = 0; f < 2; ++f)
#pragma unroll
            for (int r = 0; r < 4; ++r) {
                int k_abs = kf + f * 16 + hi * 4 + r;
                int dd = k_abs - q_abs;
                dd = dd < -64 ? -64 : (dd > 64 ? 64 : dd);
                int rel = dd + 64;
                float sv = f ? s1[r] : s0[r];
                float mv = bf2f(f ? K.m1[r] : K.m0[r]);
                float pex = __expf(sv + bf2f(sQrelw[lo16][rel]) + mv);
                p[f * 4 + r] = pex;
                lsum += pex;
                if (rel >= 1 && rel <= 127) sBandw[lo16][rel] = f2bf(pex);
                else if (rel == 0) lov += pex;
                else hiv += pex;
            }
    }

    // S-frag (col=q=lo16, k=hi*4+r) IS the 16x16x16 B-operand layout: no shuffle.
    u32x2 w0 = { cvtpk(p[0], p[1]), cvtpk(p[2], p[3]) };
    u32x2 w1 = { cvtpk(p[4], p[5]), cvtpk(p[6], p[7]) };
    s16x4 pf0 = __builtin_bit_cast(s16x4, w0);
    s16x4 pf1 = __builtin_bit_cast(s16x4, w1);

    // split interleaved V chunks: low 8B = f0 frag, high 8B = f1 frag
    s16x4 a0 = __builtin_shufflevector(V.v0, V.v0, 0, 1, 2, 3);
    s16x4 b0 = __builtin_shufflevector(V.v0, V.v0, 4, 5, 6, 7);
    s16x4 a1 = __builtin_shufflevector(V.v1, V.v1, 0, 1, 2, 3);
    s16x4 b1 = __builtin_shufflevector(V.v1, V.v1, 4, 5, 6, 7);
    s16x4 a2 = __builtin_shufflevector(V.v2, V.v2, 0, 1, 2, 3);
    s16x4 b2 = __builtin_shufflevector(V.v2, V.v2, 4, 5, 6, 7);
    s16x4 a3 = __builtin_shufflevector(V.v3, V.v3, 0, 1, 2, 3);
    s16x4 b3 = __builtin_shufflevector(V.v3, V.v3, 4, 5, 6, 7);

    __builtin_amdgcn_s_setprio(1);
    ctx[0] = MFMA16(a0, pf0, ctx[0]);
    ctx[1] = MFMA16(a1, pf0, ctx[1]);
    ctx[2] = MFMA16(a2, pf0, ctx[2]);
    ctx[3] = MFMA16(a3, pf0, ctx[3]);
    ctx[0] = MFMA16(b0, pf1, ctx[0]);
    ctx[1] = MFMA16(b1, pf1, ctx[1]);
    ctx[2] = MFMA16(b2, pf1, ctx[2]);
    ctx[3] = MFMA16(b3, pf1, ctx[3]);
    __builtin_amdgcn_s_setprio(0);
}

__global__ __launch_bounds__(256, 3)
void attn_mfma(const short* __restrict__ Qb, const short* __restrict__ Kb,
               const short* __restrict__ Vtb, const short* __restrict__ relkb,
               const short* __restrict__ relvTb, const float* __restrict__ relv_f32,
               const float* __restrict__ mask, short* __restrict__ CTXb)
{
    __shared__ __align__(16) short sK[2][2][32 * 64];  // [buf][sub], XOR-swizzled chunks (16KB)
    __shared__ __align__(16) short sMaskP[1024 + 32];  // bf16 mask * -1e9 (2.1KB)
    __shared__ __align__(16) short sQrel[4][16][144];  // bf16 Qrel[q][r], r<=143 (18KB)
    __shared__ __align__(16) short sBand[4][16][128];  // bf16 band weights (16KB)

    const int tid = threadIdx.x;
    const int w = tid >> 6, lane = tid & 63;
    const int lo16 = lane & 15, hi = lane >> 4;

    // XCD-aware swizzle (1024 = 8*128, bijective); same-bh blocks share an XCD L2
    const int p = blockIdx.x;
    const int bid = (p & 7) * 128 + (p >> 3);
    const int bh = bid >> 4;
    const int qt = bid & 15;
    const int b = bh >> 4, h = bh & 15;
    const int q0 = qt * 64 + w * 16;
    const int q_abs = q0 + lo16;

    const short* Kbase = Kb + (size_t)bh * 65536;
    const short* Vtbase = Vtb + (size_t)bh * 65536;

    // K staging geometry (per thread, 1x16B per async op)
    const int skr = tid >> 3, skc = tid & 7;             // K: row 0..31, chunk 0..7
    const short* ksrc = Kbase + (size_t)skr * 64 + ((skc ^ (skr & 7)) << 3);

    // stage K tile 0 (both 32-k subs) into buf 0
    async_copy16((char*)&sK[0][0][0] + tid * 16, ksrc);
    async_copy16((char*)&sK[0][1][0] + tid * 16, ksrc + 32 * 64);

    // V tile 0 direct to regs (drained by the prologue __syncthreads)
    VRegs VA0, VA1, VB0, VB1;
    load_vg(Vtbase, 0, lo16, hi, VA0);
    load_vg(Vtbase, 32, lo16, hi, VA1);

    // persistent Q fragments (B-operand: col = q = lane&15, depth = hi*8+j)
    const short* qptr = Qb + ((size_t)bh * 1024 + q_abs) * 64 + hi * 8;
    const s16x8 qB0 = *(const s16x8*)qptr;
    const s16x8 qB1 = *(const s16x8*)(qptr + 32);

    // init shared: maskP (block-wide), sBand zero (per-wave region)
    {
        float4 mv = *(const float4*)&mask[b * 1024 + tid * 4];
        s16x4 mp = { f2bf(mv.x * -1e9f), f2bf(mv.y * -1e9f),
                     f2bf(mv.z * -1e9f), f2bf(mv.w * -1e9f) };
        *(s16x4*)&sMaskP[tid * 4] = mp;
        if (tid < 8) *(s16x4*)&sMaskP[1024 + tid * 4] = s16x4{0, 0, 0, 0};
    }
    {
        u32* bz = (u32*)&sBand[w][0][0];   // 16*128 shorts = 1024 u32 per wave
#pragma unroll
        for (int i = 0; i < 16; ++i) bz[lane + i * 64] = 0u;
    }

    // Qrel^T = relk @ Q^T : 9 r-frags -> sQrel[w][q][r] (bf16)
#pragma unroll
    for (int rf = 0; rf < 9; ++rf) {
        const short* rp = relkb + (size_t)(rf * 16 + lo16) * 64 + hi * 8;
        s16x8 rA0 = *(const s16x8*)rp;
        s16x8 rA1 = *(const s16x8*)(rp + 32);
        f32x4 dq = {0.f, 0.f, 0.f, 0.f};
        dq = MFMA(rA0, qB0, dq);
        dq = MFMA(rA1, qB1, dq);
        s16x4 pk = { f2bf(dq[0]), f2bf(dq[1]), f2bf(dq[2]), f2bf(dq[3]) };
        *(s16x4*)&sQrel[w][lo16][rf * 16 + hi * 4] = pk;
    }
    __syncthreads();   // drains K tile-0 staging + V tile-0 regs; fences sMaskP/sQrel

    const float qrel_lo = bf2f(sQrel[w][lo16][0]);
    const float qrel_hi = bf2f(sQrel[w][lo16][128]);

    f32x4 ctx[4] = {};
    float lsum = 0.f, lov = 0.f, hiv = 0.f;

    KRegs K0, K1;
    prefetch_k(sK[0][0], sMaskP, 0, lo16, hi, K0);

    // Iter t: consume V tile t (regs, loaded iter t-1), K tile t (LDS, staged
    // iter t-1); issue V tile t+1 reg loads + K tile t+1 staging at top; all
    // drained by this iter's __syncthreads (full body of latency cover).
    auto body = [&](int t, VRegs& Vc0, VRegs& Vc1, VRegs& Vn0, VRegs& Vn1) {
        const int cb = t & 1, nb = (t + 1) & 1;
        const int kb = ((t + 1) & 15) * 64;    // wrapped next-tile base (t=15 -> dead)
        load_vg(Vtbase, kb, lo16, hi, Vn0);
        load_vg(Vtbase, kb + 32, lo16, hi, Vn1);
        async_copy16((char*)&sK[nb][0][0] + tid * 16, ksrc + (size_t)kb * 64);
        async_copy16((char*)&sK[nb][1][0] + tid * 16, ksrc + (size_t)(kb + 32) * 64);
        prefetch_k(sK[cb][1], sMaskP, t * 64 + 32, lo16, hi, K1);
        process32(t * 64,      q0, q_abs, lo16, hi, K0, Vc0, qB0, qB1, qrel_lo, qrel_hi,
                  sQrel[w], sBand[w], ctx, lsum, lov, hiv);
        process32(t * 64 + 32, q0, q_abs, lo16, hi, K1, Vc1, qB0, qB1, qrel_lo, qrel_hi,
                  sQrel[w], sBand[w], ctx, lsum, lov, hiv);
        __syncthreads();   // drains this iter's staging + V loads + all waves' LDS reads
        prefetch_k(sK[nb][0], sMaskP, kb, lo16, hi, K0);
    };
    for (int tt = 0; tt < 8; ++tt) {
        body(2 * tt,     VA0, VA1, VB0, VB1);
        body(2 * tt + 1, VB0, VB1, VA0, VA1);
    }

    // band rel_v contribution: ctx^T += relvT-frag x sBand-frag (unnormalized)
#pragma unroll
    for (int ks = 0; ks < 4; ++ks) {
        s16x8 bB = *(const s16x8*)&sBand[w][lo16][ks * 32 + hi * 8];
#pragma unroll
        for (int df = 0; df < 4; ++df) {
            s16x8 rA = *(const s16x8*)(relvTb + (size_t)(df * 16 + lo16) * 128 + ks * 32 + hi * 8);
            ctx[df] = MFMA(rA, bB, ctx[df]);
        }
    }

    // reduce per-q stats across the 4 hi-groups
    lsum += __shfl_xor(lsum, 16); lsum += __shfl_xor(lsum, 32);
    lov  += __shfl_xor(lov, 16);  lov  += __shfl_xor(lov, 32);
    hiv  += __shfl_xor(hiv, 16);  hiv  += __shfl_xor(hiv, 32);
    const float inv = 1.0f / lsum;

    // tails (clipped buckets 0 / 128) + normalize + store bf16 ctx
#pragma unroll
    for (int df = 0; df < 4; ++df) {
        s16x4 pk;
#pragma unroll
        for (int r = 0; r < 4; ++r) {
            int d = df * 16 + hi * 4 + r;
            float t = ctx[df][r] + lov * relv_f32[d] + hiv * relv_f32[128 * 64 + d];
            pk[r] = f2bf(t * inv);
        }
        *(s16x4*)(CTXb + ((size_t)(b * 1024) + q_abs) * 1024 + h * 64 + df * 16 + hi * 4) = pk;
    }
}

// ---------------------------------------------------------------------------
// Output GEMM: out[4096,1024] = CTXb @ wo + bo (fp32 out). 128x64 tile, BK=64.
// ---------------------------------------------------------------------------
__global__ __launch_bounds__(256)
void gemm_out(const short* __restrict__ Ab, const short* __restrict__ Wto,
              const float* __restrict__ bo, float* __restrict__ out)
{
    __shared__ __align__(16) short As[128 * 64];
    __shared__ __align__(16) short Bs[64 * 64];
    const int tid = threadIdx.x;
    const int w = tid >> 6, lane = tid & 63;
    const int lo16 = lane & 15, hi = lane >> 4;
    const int n0 = blockIdx.x * 64;
    const int m0 = blockIdx.y * 128;
    const int wr = w;

    f32x4 acc[2][4] = {};

    for (int t = 0; t < 16; ++t) {
        const int k0 = t * 64;
        __syncthreads();
#pragma unroll
        for (int i = 0; i < 4; ++i) {
            int o = i * 4096 + tid * 16;
            int row = o >> 7;
            int cb = o & 127;
            int sc = cb ^ ((row & 7) << 4);
            async_copy16((char*)As + o, Ab + (size_t)(m0 + row) * 1024 + k0 + (sc >> 1));
        }
#pragma unroll
        for (int i = 0; i < 2; ++i) {
            int o = i * 4096 + tid * 16;
            int row = o >> 7;
            int cb = o & 127;
            int sc = cb ^ ((row & 7) << 4);
            async_copy16((char*)Bs + o, Wto + (size_t)(n0 + row) * 1024 + k0 + (sc >> 1));
        }
        __syncthreads();
#pragma unroll
        for (int ks = 0; ks < 2; ++ks) {
            s16x8 aF[2], bF[4];
#pragma unroll
            for (int mi = 0; mi < 2; ++mi) {
                int row = wr * 32 + mi * 16 + lo16;
                int cb = ks * 64 + hi * 16;
                aF[mi] = *(const s16x8*)((const char*)As + row * 128 + (cb ^ ((row & 7) << 4)));
            }
#pragma unroll
            for (int ni = 0; ni < 4; ++ni) {
                int row = ni * 16 + lo16;
                int cb = ks * 64 + hi * 16;
                bF[ni] = *(const s16x8*)((const char*)Bs + row * 128 + (cb ^ ((row & 7) << 4)));
            }
#pragma unroll
            for (int mi = 0; mi < 2; ++mi)
#pragma unroll
                for (int ni = 0; ni < 4; ++ni)
                    acc[mi][ni] = MFMA(aF[mi], bF[ni], acc[mi][ni]);
        }
    }

    float bv4[4];
#pragma unroll
    for (int ni = 0; ni < 4; ++ni) bv4[ni] = bo[n0 + ni * 16 + lo16];
#pragma unroll
    for (int mi = 0; mi < 2; ++mi)
#pragma unroll
        for (int ni = 0; ni < 4; ++ni)
#pragma unroll
            for (int r = 0; r < 4; ++r) {
                int m = m0 + wr * 32 + mi * 16 + hi * 4 + r;
                out[(size_t)m * 1024 + n0 + ni * 16 + lo16] = acc[mi][ni][r] + bv4[ni];
            }
}

// ---------------------------------------------------------------------------
extern "C" void kernel_launch(void* const* d_in, const int* in_sizes, int n_in,
                              void* d_out, int out_size, void* d_ws, size_t ws_size,
                              hipStream_t stream)
{
    (void)in_sizes; (void)n_in; (void)out_size; (void)ws_size;
    const float* x    = (const float*)d_in[0];
    const float* mask = (const float*)d_in[1];
    const float* wq   = (const float*)d_in[2];
    const float* bq   = (const float*)d_in[3];
    const float* wk   = (const float*)d_in[4];
    const float* bk   = (const float*)d_in[5];
    const float* wv   = (const float*)d_in[6];
    const float* bv   = (const float*)d_in[7];
    const float* wo   = (const float*)d_in[8];
    const float* bo   = (const float*)d_in[9];
    const float* relk = (const float*)d_in[10];
    const float* relv = (const float*)d_in[11];
    float* out = (float*)d_out;

    char* p = (char*)d_ws;
    short* xb    = (short*)p; p += (size_t)4096 * 1024 * 2;     // 8 MB
    short* Wtqkv = (short*)p; p += (size_t)3072 * 1024 * 2;     // 6 MB
    short* Wto   = (short*)p; p += (size_t)1024 * 1024 * 2;     // 2 MB
    short* Qb    = (short*)p; p += (size_t)4096 * 1024 * 2;     // 8 MB
    short* Kb    = (short*)p; p += (size_t)4096 * 1024 * 2;     // 8 MB
    short* Vtb   = (short*)p; p += (size_t)4096 * 1024 * 2;     // 8 MB
    short* CTXb  = (short*)p; p += (size_t)4096 * 1024 * 2;     // 8 MB
    short* relkb = (short*)p; p += (size_t)144 * 64 * 2;
    short* relvT = (short*)p; p += (size_t)64 * 128 * 2;

    cast_x       <<<2048, 256, 0, stream>>>(x, xb);
    transpose_w  <<<dim3(16, 16, 4), 256, 0, stream>>>(wq, wk, wv, wo, Wtqkv, Wto);
    prep_tables  <<<1, 256, 0, stream>>>(relk, relv, relkb, relvT);
    gemm_qkv     <<<dim3(24, 32), 256, 0, stream>>>(xb, Wtqkv, bq, bk, bv, Qb, Kb, Vtb);
    attn_mfma    <<<1024, 256, 0, stream>>>(Qb, Kb, Vtb, relkb, relvT, relv, mask, CTXb);
    gemm_out     <<<dim3(16, 32), 256, 0, stream>>>(CTXb, Wto, bo, out);
}

// Round 12
// 144.424 us; speedup vs baseline: 1.3657x; 1.3657x over previous
//
#include <hip/hip_runtime.h>
#include <hip/hip_bf16.h>
#include <cstdint>
#include <cstddef>

typedef unsigned int u32;
typedef __attribute__((ext_vector_type(8))) short s16x8;   // 8 bf16 (4 VGPR) MFMA A/B frag
typedef __attribute__((ext_vector_type(4))) short s16x4;   // 4 bf16, 8B pack
typedef __attribute__((ext_vector_type(4))) float f32x4;   // MFMA C/D frag
typedef __attribute__((ext_vector_type(2))) u32   u32x2;

#define MFMA(a,b,c) __builtin_amdgcn_mfma_f32_16x16x32_bf16(a,b,c,0,0,0)

#if __has_builtin(__builtin_amdgcn_mfma_f32_16x16x16bf16_1k)
#define MFMA16(a,b,c) __builtin_amdgcn_mfma_f32_16x16x16bf16_1k(a,b,c,0,0,0)
#else
static __device__ __forceinline__ f32x4 MFMA16(s16x4 a, s16x4 b, f32x4 c){
    f32x4 d;
    asm("v_mfma_f32_16x16x16_bf16 %0, %1, %2, %3"
        : "=v"(d) : "v"(a), "v"(b), "v"(c));
    return d;
}
#endif

__device__ __forceinline__ short f2bf(float f) {
    u32 u = __builtin_bit_cast(u32, f);
    u32 r = (u + 0x7fffu + ((u >> 16) & 1u)) >> 16;   // RNE
    return (short)r;
}
__device__ __forceinline__ float bf2f(short s) {
    return __builtin_bit_cast(float, ((u32)(unsigned short)s) << 16);
}
__device__ __forceinline__ u32 cvtpk(float lo, float hi) {
    u32 r;
    asm("v_cvt_pk_bf16_f32 %0, %1, %2" : "=v"(r) : "v"(lo), "v"(hi));
    return r;
}
__device__ __forceinline__ void async_copy16(void* lds, const void* g) {
    __builtin_amdgcn_global_load_lds((const __attribute__((address_space(1))) u32*)g,
                                     (__attribute__((address_space(3))) u32*)lds, 16, 0, 0);
}

// ---------------------------------------------------------------------------
// Prep: cast x (fp32 -> bf16), 8 elems/thread
// ---------------------------------------------------------------------------
__global__ __launch_bounds__(256) void cast_x(const float* __restrict__ x, short* __restrict__ xb) {
    int i = (blockIdx.x * 256 + threadIdx.x) * 8;
    float4 a = *(const float4*)&x[i];
    float4 b = *(const float4*)&x[i + 4];
    s16x8 v = { f2bf(a.x), f2bf(a.y), f2bf(a.z), f2bf(a.w),
                f2bf(b.x), f2bf(b.y), f2bf(b.z), f2bf(b.w) };
    *(s16x8*)&xb[i] = v;
}

// ---------------------------------------------------------------------------
// Prep: transpose + cast weights. seg 0..2 -> Wtqkv rows [seg*1024, +1024); seg 3 -> Wto.
// ---------------------------------------------------------------------------
__global__ __launch_bounds__(256)
void transpose_w(const float* __restrict__ wq, const float* __restrict__ wk,
                 const float* __restrict__ wv, const float* __restrict__ wo,
                 short* __restrict__ Wtqkv, short* __restrict__ Wto)
{
    __shared__ float sT[64][68];
    const int kt = blockIdx.x, nt = blockIdx.y, seg = blockIdx.z;
    const float* src = seg == 0 ? wq : seg == 1 ? wk : seg == 2 ? wv : wo;
    const int k0 = kt * 64, n0 = nt * 64;
    const int tid = threadIdx.x;
#pragma unroll
    for (int i = 0; i < 4; ++i) {
        int t2 = tid + i * 256;          // 0..1023 -> 64 rows x 16 float4
        int r = t2 >> 4, c4 = t2 & 15;
        *(float4*)&sT[r][c4 * 4] = *(const float4*)&src[(size_t)(k0 + r) * 1024 + n0 + c4 * 4];
    }
    __syncthreads();
#pragma unroll
    for (int i = 0; i < 2; ++i) {
        int t2 = tid + i * 256;
        int rn = t2 >> 3, ch = t2 & 7;
        s16x8 v;
#pragma unroll
        for (int j = 0; j < 8; ++j) v[j] = f2bf(sT[ch * 8 + j][rn]);
        if (seg < 3)
            *(s16x8*)&Wtqkv[(size_t)(seg * 1024 + n0 + rn) * 1024 + k0 + ch * 8] = v;
        else
            *(s16x8*)&Wto[(size_t)(n0 + rn) * 1024 + k0 + ch * 8] = v;
    }
}

// ---------------------------------------------------------------------------
// Prep: relkb [144][64] bf16 zero-padded rows>=129; relvT [64][128] bf16 (r<128).
// ---------------------------------------------------------------------------
__global__ __launch_bounds__(256)
void prep_tables(const float* __restrict__ relk, const float* __restrict__ relv,
                 short* __restrict__ relkb, short* __restrict__ relvT)
{
    int tid = threadIdx.x;
    for (int i = tid; i < 144 * 64; i += 256) {
        int r = i >> 6, d = i & 63;
        relkb[i] = (r < 129) ? f2bf(relk[r * 64 + d]) : (short)0;
    }
    for (int i = tid; i < 64 * 128; i += 256) {
        int d = i >> 7, r = i & 127;
        relvT[i] = f2bf(relv[r * 64 + d]);
    }
}

// ---------------------------------------------------------------------------
// Fused QKV GEMM; V segment stores TRANSPOSED + k-interleaved:
// col(k) = (k>>5)*32 + (k&3) + (((k>>4)&1)<<2) + (((k>>2)&3)<<3)
// ---------------------------------------------------------------------------
__global__ __launch_bounds__(256)
void gemm_qkv(const short* __restrict__ Ab, const short* __restrict__ Wt,
              const float* __restrict__ bq, const float* __restrict__ bk,
              const float* __restrict__ bv,
              short* __restrict__ Qb, short* __restrict__ Kb, short* __restrict__ Vtb)
{
    __shared__ __align__(16) short As[128 * 64];
    __shared__ __align__(16) short Bs[128 * 64];
    const int tid = threadIdx.x;
    const int w = tid >> 6, lane = tid & 63;
    const int lo16 = lane & 15, hi = lane >> 4;
    const int n0g = blockIdx.x * 128;
    const int m0 = blockIdx.y * 128;
    const int wr = w >> 1, wc = w & 1;

    f32x4 acc[4][4] = {};

    for (int t = 0; t < 16; ++t) {
        const int k0 = t * 64;
        __syncthreads();
#pragma unroll
        for (int i = 0; i < 4; ++i) {
            int o = i * 4096 + tid * 16;
            int row = o >> 7;
            int cb = o & 127;
            int sc = cb ^ ((row & 7) << 4);
            async_copy16((char*)As + o, Ab + (size_t)(m0 + row) * 1024 + k0 + (sc >> 1));
            async_copy16((char*)Bs + o, Wt + (size_t)(n0g + row) * 1024 + k0 + (sc >> 1));
        }
        __syncthreads();
#pragma unroll
        for (int ks = 0; ks < 2; ++ks) {
            s16x8 aF[4], bF[4];
#pragma unroll
            for (int mi = 0; mi < 4; ++mi) {
                int row = wr * 64 + mi * 16 + lo16;
                int cb = ks * 64 + hi * 16;
                aF[mi] = *(const s16x8*)((const char*)As + row * 128 + (cb ^ ((row & 7) << 4)));
            }
#pragma unroll
            for (int ni = 0; ni < 4; ++ni) {
                int row = wc * 64 + ni * 16 + lo16;
                int cb = ks * 64 + hi * 16;
                bF[ni] = *(const s16x8*)((const char*)Bs + row * 128 + (cb ^ ((row & 7) << 4)));
            }
#pragma unroll
            for (int mi = 0; mi < 4; ++mi)
#pragma unroll
                for (int ni = 0; ni < 4; ++ni)
                    acc[mi][ni] = MFMA(aF[mi], bF[ni], acc[mi][ni]);
        }
    }

    const int seg = n0g >> 10;
    const int nn = n0g & 1023;
    const float* bias = seg == 0 ? bq : seg == 1 ? bk : bv;
    float bv4[4];
#pragma unroll
    for (int ni = 0; ni < 4; ++ni) bv4[ni] = bias[nn + wc * 64 + ni * 16 + lo16];

    if (seg == 2) {
        // V: store transposed + interleaved, 4 consecutive l per thread -> 8B stores
#pragma unroll
        for (int mi = 0; mi < 4; ++mi)
#pragma unroll
            for (int ni = 0; ni < 4; ++ni) {
                int nl = nn + wc * 64 + ni * 16 + lo16;
                int hh = nl >> 6, d = nl & 63;
                int mbase = m0 + wr * 64 + mi * 16 + hi * 4;
                int bb = mbase >> 10, l0 = mbase & 1023;
                int j0 = l0 & 31;                          // j0 % 4 == 0
                int col = (l0 >> 5) * 32 + (((j0 >> 4) & 1) << 2) + (((j0 >> 2) & 3) << 3);
                s16x4 pk = { f2bf(acc[mi][ni][0] + bv4[ni]),
                             f2bf(acc[mi][ni][1] + bv4[ni]),
                             f2bf(acc[mi][ni][2] + bv4[ni]),
                             f2bf(acc[mi][ni][3] + bv4[ni]) };
                *(s16x4*)&Vtb[((size_t)(bb * 16 + hh) * 64 + d) * 1024 + col] = pk;
            }
    } else {
        short* out = seg == 0 ? Qb : Kb;
#pragma unroll
        for (int mi = 0; mi < 4; ++mi)
#pragma unroll
            for (int ni = 0; ni < 4; ++ni) {
                int nl = nn + wc * 64 + ni * 16 + lo16;
                int hh = nl >> 6, d = nl & 63;
#pragma unroll
                for (int r = 0; r < 4; ++r) {
                    int m = m0 + wr * 64 + mi * 16 + hi * 4 + r;
                    int bb = m >> 10, l = m & 1023;
                    out[(((size_t)bb * 16 + hh) * 1024 + l) * 64 + d] = f2bf(acc[mi][ni][r] + bv4[ni]);
                }
            }
    }
}

// ---------------------------------------------------------------------------
// Flash attention v9: SINGLE-buffered K+V LDS tile (52.1KB total -> 3
// blocks/CU). Per 64-k iter: phase A reads whole tile LDS->regs (fence
// forces them to stay in VGPRs), barrier, stage t+1 into same buffer
// (drain covered by compute), compute both 32-k chunks, barrier.
// Only __syncthreads — provably-safe sync.
// ---------------------------------------------------------------------------
struct TileRegs {
    s16x8 k0, k1, k2, k3;    // K frags (QK A-operand)
    s16x8 v0, v1, v2, v3;    // V frags (two 8B PV A-frags packed per 16B)
    s16x4 m0, m1;            // mask bias
};

__device__ __forceinline__ void prefetch_tile(
    const short* __restrict__ sKc, const short* __restrict__ sVc,
    const short* __restrict__ sMaskP, int kfm, int lo16, int hi, TileRegs& R)
{
    const int km = lo16 & 7;
    R.k0 = *(const s16x8*)(sKc + lo16 * 64 + ((hi ^ km) << 3));
    R.k1 = *(const s16x8*)(sKc + lo16 * 64 + (((hi + 4) ^ km) << 3));
    R.k2 = *(const s16x8*)(sKc + (lo16 + 16) * 64 + ((hi ^ km) << 3));
    R.k3 = *(const s16x8*)(sKc + (lo16 + 16) * 64 + (((hi + 4) ^ km) << 3));
    R.v0 = *(const s16x8*)(sVc + lo16 * 32 + hi * 8);
    R.v1 = *(const s16x8*)(sVc + (16 + lo16) * 32 + hi * 8);
    R.v2 = *(const s16x8*)(sVc + (32 + lo16) * 32 + hi * 8);
    R.v3 = *(const s16x8*)(sVc + (48 + lo16) * 32 + hi * 8);
    R.m0 = *(const s16x4*)&sMaskP[kfm + hi * 4];
    R.m1 = *(const s16x4*)&sMaskP[kfm + 16 + hi * 4];
}

__device__ __forceinline__ void process32(
    int kf, int q0, int q_abs, int lo16, int hi,
    const TileRegs& R,
    const s16x8& qB0, const s16x8& qB1,
    float qrel_lo, float qrel_hi,
    const short (*sQrelw)[144], short (*sBandw)[128],
    f32x4* ctx, float& lsum, float& lov, float& hiv)
{
    const f32x4 z = {0.f, 0.f, 0.f, 0.f};
    __builtin_amdgcn_s_setprio(1);
    f32x4 sa = MFMA(R.k0, qB0, z);
    f32x4 sb = MFMA(R.k1, qB1, z);
    f32x4 sc = MFMA(R.k2, qB0, z);
    f32x4 sd = MFMA(R.k3, qB1, z);
    __builtin_amdgcn_s_setprio(0);
    f32x4 s0 = sa + sb, s1 = sc + sd;

    float p[8];
    if (kf + 95 <= q0 || kf >= q0 + 79) {
        // whole block out of band: rel uniform 0 or 128
        const float qc = (kf < q0) ? qrel_lo : qrel_hi;
        float bs = 0.f;
#pragma unroll
        for (int r = 0; r < 4; ++r) {
            p[r]     = __expf(s0[r] + qc + bf2f(R.m0[r]));
            p[4 + r] = __expf(s1[r] + qc + bf2f(R.m1[r]));
        }
#pragma unroll
        for (int r = 0; r < 8; ++r) bs += p[r];
        lsum += bs;
        if (kf < q0) lov += bs; else hiv += bs;
    } else {
#pragma unroll
        for (int f = 0; f < 2; ++f)
#pragma unroll
            for (int r = 0; r < 4; ++r) {
                int k_abs = kf + f * 16 + hi * 4 + r;
                int dd = k_abs - q_abs;
                dd = dd < -64 ? -64 : (dd > 64 ? 64 : dd);
                int rel = dd + 64;
                float sv = f ? s1[r] : s0[r];
                float mv = bf2f(f ? R.m1[r] : R.m0[r]);
                float pex = __expf(sv + bf2f(sQrelw[lo16][rel]) + mv);
                p[f * 4 + r] = pex;
                lsum += pex;
                if (rel >= 1 && rel <= 127) sBandw[lo16][rel] = f2bf(pex);
                else if (rel == 0) lov += pex;
                else hiv += pex;
            }
    }

    // S-frag (col=q=lo16, k=hi*4+r) IS the 16x16x16 B-operand layout: no shuffle.
    u32x2 w0 = { cvtpk(p[0], p[1]), cvtpk(p[2], p[3]) };
    u32x2 w1 = { cvtpk(p[4], p[5]), cvtpk(p[6], p[7]) };
    s16x4 pf0 = __builtin_bit_cast(s16x4, w0);
    s16x4 pf1 = __builtin_bit_cast(s16x4, w1);

    // split interleaved V chunks: low 8B = f0 frag, high 8B = f1 frag
    s16x4 a0 = __builtin_shufflevector(R.v0, R.v0, 0, 1, 2, 3);
    s16x4 b0 = __builtin_shufflevector(R.v0, R.v0, 4, 5, 6, 7);
    s16x4 a1 = __builtin_shufflevector(R.v1, R.v1, 0, 1, 2, 3);
    s16x4 b1 = __builtin_shufflevector(R.v1, R.v1, 4, 5, 6, 7);
    s16x4 a2 = __builtin_shufflevector(R.v2, R.v2, 0, 1, 2, 3);
    s16x4 b2 = __builtin_shufflevector(R.v2, R.v2, 4, 5, 6, 7);
    s16x4 a3 = __builtin_shufflevector(R.v3, R.v3, 0, 1, 2, 3);
    s16x4 b3 = __builtin_shufflevector(R.v3, R.v3, 4, 5, 6, 7);

    __builtin_amdgcn_s_setprio(1);
    ctx[0] = MFMA16(a0, pf0, ctx[0]);
    ctx[1] = MFMA16(a1, pf0, ctx[1]);
    ctx[2] = MFMA16(a2, pf0, ctx[2]);
    ctx[3] = MFMA16(a3, pf0, ctx[3]);
    ctx[0] = MFMA16(b0, pf1, ctx[0]);
    ctx[1] = MFMA16(b1, pf1, ctx[1]);
    ctx[2] = MFMA16(b2, pf1, ctx[2]);
    ctx[3] = MFMA16(b3, pf1, ctx[3]);
    __builtin_amdgcn_s_setprio(0);
}

__global__ __launch_bounds__(256, 3)
void attn_mfma(const short* __restrict__ Qb, const short* __restrict__ Kb,
               const short* __restrict__ Vtb, const short* __restrict__ relkb,
               const short* __restrict__ relvTb, const float* __restrict__ relv_f32,
               const float* __restrict__ mask, short* __restrict__ CTXb)
{
    __shared__ __align__(16) short sK[2][32 * 64];     // [sub], single tile, swizzled (8KB)
    __shared__ __align__(16) short sV[2][64 * 32];     // [sub], k-interleaved (8KB)
    __shared__ __align__(16) short sMaskP[1024 + 32];  // bf16 mask * -1e9 (2.1KB)
    __shared__ __align__(16) short sQrel[4][16][144];  // bf16 Qrel[q][r] (18.4KB)
    __shared__ __align__(16) short sBand[4][16][128];  // bf16 band weights (16KB)

    const int tid = threadIdx.x;
    const int w = tid >> 6, lane = tid & 63;
    const int lo16 = lane & 15, hi = lane >> 4;

    // XCD-aware swizzle (1024 = 8*128, bijective); same-bh blocks share an XCD L2
    const int p = blockIdx.x;
    const int bid = (p & 7) * 128 + (p >> 3);
    const int bh = bid >> 4;
    const int qt = bid & 15;
    const int b = bh >> 4, h = bh & 15;
    const int q0 = qt * 64 + w * 16;
    const int q_abs = q0 + lo16;

    const short* Kbase = Kb + (size_t)bh * 65536;
    const short* Vtbase = Vtb + (size_t)bh * 65536;

    // staging geometry (per thread, 1x16B per async op)
    const int skr = tid >> 3, skc = tid & 7;             // K: row 0..31, chunk 0..7
    const int svd = tid >> 2, svc = tid & 3;             // V: row d 0..63, chunk 0..3
    const short* ksrc = Kbase + (size_t)skr * 64 + ((skc ^ (skr & 7)) << 3);
    const short* vsrc = Vtbase + (size_t)svd * 1024 + svc * 8;   // interleave is in global layout

    // stage tile 0 (both 32-k subs)
    async_copy16((char*)&sK[0][0] + tid * 16, ksrc);
    async_copy16((char*)&sK[1][0] + tid * 16, ksrc + 32 * 64);
    async_copy16((char*)&sV[0][0] + tid * 16, vsrc);
    async_copy16((char*)&sV[1][0] + tid * 16, vsrc + 32);

    // persistent Q fragments (B-operand: col = q = lane&15, depth = hi*8+j)
    const short* qptr = Qb + ((size_t)bh * 1024 + q_abs) * 64 + hi * 8;
    const s16x8 qB0 = *(const s16x8*)qptr;
    const s16x8 qB1 = *(const s16x8*)(qptr + 32);

    // init shared: maskP (block-wide), sBand zero (per-wave region)
    {
        float4 mv = *(const float4*)&mask[b * 1024 + tid * 4];
        s16x4 mp = { f2bf(mv.x * -1e9f), f2bf(mv.y * -1e9f),
                     f2bf(mv.z * -1e9f), f2bf(mv.w * -1e9f) };
        *(s16x4*)&sMaskP[tid * 4] = mp;
        if (tid < 8) *(s16x4*)&sMaskP[1024 + tid * 4] = s16x4{0, 0, 0, 0};
    }
    {
        u32* bz = (u32*)&sBand[w][0][0];   // 16*128 shorts = 1024 u32 per wave
#pragma unroll
        for (int i = 0; i < 16; ++i) bz[lane + i * 64] = 0u;
    }

    // Qrel^T = relk @ Q^T : 9 r-frags -> sQrel[w][q][r] (bf16)
#pragma unroll
    for (int rf = 0; rf < 9; ++rf) {
        const short* rp = relkb + (size_t)(rf * 16 + lo16) * 64 + hi * 8;
        s16x8 rA0 = *(const s16x8*)rp;
        s16x8 rA1 = *(const s16x8*)(rp + 32);
        f32x4 dq = {0.f, 0.f, 0.f, 0.f};
        dq = MFMA(rA0, qB0, dq);
        dq = MFMA(rA1, qB1, dq);
        s16x4 pk = { f2bf(dq[0]), f2bf(dq[1]), f2bf(dq[2]), f2bf(dq[3]) };
        *(s16x4*)&sQrel[w][lo16][rf * 16 + hi * 4] = pk;
    }
    __syncthreads();   // drains tile-0 staging; fences sMaskP/sQrel (= barrier 2 of iter -1)

    const float qrel_lo = bf2f(sQrel[w][lo16][0]);
    const float qrel_hi = bf2f(sQrel[w][lo16][128]);

    f32x4 ctx[4] = {};
    float lsum = 0.f, lov = 0.f, hiv = 0.f;

    TileRegs R0, R1;
    for (int t = 0; t < 16; ++t) {
        // phase A: whole tile t LDS -> regs (fence below forces them live)
        prefetch_tile(sK[0], sV[0], sMaskP, t * 64,      lo16, hi, R0);
        prefetch_tile(sK[1], sV[1], sMaskP, t * 64 + 32, lo16, hi, R1);
        __syncthreads();   // barrier 1: all waves done reading the buffer
        // stage tile t+1 into the same (single) buffer; drains at barrier 2
        const int kb = ((t + 1) & 15) * 64;     // wrapped at t=15 (dead data)
        async_copy16((char*)&sK[0][0] + tid * 16, ksrc + (size_t)kb * 64);
        async_copy16((char*)&sK[1][0] + tid * 16, ksrc + (size_t)(kb + 32) * 64);
        async_copy16((char*)&sV[0][0] + tid * 16, vsrc + kb);
        async_copy16((char*)&sV[1][0] + tid * 16, vsrc + kb + 32);
        // compute tile t from registers (covers the staging latency)
        process32(t * 64,      q0, q_abs, lo16, hi, R0, qB0, qB1, qrel_lo, qrel_hi,
                  sQrel[w], sBand[w], ctx, lsum, lov, hiv);
        process32(t * 64 + 32, q0, q_abs, lo16, hi, R1, qB0, qB1, qrel_lo, qrel_hi,
                  sQrel[w], sBand[w], ctx, lsum, lov, hiv);
        __syncthreads();   // barrier 2: staging (vmcnt) complete for all waves
    }

    // band rel_v contribution: ctx^T += relvT-frag x sBand-frag (unnormalized)
#pragma unroll
    for (int ks = 0; ks < 4; ++ks) {
        s16x8 bB = *(const s16x8*)&sBand[w][lo16][ks * 32 + hi * 8];
#pragma unroll
        for (int df = 0; df < 4; ++df) {
            s16x8 rA = *(const s16x8*)(relvTb + (size_t)(df * 16 + lo16) * 128 + ks * 32 + hi * 8);
            ctx[df] = MFMA(rA, bB, ctx[df]);
        }
    }

    // reduce per-q stats across the 4 hi-groups
    lsum += __shfl_xor(lsum, 16); lsum += __shfl_xor(lsum, 32);
    lov  += __shfl_xor(lov, 16);  lov  += __shfl_xor(lov, 32);
    hiv  += __shfl_xor(hiv, 16);  hiv  += __shfl_xor(hiv, 32);
    const float inv = 1.0f / lsum;

    // tails (clipped buckets 0 / 128) + normalize + store bf16 ctx
#pragma unroll
    for (int df = 0; df < 4; ++df) {
        s16x4 pk;
#pragma unroll
        for (int r = 0; r < 4; ++r) {
            int d = df * 16 + hi * 4 + r;
            float t = ctx[df][r] + lov * relv_f32[d] + hiv * relv_f32[128 * 64 + d];
            pk[r] = f2bf(t * inv);
        }
        *(s16x4*)(CTXb + ((size_t)(b * 1024) + q_abs) * 1024 + h * 64 + df * 16 + hi * 4) = pk;
    }
}

// ---------------------------------------------------------------------------
// Output GEMM: out[4096,1024] = CTXb @ wo + bo (fp32 out). 128x64 tile, BK=64.
// ---------------------------------------------------------------------------
__global__ __launch_bounds__(256)
void gemm_out(const short* __restrict__ Ab, const short* __restrict__ Wto,
              const float* __restrict__ bo, float* __restrict__ out)
{
    __shared__ __align__(16) short As[128 * 64];
    __shared__ __align__(16) short Bs[64 * 64];
    const int tid = threadIdx.x;
    const int w = tid >> 6, lane = tid & 63;
    const int lo16 = lane & 15, hi = lane >> 4;
    const int n0 = blockIdx.x * 64;
    const int m0 = blockIdx.y * 128;
    const int wr = w;

    f32x4 acc[2][4] = {};

    for (int t = 0; t < 16; ++t) {
        const int k0 = t * 64;
        __syncthreads();
#pragma unroll
        for (int i = 0; i < 4; ++i) {
            int o = i * 4096 + tid * 16;
            int row = o >> 7;
            int cb = o & 127;
            int sc = cb ^ ((row & 7) << 4);
            async_copy16((char*)As + o, Ab + (size_t)(m0 + row) * 1024 + k0 + (sc >> 1));
        }
#pragma unroll
        for (int i = 0; i < 2; ++i) {
            int o = i * 4096 + tid * 16;
            int row = o >> 7;
            int cb = o & 127;
            int sc = cb ^ ((row & 7) << 4);
            async_copy16((char*)Bs + o, Wto + (size_t)(n0 + row) * 1024 + k0 + (sc >> 1));
        }
        __syncthreads();
#pragma unroll
        for (int ks = 0; ks < 2; ++ks) {
            s16x8 aF[2], bF[4];
#pragma unroll
            for (int mi = 0; mi < 2; ++mi) {
                int row = wr * 32 + mi * 16 + lo16;
                int cb = ks * 64 + hi * 16;
                aF[mi] = *(const s16x8*)((const char*)As + row * 128 + (cb ^ ((row & 7) << 4)));
            }
#pragma unroll
            for (int ni = 0; ni < 4; ++ni) {
                int row = ni * 16 + lo16;
                int cb = ks * 64 + hi * 16;
                bF[ni] = *(const s16x8*)((const char*)Bs + row * 128 + (cb ^ ((row & 7) << 4)));
            }
#pragma unroll
            for (int mi = 0; mi < 2; ++mi)
#pragma unroll
                for (int ni = 0; ni < 4; ++ni)
                    acc[mi][ni] = MFMA(aF[mi], bF[ni], acc[mi][ni]);
        }
    }

    float bv4[4];
#pragma unroll
    for (int ni = 0; ni < 4; ++ni) bv4[ni] = bo[n0 + ni * 16 + lo16];
#pragma unroll
    for (int mi = 0; mi < 2; ++mi)
#pragma unroll
        for (int ni = 0; ni < 4; ++ni)
#pragma unroll
            for (int r = 0; r < 4; ++r) {
                int m = m0 + wr * 32 + mi * 16 + hi * 4 + r;
                out[(size_t)m * 1024 + n0 + ni * 16 + lo16] = acc[mi][ni][r] + bv4[ni];
            }
}

// ---------------------------------------------------------------------------
extern "C" void kernel_launch(void* const* d_in, const int* in_sizes, int n_in,
                              void* d_out, int out_size, void* d_ws, size_t ws_size,
                              hipStream_t stream)
{
    (void)in_sizes; (void)n_in; (void)out_size; (void)ws_size;
    const float* x    = (const float*)d_in[0];
    const float* mask = (const float*)d_in[1];
    const float* wq   = (const float*)d_in[2];
    const float* bq   = (const float*)d_in[3];
    const float* wk   = (const float*)d_in[4];
    const float* bk   = (const float*)d_in[5];
    const float* wv   = (const float*)d_in[6];
    const float* bv   = (const float*)d_in[7];
    const float* wo   = (const float*)d_in[8];
    const float* bo   = (const float*)d_in[9];
    const float* relk = (const float*)d_in[10];
    const float* relv = (const float*)d_in[11];
    float* out = (float*)d_out;

    char* p = (char*)d_ws;
    short* xb    = (short*)p; p += (size_t)4096 * 1024 * 2;     // 8 MB
    short* Wtqkv = (short*)p; p += (size_t)3072 * 1024 * 2;     // 6 MB
    short* Wto   = (short*)p; p += (size_t)1024 * 1024 * 2;     // 2 MB
    short* Qb    = (short*)p; p += (size_t)4096 * 1024 * 2;     // 8 MB
    short* Kb    = (short*)p; p += (size_t)4096 * 1024 * 2;     // 8 MB
    short* Vtb   = (short*)p; p += (size_t)4096 * 1024 * 2;     // 8 MB
    short* CTXb  = (short*)p; p += (size_t)4096 * 1024 * 2;     // 8 MB
    short* relkb = (short*)p; p += (size_t)144 * 64 * 2;
    short* relvT = (short*)p; p += (size_t)64 * 128 * 2;

    cast_x       <<<2048, 256, 0, stream>>>(x, xb);
    transpose_w  <<<dim3(16, 16, 4), 256, 0, stream>>>(wq, wk, wv, wo, Wtqkv, Wto);
    prep_tables  <<<1, 256, 0, stream>>>(relk, relv, relkb, relvT);
    gemm_qkv     <<<dim3(24, 32), 256, 0, stream>>>(xb, Wtqkv, bq, bk, bv, Qb, Kb, Vtb);
    attn_mfma    <<<1024, 256, 0, stream>>>(Qb, Kb, Vtb, relkb, relvT, relv, mask, CTXb);
    gemm_out     <<<dim3(16, 32), 256, 0, stream>>>(CTXb, Wto, bo, out);
}

// Round 13
// 140.598 us; speedup vs baseline: 1.4029x; 1.0272x over previous
//
#include <hip/hip_runtime.h>
#include <hip/hip_bf16.h>
#include <cstdint>
#include <cstddef>

typedef unsigned int u32;
typedef __attribute__((ext_vector_type(8))) short s16x8;   // 8 bf16 (4 VGPR) MFMA A/B frag
typedef __attribute__((ext_vector_type(4))) short s16x4;   // 4 bf16, 8B pack
typedef __attribute__((ext_vector_type(4))) float f32x4;   // MFMA C/D frag
typedef __attribute__((ext_vector_type(2))) u32   u32x2;

#define MFMA(a,b,c) __builtin_amdgcn_mfma_f32_16x16x32_bf16(a,b,c,0,0,0)

#if __has_builtin(__builtin_amdgcn_mfma_f32_16x16x16bf16_1k)
#define MFMA16(a,b,c) __builtin_amdgcn_mfma_f32_16x16x16bf16_1k(a,b,c,0,0,0)
#else
static __device__ __forceinline__ f32x4 MFMA16(s16x4 a, s16x4 b, f32x4 c){
    f32x4 d;
    asm("v_mfma_f32_16x16x16_bf16 %0, %1, %2, %3"
        : "=v"(d) : "v"(a), "v"(b), "v"(c));
    return d;
}
#endif

__device__ __forceinline__ short f2bf(float f) {
    u32 u = __builtin_bit_cast(u32, f);
    u32 r = (u + 0x7fffu + ((u >> 16) & 1u)) >> 16;   // RNE
    return (short)r;
}
__device__ __forceinline__ float bf2f(short s) {
    return __builtin_bit_cast(float, ((u32)(unsigned short)s) << 16);
}
__device__ __forceinline__ u32 cvtpk(float lo, float hi) {
    u32 r;
    asm("v_cvt_pk_bf16_f32 %0, %1, %2" : "=v"(r) : "v"(lo), "v"(hi));
    return r;
}
__device__ __forceinline__ void async_copy16(void* lds, const void* g) {
    __builtin_amdgcn_global_load_lds((const __attribute__((address_space(1))) u32*)g,
                                     (__attribute__((address_space(3))) u32*)lds, 16, 0, 0);
}

// ---------------------------------------------------------------------------
// Prep: cast x (fp32 -> bf16), 8 elems/thread
// ---------------------------------------------------------------------------
__global__ __launch_bounds__(256) void cast_x(const float* __restrict__ x, short* __restrict__ xb) {
    int i = (blockIdx.x * 256 + threadIdx.x) * 8;
    float4 a = *(const float4*)&x[i];
    float4 b = *(const float4*)&x[i + 4];
    s16x8 v = { f2bf(a.x), f2bf(a.y), f2bf(a.z), f2bf(a.w),
                f2bf(b.x), f2bf(b.y), f2bf(b.z), f2bf(b.w) };
    *(s16x8*)&xb[i] = v;
}

// ---------------------------------------------------------------------------
// Prep: transpose + cast weights. seg 0..2 -> Wtqkv rows [seg*1024, +1024); seg 3 -> Wto.
// ---------------------------------------------------------------------------
__global__ __launch_bounds__(256)
void transpose_w(const float* __restrict__ wq, const float* __restrict__ wk,
                 const float* __restrict__ wv, const float* __restrict__ wo,
                 short* __restrict__ Wtqkv, short* __restrict__ Wto)
{
    __shared__ float sT[64][68];
    const int kt = blockIdx.x, nt = blockIdx.y, seg = blockIdx.z;
    const float* src = seg == 0 ? wq : seg == 1 ? wk : seg == 2 ? wv : wo;
    const int k0 = kt * 64, n0 = nt * 64;
    const int tid = threadIdx.x;
#pragma unroll
    for (int i = 0; i < 4; ++i) {
        int t2 = tid + i * 256;          // 0..1023 -> 64 rows x 16 float4
        int r = t2 >> 4, c4 = t2 & 15;
        *(float4*)&sT[r][c4 * 4] = *(const float4*)&src[(size_t)(k0 + r) * 1024 + n0 + c4 * 4];
    }
    __syncthreads();
#pragma unroll
    for (int i = 0; i < 2; ++i) {
        int t2 = tid + i * 256;
        int rn = t2 >> 3, ch = t2 & 7;
        s16x8 v;
#pragma unroll
        for (int j = 0; j < 8; ++j) v[j] = f2bf(sT[ch * 8 + j][rn]);
        if (seg < 3)
            *(s16x8*)&Wtqkv[(size_t)(seg * 1024 + n0 + rn) * 1024 + k0 + ch * 8] = v;
        else
            *(s16x8*)&Wto[(size_t)(n0 + rn) * 1024 + k0 + ch * 8] = v;
    }
}

// ---------------------------------------------------------------------------
// Prep: relkb [144][64] bf16 zero-padded rows>=129; relvT [64][128] bf16 (r<128).
// 8 blocks, grid-strided.
// ---------------------------------------------------------------------------
__global__ __launch_bounds__(256)
void prep_tables(const float* __restrict__ relk, const float* __restrict__ relv,
                 short* __restrict__ relkb, short* __restrict__ relvT)
{
    int tid = blockIdx.x * 256 + threadIdx.x;
    for (int i = tid; i < 144 * 64; i += 256 * 8) {
        int r = i >> 6, d = i & 63;
        relkb[i] = (r < 129) ? f2bf(relk[r * 64 + d]) : (short)0;
    }
    for (int i = tid; i < 64 * 128; i += 256 * 8) {
        int d = i >> 7, r = i & 127;
        relvT[i] = f2bf(relv[r * 64 + d]);
    }
}

// ---------------------------------------------------------------------------
// Fused QKV GEMM (XCD-swizzled 1D grid, 768 blocks); V segment stores
// TRANSPOSED + k-interleaved: col(k) = (k>>5)*32 + (k&3)+(((k>>4)&1)<<2)+(((k>>2)&3)<<3)
// ---------------------------------------------------------------------------
__global__ __launch_bounds__(256)
void gemm_qkv(const short* __restrict__ Ab, const short* __restrict__ Wt,
              const float* __restrict__ bq, const float* __restrict__ bk,
              const float* __restrict__ bv,
              short* __restrict__ Qb, short* __restrict__ Kb, short* __restrict__ Vtb)
{
    __shared__ __align__(16) short As[128 * 64];
    __shared__ __align__(16) short Bs[128 * 64];
    const int tid = threadIdx.x;
    const int w = tid >> 6, lane = tid & 63;
    const int lo16 = lane & 15, hi = lane >> 4;
    // XCD swizzle: 768 blocks % 8 == 0 -> bijective; same-XCD blocks share m-panel
    const int pb = blockIdx.x;
    const int wg = (pb & 7) * 96 + (pb >> 3);
    const int n0g = (wg % 24) * 128;
    const int m0 = (wg / 24) * 128;
    const int wr = w >> 1, wc = w & 1;

    f32x4 acc[4][4] = {};

    for (int t = 0; t < 16; ++t) {
        const int k0 = t * 64;
        __syncthreads();
#pragma unroll
        for (int i = 0; i < 4; ++i) {
            int o = i * 4096 + tid * 16;
            int row = o >> 7;
            int cb = o & 127;
            int sc = cb ^ ((row & 7) << 4);
            async_copy16((char*)As + o, Ab + (size_t)(m0 + row) * 1024 + k0 + (sc >> 1));
            async_copy16((char*)Bs + o, Wt + (size_t)(n0g + row) * 1024 + k0 + (sc >> 1));
        }
        __syncthreads();
#pragma unroll
        for (int ks = 0; ks < 2; ++ks) {
            s16x8 aF[4], bF[4];
#pragma unroll
            for (int mi = 0; mi < 4; ++mi) {
                int row = wr * 64 + mi * 16 + lo16;
                int cb = ks * 64 + hi * 16;
                aF[mi] = *(const s16x8*)((const char*)As + row * 128 + (cb ^ ((row & 7) << 4)));
            }
#pragma unroll
            for (int ni = 0; ni < 4; ++ni) {
                int row = wc * 64 + ni * 16 + lo16;
                int cb = ks * 64 + hi * 16;
                bF[ni] = *(const s16x8*)((const char*)Bs + row * 128 + (cb ^ ((row & 7) << 4)));
            }
#pragma unroll
            for (int mi = 0; mi < 4; ++mi)
#pragma unroll
                for (int ni = 0; ni < 4; ++ni)
                    acc[mi][ni] = MFMA(aF[mi], bF[ni], acc[mi][ni]);
        }
    }

    const int seg = n0g >> 10;
    const int nn = n0g & 1023;
    const float* bias = seg == 0 ? bq : seg == 1 ? bk : bv;
    float bv4[4];
#pragma unroll
    for (int ni = 0; ni < 4; ++ni) bv4[ni] = bias[nn + wc * 64 + ni * 16 + lo16];

    if (seg == 2) {
        // V: store transposed + interleaved, 4 consecutive l per thread -> 8B stores
#pragma unroll
        for (int mi = 0; mi < 4; ++mi)
#pragma unroll
            for (int ni = 0; ni < 4; ++ni) {
                int nl = nn + wc * 64 + ni * 16 + lo16;
                int hh = nl >> 6, d = nl & 63;
                int mbase = m0 + wr * 64 + mi * 16 + hi * 4;
                int bb = mbase >> 10, l0 = mbase & 1023;
                int j0 = l0 & 31;                          // j0 % 4 == 0
                int col = (l0 >> 5) * 32 + (((j0 >> 4) & 1) << 2) + (((j0 >> 2) & 3) << 3);
                s16x4 pk = { f2bf(acc[mi][ni][0] + bv4[ni]),
                             f2bf(acc[mi][ni][1] + bv4[ni]),
                             f2bf(acc[mi][ni][2] + bv4[ni]),
                             f2bf(acc[mi][ni][3] + bv4[ni]) };
                *(s16x4*)&Vtb[((size_t)(bb * 16 + hh) * 64 + d) * 1024 + col] = pk;
            }
    } else {
        short* out = seg == 0 ? Qb : Kb;
#pragma unroll
        for (int mi = 0; mi < 4; ++mi)
#pragma unroll
            for (int ni = 0; ni < 4; ++ni) {
                int nl = nn + wc * 64 + ni * 16 + lo16;
                int hh = nl >> 6, d = nl & 63;
#pragma unroll
                for (int r = 0; r < 4; ++r) {
                    int m = m0 + wr * 64 + mi * 16 + hi * 4 + r;
                    int bb = m >> 10, l = m & 1023;
                    out[(((size_t)bb * 16 + hh) * 1024 + l) * 64 + d] = f2bf(acc[mi][ni][r] + bv4[ni]);
                }
            }
    }
}

// ---------------------------------------------------------------------------
// Flash attention v9 (UNCHANGED from round 12 — passing, 64.4us):
// single-buffered K+V LDS tile, 3 blocks/CU, __syncthreads-only sync.
// ---------------------------------------------------------------------------
struct TileRegs {
    s16x8 k0, k1, k2, k3;    // K frags (QK A-operand)
    s16x8 v0, v1, v2, v3;    // V frags (two 8B PV A-frags packed per 16B)
    s16x4 m0, m1;            // mask bias
};

__device__ __forceinline__ void prefetch_tile(
    const short* __restrict__ sKc, const short* __restrict__ sVc,
    const short* __restrict__ sMaskP, int kfm, int lo16, int hi, TileRegs& R)
{
    const int km = lo16 & 7;
    R.k0 = *(const s16x8*)(sKc + lo16 * 64 + ((hi ^ km) << 3));
    R.k1 = *(const s16x8*)(sKc + lo16 * 64 + (((hi + 4) ^ km) << 3));
    R.k2 = *(const s16x8*)(sKc + (lo16 + 16) * 64 + ((hi ^ km) << 3));
    R.k3 = *(const s16x8*)(sKc + (lo16 + 16) * 64 + (((hi + 4) ^ km) << 3));
    R.v0 = *(const s16x8*)(sVc + lo16 * 32 + hi * 8);
    R.v1 = *(const s16x8*)(sVc + (16 + lo16) * 32 + hi * 8);
    R.v2 = *(const s16x8*)(sVc + (32 + lo16) * 32 + hi * 8);
    R.v3 = *(const s16x8*)(sVc + (48 + lo16) * 32 + hi * 8);
    R.m0 = *(const s16x4*)&sMaskP[kfm + hi * 4];
    R.m1 = *(const s16x4*)&sMaskP[kfm + 16 + hi * 4];
}

__device__ __forceinline__ void process32(
    int kf, int q0, int q_abs, int lo16, int hi,
    const TileRegs& R,
    const s16x8& qB0, const s16x8& qB1,
    float qrel_lo, float qrel_hi,
    const short (*sQrelw)[144], short (*sBandw)[128],
    f32x4* ctx, float& lsum, float& lov, float& hiv)
{
    const f32x4 z = {0.f, 0.f, 0.f, 0.f};
    __builtin_amdgcn_s_setprio(1);
    f32x4 sa = MFMA(R.k0, qB0, z);
    f32x4 sb = MFMA(R.k1, qB1, z);
    f32x4 sc = MFMA(R.k2, qB0, z);
    f32x4 sd = MFMA(R.k3, qB1, z);
    __builtin_amdgcn_s_setprio(0);
    f32x4 s0 = sa + sb, s1 = sc + sd;

    float p[8];
    if (kf + 95 <= q0 || kf >= q0 + 79) {
        // whole block out of band: rel uniform 0 or 128
        const float qc = (kf < q0) ? qrel_lo : qrel_hi;
        float bs = 0.f;
#pragma unroll
        for (int r = 0; r < 4; ++r) {
            p[r]     = __expf(s0[r] + qc + bf2f(R.m0[r]));
            p[4 + r] = __expf(s1[r] + qc + bf2f(R.m1[r]));
        }
#pragma unroll
        for (int r = 0; r < 8; ++r) bs += p[r];
        lsum += bs;
        if (kf < q0) lov += bs; else hiv += bs;
    } else {
#pragma unroll
        for (int f = 0; f < 2; ++f)
#pragma unroll
            for (int r = 0; r < 4; ++r) {
                int k_abs = kf + f * 16 + hi * 4 + r;
                int dd = k_abs - q_abs;
                dd = dd < -64 ? -64 : (dd > 64 ? 64 : dd);
                int rel = dd + 64;
                float sv = f ? s1[r] : s0[r];
                float mv = bf2f(f ? R.m1[r] : R.m0[r]);
                float pex = __expf(sv + bf2f(sQrelw[lo16][rel]) + mv);
                p[f * 4 + r] = pex;
                lsum += pex;
                if (rel >= 1 && rel <= 127) sBandw[lo16][rel] = f2bf(pex);
                else if (rel == 0) lov += pex;
                else hiv += pex;
            }
    }

    // S-frag (col=q=lo16, k=hi*4+r) IS the 16x16x16 B-operand layout: no shuffle.
    u32x2 w0 = { cvtpk(p[0], p[1]), cvtpk(p[2], p[3]) };
    u32x2 w1 = { cvtpk(p[4], p[5]), cvtpk(p[6], p[7]) };
    s16x4 pf0 = __builtin_bit_cast(s16x4, w0);
    s16x4 pf1 = __builtin_bit_cast(s16x4, w1);

    // split interleaved V chunks: low 8B = f0 frag, high 8B = f1 frag
    s16x4 a0 = __builtin_shufflevector(R.v0, R.v0, 0, 1, 2, 3);
    s16x4 b0 = __builtin_shufflevector(R.v0, R.v0, 4, 5, 6, 7);
    s16x4 a1 = __builtin_shufflevector(R.v1, R.v1, 0, 1, 2, 3);
    s16x4 b1 = __builtin_shufflevector(R.v1, R.v1, 4, 5, 6, 7);
    s16x4 a2 = __builtin_shufflevector(R.v2, R.v2, 0, 1, 2, 3);
    s16x4 b2 = __builtin_shufflevector(R.v2, R.v2, 4, 5, 6, 7);
    s16x4 a3 = __builtin_shufflevector(R.v3, R.v3, 0, 1, 2, 3);
    s16x4 b3 = __builtin_shufflevector(R.v3, R.v3, 4, 5, 6, 7);

    __builtin_amdgcn_s_setprio(1);
    ctx[0] = MFMA16(a0, pf0, ctx[0]);
    ctx[1] = MFMA16(a1, pf0, ctx[1]);
    ctx[2] = MFMA16(a2, pf0, ctx[2]);
    ctx[3] = MFMA16(a3, pf0, ctx[3]);
    ctx[0] = MFMA16(b0, pf1, ctx[0]);
    ctx[1] = MFMA16(b1, pf1, ctx[1]);
    ctx[2] = MFMA16(b2, pf1, ctx[2]);
    ctx[3] = MFMA16(b3, pf1, ctx[3]);
    __builtin_amdgcn_s_setprio(0);
}

__global__ __launch_bounds__(256, 3)
void attn_mfma(const short* __restrict__ Qb, const short* __restrict__ Kb,
               const short* __restrict__ Vtb, const short* __restrict__ relkb,
               const short* __restrict__ relvTb, const float* __restrict__ relv_f32,
               const float* __restrict__ mask, short* __restrict__ CTXb)
{
    __shared__ __align__(16) short sK[2][32 * 64];     // [sub], single tile, swizzled (8KB)
    __shared__ __align__(16) short sV[2][64 * 32];     // [sub], k-interleaved (8KB)
    __shared__ __align__(16) short sMaskP[1024 + 32];  // bf16 mask * -1e9 (2.1KB)
    __shared__ __align__(16) short sQrel[4][16][144];  // bf16 Qrel[q][r] (18.4KB)
    __shared__ __align__(16) short sBand[4][16][128];  // bf16 band weights (16KB)

    const int tid = threadIdx.x;
    const int w = tid >> 6, lane = tid & 63;
    const int lo16 = lane & 15, hi = lane >> 4;

    // XCD-aware swizzle (1024 = 8*128, bijective); same-bh blocks share an XCD L2
    const int p = blockIdx.x;
    const int bid = (p & 7) * 128 + (p >> 3);
    const int bh = bid >> 4;
    const int qt = bid & 15;
    const int b = bh >> 4, h = bh & 15;
    const int q0 = qt * 64 + w * 16;
    const int q_abs = q0 + lo16;

    const short* Kbase = Kb + (size_t)bh * 65536;
    const short* Vtbase = Vtb + (size_t)bh * 65536;

    // staging geometry (per thread, 1x16B per async op)
    const int skr = tid >> 3, skc = tid & 7;             // K: row 0..31, chunk 0..7
    const int svd = tid >> 2, svc = tid & 3;             // V: row d 0..63, chunk 0..3
    const short* ksrc = Kbase + (size_t)skr * 64 + ((skc ^ (skr & 7)) << 3);
    const short* vsrc = Vtbase + (size_t)svd * 1024 + svc * 8;   // interleave is in global layout

    // stage tile 0 (both 32-k subs)
    async_copy16((char*)&sK[0][0] + tid * 16, ksrc);
    async_copy16((char*)&sK[1][0] + tid * 16, ksrc + 32 * 64);
    async_copy16((char*)&sV[0][0] + tid * 16, vsrc);
    async_copy16((char*)&sV[1][0] + tid * 16, vsrc + 32);

    // persistent Q fragments (B-operand: col = q = lane&15, depth = hi*8+j)
    const short* qptr = Qb + ((size_t)bh * 1024 + q_abs) * 64 + hi * 8;
    const s16x8 qB0 = *(const s16x8*)qptr;
    const s16x8 qB1 = *(const s16x8*)(qptr + 32);

    // init shared: maskP (block-wide), sBand zero (per-wave region)
    {
        float4 mv = *(const float4*)&mask[b * 1024 + tid * 4];
        s16x4 mp = { f2bf(mv.x * -1e9f), f2bf(mv.y * -1e9f),
                     f2bf(mv.z * -1e9f), f2bf(mv.w * -1e9f) };
        *(s16x4*)&sMaskP[tid * 4] = mp;
        if (tid < 8) *(s16x4*)&sMaskP[1024 + tid * 4] = s16x4{0, 0, 0, 0};
    }
    {
        u32* bz = (u32*)&sBand[w][0][0];   // 16*128 shorts = 1024 u32 per wave
#pragma unroll
        for (int i = 0; i < 16; ++i) bz[lane + i * 64] = 0u;
    }

    // Qrel^T = relk @ Q^T : 9 r-frags -> sQrel[w][q][r] (bf16)
#pragma unroll
    for (int rf = 0; rf < 9; ++rf) {
        const short* rp = relkb + (size_t)(rf * 16 + lo16) * 64 + hi * 8;
        s16x8 rA0 = *(const s16x8*)rp;
        s16x8 rA1 = *(const s16x8*)(rp + 32);
        f32x4 dq = {0.f, 0.f, 0.f, 0.f};
        dq = MFMA(rA0, qB0, dq);
        dq = MFMA(rA1, qB1, dq);
        s16x4 pk = { f2bf(dq[0]), f2bf(dq[1]), f2bf(dq[2]), f2bf(dq[3]) };
        *(s16x4*)&sQrel[w][lo16][rf * 16 + hi * 4] = pk;
    }
    __syncthreads();   // drains tile-0 staging; fences sMaskP/sQrel (= barrier 2 of iter -1)

    const float qrel_lo = bf2f(sQrel[w][lo16][0]);
    const float qrel_hi = bf2f(sQrel[w][lo16][128]);

    f32x4 ctx[4] = {};
    float lsum = 0.f, lov = 0.f, hiv = 0.f;

    TileRegs R0, R1;
    for (int t = 0; t < 16; ++t) {
        // phase A: whole tile t LDS -> regs (fence below forces them live)
        prefetch_tile(sK[0], sV[0], sMaskP, t * 64,      lo16, hi, R0);
        prefetch_tile(sK[1], sV[1], sMaskP, t * 64 + 32, lo16, hi, R1);
        __syncthreads();   // barrier 1: all waves done reading the buffer
        // stage tile t+1 into the same (single) buffer; drains at barrier 2
        const int kb = ((t + 1) & 15) * 64;     // wrapped at t=15 (dead data)
        async_copy16((char*)&sK[0][0] + tid * 16, ksrc + (size_t)kb * 64);
        async_copy16((char*)&sK[1][0] + tid * 16, ksrc + (size_t)(kb + 32) * 64);
        async_copy16((char*)&sV[0][0] + tid * 16, vsrc + kb);
        async_copy16((char*)&sV[1][0] + tid * 16, vsrc + kb + 32);
        // compute tile t from registers (covers the staging latency)
        process32(t * 64,      q0, q_abs, lo16, hi, R0, qB0, qB1, qrel_lo, qrel_hi,
                  sQrel[w], sBand[w], ctx, lsum, lov, hiv);
        process32(t * 64 + 32, q0, q_abs, lo16, hi, R1, qB0, qB1, qrel_lo, qrel_hi,
                  sQrel[w], sBand[w], ctx, lsum, lov, hiv);
        __syncthreads();   // barrier 2: staging (vmcnt) complete for all waves
    }

    // band rel_v contribution: ctx^T += relvT-frag x sBand-frag (unnormalized)
#pragma unroll
    for (int ks = 0; ks < 4; ++ks) {
        s16x8 bB = *(const s16x8*)&sBand[w][lo16][ks * 32 + hi * 8];
#pragma unroll
        for (int df = 0; df < 4; ++df) {
            s16x8 rA = *(const s16x8*)(relvTb + (size_t)(df * 16 + lo16) * 128 + ks * 32 + hi * 8);
            ctx[df] = MFMA(rA, bB, ctx[df]);
        }
    }

    // reduce per-q stats across the 4 hi-groups
    lsum += __shfl_xor(lsum, 16); lsum += __shfl_xor(lsum, 32);
    lov  += __shfl_xor(lov, 16);  lov  += __shfl_xor(lov, 32);
    hiv  += __shfl_xor(hiv, 16);  hiv  += __shfl_xor(hiv, 32);
    const float inv = 1.0f / lsum;

    // tails (clipped buckets 0 / 128) + normalize + store bf16 ctx
#pragma unroll
    for (int df = 0; df < 4; ++df) {
        s16x4 pk;
#pragma unroll
        for (int r = 0; r < 4; ++r) {
            int d = df * 16 + hi * 4 + r;
            float t = ctx[df][r] + lov * relv_f32[d] + hiv * relv_f32[128 * 64 + d];
            pk[r] = f2bf(t * inv);
        }
        *(s16x4*)(CTXb + ((size_t)(b * 1024) + q_abs) * 1024 + h * 64 + df * 16 + hi * 4) = pk;
    }
}

// ---------------------------------------------------------------------------
// Output GEMM v2: out[4096,1024] = CTXb @ wo + bo (fp32). 128x128 tile
// (gemm_qkv structure), XCD-swizzled 1D grid (256 blocks).
// ---------------------------------------------------------------------------
__global__ __launch_bounds__(256)
void gemm_out(const short* __restrict__ Ab, const short* __restrict__ Wto,
              const float* __restrict__ bo, float* __restrict__ out)
{
    __shared__ __align__(16) short As[128 * 64];
    __shared__ __align__(16) short Bs[128 * 64];
    const int tid = threadIdx.x;
    const int w = tid >> 6, lane = tid & 63;
    const int lo16 = lane & 15, hi = lane >> 4;
    // XCD swizzle: 256 blocks % 8 == 0 -> bijective; same-XCD blocks share m-panel
    const int pb = blockIdx.x;
    const int wg = (pb & 7) * 32 + (pb >> 3);
    const int n0 = (wg & 7) * 128;     // 8 n-tiles
    const int m0 = (wg >> 3) * 128;    // 32 m-tiles
    const int wr = w >> 1, wc = w & 1;

    f32x4 acc[4][4] = {};

    for (int t = 0; t < 16; ++t) {
        const int k0 = t * 64;
        __syncthreads();
#pragma unroll
        for (int i = 0; i < 4; ++i) {
            int o = i * 4096 + tid * 16;
            int row = o >> 7;
            int cb = o & 127;
            int sc = cb ^ ((row & 7) << 4);
            async_copy16((char*)As + o, Ab + (size_t)(m0 + row) * 1024 + k0 + (sc >> 1));
            async_copy16((char*)Bs + o, Wto + (size_t)(n0 + row) * 1024 + k0 + (sc >> 1));
        }
        __syncthreads();
#pragma unroll
        for (int ks = 0; ks < 2; ++ks) {
            s16x8 aF[4], bF[4];
#pragma unroll
            for (int mi = 0; mi < 4; ++mi) {
                int row = wr * 64 + mi * 16 + lo16;
                int cb = ks * 64 + hi * 16;
                aF[mi] = *(const s16x8*)((const char*)As + row * 128 + (cb ^ ((row & 7) << 4)));
            }
#pragma unroll
            for (int ni = 0; ni < 4; ++ni) {
                int row = wc * 64 + ni * 16 + lo16;
                int cb = ks * 64 + hi * 16;
                bF[ni] = *(const s16x8*)((const char*)Bs + row * 128 + (cb ^ ((row & 7) << 4)));
            }
#pragma unroll
            for (int mi = 0; mi < 4; ++mi)
#pragma unroll
                for (int ni = 0; ni < 4; ++ni)
                    acc[mi][ni] = MFMA(aF[mi], bF[ni], acc[mi][ni]);
        }
    }

    float bv4[4];
#pragma unroll
    for (int ni = 0; ni < 4; ++ni) bv4[ni] = bo[n0 + wc * 64 + ni * 16 + lo16];
#pragma unroll
    for (int mi = 0; mi < 4; ++mi)
#pragma unroll
        for (int ni = 0; ni < 4; ++ni) {
            int n = n0 + wc * 64 + ni * 16 + lo16;
#pragma unroll
            for (int r = 0; r < 4; ++r) {
                int m = m0 + wr * 64 + mi * 16 + hi * 4 + r;
                out[(size_t)m * 1024 + n] = acc[mi][ni][r] + bv4[ni];
            }
        }
}

// ---------------------------------------------------------------------------
extern "C" void kernel_launch(void* const* d_in, const int* in_sizes, int n_in,
                              void* d_out, int out_size, void* d_ws, size_t ws_size,
                              hipStream_t stream)
{
    (void)in_sizes; (void)n_in; (void)out_size; (void)ws_size;
    const float* x    = (const float*)d_in[0];
    const float* mask = (const float*)d_in[1];
    const float* wq   = (const float*)d_in[2];
    const float* bq   = (const float*)d_in[3];
    const float* wk   = (const float*)d_in[4];
    const float* bk   = (const float*)d_in[5];
    const float* wv   = (const float*)d_in[6];
    const float* bv   = (const float*)d_in[7];
    const float* wo   = (const float*)d_in[8];
    const float* bo   = (const float*)d_in[9];
    const float* relk = (const float*)d_in[10];
    const float* relv = (const float*)d_in[11];
    float* out = (float*)d_out;

    char* p = (char*)d_ws;
    short* xb    = (short*)p; p += (size_t)4096 * 1024 * 2;     // 8 MB
    short* Wtqkv = (short*)p; p += (size_t)3072 * 1024 * 2;     // 6 MB
    short* Wto   = (short*)p; p += (size_t)1024 * 1024 * 2;     // 2 MB
    short* Qb    = (short*)p; p += (size_t)4096 * 1024 * 2;     // 8 MB
    short* Kb    = (short*)p; p += (size_t)4096 * 1024 * 2;     // 8 MB
    short* Vtb   = (short*)p; p += (size_t)4096 * 1024 * 2;     // 8 MB
    short* CTXb  = (short*)p; p += (size_t)4096 * 1024 * 2;     // 8 MB
    short* relkb = (short*)p; p += (size_t)144 * 64 * 2;
    short* relvT = (short*)p; p += (size_t)64 * 128 * 2;

    cast_x       <<<2048, 256, 0, stream>>>(x, xb);
    transpose_w  <<<dim3(16, 16, 4), 256, 0, stream>>>(wq, wk, wv, wo, Wtqkv, Wto);
    prep_tables  <<<8, 256, 0, stream>>>(relk, relv, relkb, relvT);
    gemm_qkv     <<<768, 256, 0, stream>>>(xb, Wtqkv, bq, bk, bv, Qb, Kb, Vtb);
    attn_mfma    <<<1024, 256, 0, stream>>>(Qb, Kb, Vtb, relkb, relvT, relv, mask, CTXb);
    gemm_out     <<<256, 256, 0, stream>>>(CTXb, Wto, bo, out);
}

// Round 14
// 117.853 us; speedup vs baseline: 1.6736x; 1.1930x over previous
//
#include <hip/hip_runtime.h>
#include <hip/hip_bf16.h>
#include <cstdint>
#include <cstddef>

typedef unsigned int u32;
typedef __attribute__((ext_vector_type(8))) short s16x8;   // 8 bf16 (4 VGPR) MFMA A/B frag
typedef __attribute__((ext_vector_type(4))) short s16x4;   // 4 bf16, 8B pack
typedef __attribute__((ext_vector_type(4))) float f32x4;   // MFMA C/D frag
typedef __attribute__((ext_vector_type(2))) u32   u32x2;

#define MFMA(a,b,c) __builtin_amdgcn_mfma_f32_16x16x32_bf16(a,b,c,0,0,0)

#if __has_builtin(__builtin_amdgcn_mfma_f32_16x16x16bf16_1k)
#define MFMA16(a,b,c) __builtin_amdgcn_mfma_f32_16x16x16bf16_1k(a,b,c,0,0,0)
#else
static __device__ __forceinline__ f32x4 MFMA16(s16x4 a, s16x4 b, f32x4 c){
    f32x4 d;
    asm("v_mfma_f32_16x16x16_bf16 %0, %1, %2, %3"
        : "=v"(d) : "v"(a), "v"(b), "v"(c));
    return d;
}
#endif

__device__ __forceinline__ short f2bf(float f) {
    u32 u = __builtin_bit_cast(u32, f);
    u32 r = (u + 0x7fffu + ((u >> 16) & 1u)) >> 16;   // RNE
    return (short)r;
}
__device__ __forceinline__ float bf2f(short s) {
    return __builtin_bit_cast(float, ((u32)(unsigned short)s) << 16);
}
__device__ __forceinline__ u32 cvtpk(float lo, float hi) {
    u32 r;
    asm("v_cvt_pk_bf16_f32 %0, %1, %2" : "=v"(r) : "v"(lo), "v"(hi));
    return r;
}
__device__ __forceinline__ void async_copy16(void* lds, const void* g) {
    __builtin_amdgcn_global_load_lds((const __attribute__((address_space(1))) u32*)g,
                                     (__attribute__((address_space(3))) u32*)lds, 16, 0, 0);
}

// ---------------------------------------------------------------------------
// prep_all: fused {cast_x | transpose_w | prep_tables} — mutually independent
// producers for gemm_qkv. Block ranges: [0,2048) cast, [2048,3072) transpose,
// [3072,3080) tables.
// ---------------------------------------------------------------------------
__global__ __launch_bounds__(256)
void prep_all(const float* __restrict__ x, short* __restrict__ xb,
              const float* __restrict__ wq, const float* __restrict__ wk,
              const float* __restrict__ wv, const float* __restrict__ wo,
              short* __restrict__ Wtqkv, short* __restrict__ Wto,
              const float* __restrict__ relk, const float* __restrict__ relv,
              short* __restrict__ relkb, short* __restrict__ relvT)
{
    __shared__ float sT[64][68];
    const int bid = blockIdx.x;
    const int tid = threadIdx.x;

    if (bid < 2048) {
        // cast x (fp32 -> bf16), 8 elems/thread
        int i = (bid * 256 + tid) * 8;
        float4 a = *(const float4*)&x[i];
        float4 b = *(const float4*)&x[i + 4];
        s16x8 v = { f2bf(a.x), f2bf(a.y), f2bf(a.z), f2bf(a.w),
                    f2bf(b.x), f2bf(b.y), f2bf(b.z), f2bf(b.w) };
        *(s16x8*)&xb[i] = v;
    } else if (bid < 3072) {
        // transpose + cast weights
        const int wid = bid - 2048;
        const int kt = wid & 15, nt = (wid >> 4) & 15, seg = wid >> 8;
        const float* src = seg == 0 ? wq : seg == 1 ? wk : seg == 2 ? wv : wo;
        const int k0 = kt * 64, n0 = nt * 64;
#pragma unroll
        for (int i = 0; i < 4; ++i) {
            int t2 = tid + i * 256;          // 0..1023 -> 64 rows x 16 float4
            int r = t2 >> 4, c4 = t2 & 15;
            *(float4*)&sT[r][c4 * 4] = *(const float4*)&src[(size_t)(k0 + r) * 1024 + n0 + c4 * 4];
        }
        __syncthreads();
#pragma unroll
        for (int i = 0; i < 2; ++i) {
            int t2 = tid + i * 256;
            int rn = t2 >> 3, ch = t2 & 7;
            s16x8 v;
#pragma unroll
            for (int j = 0; j < 8; ++j) v[j] = f2bf(sT[ch * 8 + j][rn]);
            if (seg < 3)
                *(s16x8*)&Wtqkv[(size_t)(seg * 1024 + n0 + rn) * 1024 + k0 + ch * 8] = v;
            else
                *(s16x8*)&Wto[(size_t)(n0 + rn) * 1024 + k0 + ch * 8] = v;
        }
    } else {
        // rel tables (8 blocks, grid-strided)
        int gt = (bid - 3072) * 256 + tid;
        for (int i = gt; i < 144 * 64; i += 256 * 8) {
            int r = i >> 6, d = i & 63;
            relkb[i] = (r < 129) ? f2bf(relk[r * 64 + d]) : (short)0;
        }
        for (int i = gt; i < 64 * 128; i += 256 * 8) {
            int d = i >> 7, r = i & 127;
            relvT[i] = f2bf(relv[r * 64 + d]);
        }
    }
}

// ---------------------------------------------------------------------------
// Fused QKV GEMM (XCD-swizzled 1D grid, 768 blocks, 4 waves/SIMD bound);
// V segment stores TRANSPOSED + k-interleaved:
// col(k) = (k>>5)*32 + (k&3)+(((k>>4)&1)<<2)+(((k>>2)&3)<<3)
// ---------------------------------------------------------------------------
__global__ __launch_bounds__(256, 4)
void gemm_qkv(const short* __restrict__ Ab, const short* __restrict__ Wt,
              const float* __restrict__ bq, const float* __restrict__ bk,
              const float* __restrict__ bv,
              short* __restrict__ Qb, short* __restrict__ Kb, short* __restrict__ Vtb)
{
    __shared__ __align__(16) short As[128 * 64];
    __shared__ __align__(16) short Bs[128 * 64];
    const int tid = threadIdx.x;
    const int w = tid >> 6, lane = tid & 63;
    const int lo16 = lane & 15, hi = lane >> 4;
    // XCD swizzle: 768 blocks % 8 == 0 -> bijective; same-XCD blocks share m-panel
    const int pb = blockIdx.x;
    const int wg = (pb & 7) * 96 + (pb >> 3);
    const int n0g = (wg % 24) * 128;
    const int m0 = (wg / 24) * 128;
    const int wr = w >> 1, wc = w & 1;

    f32x4 acc[4][4] = {};

    for (int t = 0; t < 16; ++t) {
        const int k0 = t * 64;
        __syncthreads();
#pragma unroll
        for (int i = 0; i < 4; ++i) {
            int o = i * 4096 + tid * 16;
            int row = o >> 7;
            int cb = o & 127;
            int sc = cb ^ ((row & 7) << 4);
            async_copy16((char*)As + o, Ab + (size_t)(m0 + row) * 1024 + k0 + (sc >> 1));
            async_copy16((char*)Bs + o, Wt + (size_t)(n0g + row) * 1024 + k0 + (sc >> 1));
        }
        __syncthreads();
#pragma unroll
        for (int ks = 0; ks < 2; ++ks) {
            s16x8 aF[4], bF[4];
#pragma unroll
            for (int mi = 0; mi < 4; ++mi) {
                int row = wr * 64 + mi * 16 + lo16;
                int cb = ks * 64 + hi * 16;
                aF[mi] = *(const s16x8*)((const char*)As + row * 128 + (cb ^ ((row & 7) << 4)));
            }
#pragma unroll
            for (int ni = 0; ni < 4; ++ni) {
                int row = wc * 64 + ni * 16 + lo16;
                int cb = ks * 64 + hi * 16;
                bF[ni] = *(const s16x8*)((const char*)Bs + row * 128 + (cb ^ ((row & 7) << 4)));
            }
#pragma unroll
            for (int mi = 0; mi < 4; ++mi)
#pragma unroll
                for (int ni = 0; ni < 4; ++ni)
                    acc[mi][ni] = MFMA(aF[mi], bF[ni], acc[mi][ni]);
        }
    }

    const int seg = n0g >> 10;
    const int nn = n0g & 1023;
    const float* bias = seg == 0 ? bq : seg == 1 ? bk : bv;
    float bv4[4];
#pragma unroll
    for (int ni = 0; ni < 4; ++ni) bv4[ni] = bias[nn + wc * 64 + ni * 16 + lo16];

    if (seg == 2) {
        // V: store transposed + interleaved, 4 consecutive l per thread -> 8B stores
#pragma unroll
        for (int mi = 0; mi < 4; ++mi)
#pragma unroll
            for (int ni = 0; ni < 4; ++ni) {
                int nl = nn + wc * 64 + ni * 16 + lo16;
                int hh = nl >> 6, d = nl & 63;
                int mbase = m0 + wr * 64 + mi * 16 + hi * 4;
                int bb = mbase >> 10, l0 = mbase & 1023;
                int j0 = l0 & 31;                          // j0 % 4 == 0
                int col = (l0 >> 5) * 32 + (((j0 >> 4) & 1) << 2) + (((j0 >> 2) & 3) << 3);
                s16x4 pk = { f2bf(acc[mi][ni][0] + bv4[ni]),
                             f2bf(acc[mi][ni][1] + bv4[ni]),
                             f2bf(acc[mi][ni][2] + bv4[ni]),
                             f2bf(acc[mi][ni][3] + bv4[ni]) };
                *(s16x4*)&Vtb[((size_t)(bb * 16 + hh) * 64 + d) * 1024 + col] = pk;
            }
    } else {
        short* out = seg == 0 ? Qb : Kb;
#pragma unroll
        for (int mi = 0; mi < 4; ++mi)
#pragma unroll
            for (int ni = 0; ni < 4; ++ni) {
                int nl = nn + wc * 64 + ni * 16 + lo16;
                int hh = nl >> 6, d = nl & 63;
#pragma unroll
                for (int r = 0; r < 4; ++r) {
                    int m = m0 + wr * 64 + mi * 16 + hi * 4 + r;
                    int bb = m >> 10, l = m & 1023;
                    out[(((size_t)bb * 16 + hh) * 1024 + l) * 64 + d] = f2bf(acc[mi][ni][r] + bv4[ni]);
                }
            }
    }
}

// ---------------------------------------------------------------------------
// Flash attention v9 (UNCHANGED — passing, 64.4us): single-buffered K+V LDS
// tile, 3 blocks/CU, __syncthreads-only sync.
// ---------------------------------------------------------------------------
struct TileRegs {
    s16x8 k0, k1, k2, k3;    // K frags (QK A-operand)
    s16x8 v0, v1, v2, v3;    // V frags (two 8B PV A-frags packed per 16B)
    s16x4 m0, m1;            // mask bias
};

__device__ __forceinline__ void prefetch_tile(
    const short* __restrict__ sKc, const short* __restrict__ sVc,
    const short* __restrict__ sMaskP, int kfm, int lo16, int hi, TileRegs& R)
{
    const int km = lo16 & 7;
    R.k0 = *(const s16x8*)(sKc + lo16 * 64 + ((hi ^ km) << 3));
    R.k1 = *(const s16x8*)(sKc + lo16 * 64 + (((hi + 4) ^ km) << 3));
    R.k2 = *(const s16x8*)(sKc + (lo16 + 16) * 64 + ((hi ^ km) << 3));
    R.k3 = *(const s16x8*)(sKc + (lo16 + 16) * 64 + (((hi + 4) ^ km) << 3));
    R.v0 = *(const s16x8*)(sVc + lo16 * 32 + hi * 8);
    R.v1 = *(const s16x8*)(sVc + (16 + lo16) * 32 + hi * 8);
    R.v2 = *(const s16x8*)(sVc + (32 + lo16) * 32 + hi * 8);
    R.v3 = *(const s16x8*)(sVc + (48 + lo16) * 32 + hi * 8);
    R.m0 = *(const s16x4*)&sMaskP[kfm + hi * 4];
    R.m1 = *(const s16x4*)&sMaskP[kfm + 16 + hi * 4];
}

__device__ __forceinline__ void process32(
    int kf, int q0, int q_abs, int lo16, int hi,
    const TileRegs& R,
    const s16x8& qB0, const s16x8& qB1,
    float qrel_lo, float qrel_hi,
    const short (*sQrelw)[144], short (*sBandw)[128],
    f32x4* ctx, float& lsum, float& lov, float& hiv)
{
    const f32x4 z = {0.f, 0.f, 0.f, 0.f};
    __builtin_amdgcn_s_setprio(1);
    f32x4 sa = MFMA(R.k0, qB0, z);
    f32x4 sb = MFMA(R.k1, qB1, z);
    f32x4 sc = MFMA(R.k2, qB0, z);
    f32x4 sd = MFMA(R.k3, qB1, z);
    __builtin_amdgcn_s_setprio(0);
    f32x4 s0 = sa + sb, s1 = sc + sd;

    float p[8];
    if (kf + 95 <= q0 || kf >= q0 + 79) {
        // whole block out of band: rel uniform 0 or 128
        const float qc = (kf < q0) ? qrel_lo : qrel_hi;
        float bs = 0.f;
#pragma unroll
        for (int r = 0; r < 4; ++r) {
            p[r]     = __expf(s0[r] + qc + bf2f(R.m0[r]));
            p[4 + r] = __expf(s1[r] + qc + bf2f(R.m1[r]));
        }
#pragma unroll
        for (int r = 0; r < 8; ++r) bs += p[r];
        lsum += bs;
        if (kf < q0) lov += bs; else hiv += bs;
    } else {
#pragma unroll
        for (int f = 0; f < 2; ++f)
#pragma unroll
            for (int r = 0; r < 4; ++r) {
                int k_abs = kf + f * 16 + hi * 4 + r;
                int dd = k_abs - q_abs;
                dd = dd < -64 ? -64 : (dd > 64 ? 64 : dd);
                int rel = dd + 64;
                float sv = f ? s1[r] : s0[r];
                float mv = bf2f(f ? R.m1[r] : R.m0[r]);
                float pex = __expf(sv + bf2f(sQrelw[lo16][rel]) + mv);
                p[f * 4 + r] = pex;
                lsum += pex;
                if (rel >= 1 && rel <= 127) sBandw[lo16][rel] = f2bf(pex);
                else if (rel == 0) lov += pex;
                else hiv += pex;
            }
    }

    // S-frag (col=q=lo16, k=hi*4+r) IS the 16x16x16 B-operand layout: no shuffle.
    u32x2 w0 = { cvtpk(p[0], p[1]), cvtpk(p[2], p[3]) };
    u32x2 w1 = { cvtpk(p[4], p[5]), cvtpk(p[6], p[7]) };
    s16x4 pf0 = __builtin_bit_cast(s16x4, w0);
    s16x4 pf1 = __builtin_bit_cast(s16x4, w1);

    // split interleaved V chunks: low 8B = f0 frag, high 8B = f1 frag
    s16x4 a0 = __builtin_shufflevector(R.v0, R.v0, 0, 1, 2, 3);
    s16x4 b0 = __builtin_shufflevector(R.v0, R.v0, 4, 5, 6, 7);
    s16x4 a1 = __builtin_shufflevector(R.v1, R.v1, 0, 1, 2, 3);
    s16x4 b1 = __builtin_shufflevector(R.v1, R.v1, 4, 5, 6, 7);
    s16x4 a2 = __builtin_shufflevector(R.v2, R.v2, 0, 1, 2, 3);
    s16x4 b2 = __builtin_shufflevector(R.v2, R.v2, 4, 5, 6, 7);
    s16x4 a3 = __builtin_shufflevector(R.v3, R.v3, 0, 1, 2, 3);
    s16x4 b3 = __builtin_shufflevector(R.v3, R.v3, 4, 5, 6, 7);

    __builtin_amdgcn_s_setprio(1);
    ctx[0] = MFMA16(a0, pf0, ctx[0]);
    ctx[1] = MFMA16(a1, pf0, ctx[1]);
    ctx[2] = MFMA16(a2, pf0, ctx[2]);
    ctx[3] = MFMA16(a3, pf0, ctx[3]);
    ctx[0] = MFMA16(b0, pf1, ctx[0]);
    ctx[1] = MFMA16(b1, pf1, ctx[1]);
    ctx[2] = MFMA16(b2, pf1, ctx[2]);
    ctx[3] = MFMA16(b3, pf1, ctx[3]);
    __builtin_amdgcn_s_setprio(0);
}

__global__ __launch_bounds__(256, 3)
void attn_mfma(const short* __restrict__ Qb, const short* __restrict__ Kb,
               const short* __restrict__ Vtb, const short* __restrict__ relkb,
               const short* __restrict__ relvTb, const float* __restrict__ relv_f32,
               const float* __restrict__ mask, short* __restrict__ CTXb)
{
    __shared__ __align__(16) short sK[2][32 * 64];     // [sub], single tile, swizzled (8KB)
    __shared__ __align__(16) short sV[2][64 * 32];     // [sub], k-interleaved (8KB)
    __shared__ __align__(16) short sMaskP[1024 + 32];  // bf16 mask * -1e9 (2.1KB)
    __shared__ __align__(16) short sQrel[4][16][144];  // bf16 Qrel[q][r] (18.4KB)
    __shared__ __align__(16) short sBand[4][16][128];  // bf16 band weights (16KB)

    const int tid = threadIdx.x;
    const int w = tid >> 6, lane = tid & 63;
    const int lo16 = lane & 15, hi = lane >> 4;

    // XCD-aware swizzle (1024 = 8*128, bijective); same-bh blocks share an XCD L2
    const int p = blockIdx.x;
    const int bid = (p & 7) * 128 + (p >> 3);
    const int bh = bid >> 4;
    const int qt = bid & 15;
    const int b = bh >> 4, h = bh & 15;
    const int q0 = qt * 64 + w * 16;
    const int q_abs = q0 + lo16;

    const short* Kbase = Kb + (size_t)bh * 65536;
    const short* Vtbase = Vtb + (size_t)bh * 65536;

    // staging geometry (per thread, 1x16B per async op)
    const int skr = tid >> 3, skc = tid & 7;             // K: row 0..31, chunk 0..7
    const int svd = tid >> 2, svc = tid & 3;             // V: row d 0..63, chunk 0..3
    const short* ksrc = Kbase + (size_t)skr * 64 + ((skc ^ (skr & 7)) << 3);
    const short* vsrc = Vtbase + (size_t)svd * 1024 + svc * 8;   // interleave is in global layout

    // stage tile 0 (both 32-k subs)
    async_copy16((char*)&sK[0][0] + tid * 16, ksrc);
    async_copy16((char*)&sK[1][0] + tid * 16, ksrc + 32 * 64);
    async_copy16((char*)&sV[0][0] + tid * 16, vsrc);
    async_copy16((char*)&sV[1][0] + tid * 16, vsrc + 32);

    // persistent Q fragments (B-operand: col = q = lane&15, depth = hi*8+j)
    const short* qptr = Qb + ((size_t)bh * 1024 + q_abs) * 64 + hi * 8;
    const s16x8 qB0 = *(const s16x8*)qptr;
    const s16x8 qB1 = *(const s16x8*)(qptr + 32);

    // init shared: maskP (block-wide), sBand zero (per-wave region)
    {
        float4 mv = *(const float4*)&mask[b * 1024 + tid * 4];
        s16x4 mp = { f2bf(mv.x * -1e9f), f2bf(mv.y * -1e9f),
                     f2bf(mv.z * -1e9f), f2bf(mv.w * -1e9f) };
        *(s16x4*)&sMaskP[tid * 4] = mp;
        if (tid < 8) *(s16x4*)&sMaskP[1024 + tid * 4] = s16x4{0, 0, 0, 0};
    }
    {
        u32* bz = (u32*)&sBand[w][0][0];   // 16*128 shorts = 1024 u32 per wave
#pragma unroll
        for (int i = 0; i < 16; ++i) bz[lane + i * 64] = 0u;
    }

    // Qrel^T = relk @ Q^T : 9 r-frags -> sQrel[w][q][r] (bf16)
#pragma unroll
    for (int rf = 0; rf < 9; ++rf) {
        const short* rp = relkb + (size_t)(rf * 16 + lo16) * 64 + hi * 8;
        s16x8 rA0 = *(const s16x8*)rp;
        s16x8 rA1 = *(const s16x8*)(rp + 32);
        f32x4 dq = {0.f, 0.f, 0.f, 0.f};
        dq = MFMA(rA0, qB0, dq);
        dq = MFMA(rA1, qB1, dq);
        s16x4 pk = { f2bf(dq[0]), f2bf(dq[1]), f2bf(dq[2]), f2bf(dq[3]) };
        *(s16x4*)&sQrel[w][lo16][rf * 16 + hi * 4] = pk;
    }
    __syncthreads();   // drains tile-0 staging; fences sMaskP/sQrel (= barrier 2 of iter -1)

    const float qrel_lo = bf2f(sQrel[w][lo16][0]);
    const float qrel_hi = bf2f(sQrel[w][lo16][128]);

    f32x4 ctx[4] = {};
    float lsum = 0.f, lov = 0.f, hiv = 0.f;

    TileRegs R0, R1;
    for (int t = 0; t < 16; ++t) {
        // phase A: whole tile t LDS -> regs (fence below forces them live)
        prefetch_tile(sK[0], sV[0], sMaskP, t * 64,      lo16, hi, R0);
        prefetch_tile(sK[1], sV[1], sMaskP, t * 64 + 32, lo16, hi, R1);
        __syncthreads();   // barrier 1: all waves done reading the buffer
        // stage tile t+1 into the same (single) buffer; drains at barrier 2
        const int kb = ((t + 1) & 15) * 64;     // wrapped at t=15 (dead data)
        async_copy16((char*)&sK[0][0] + tid * 16, ksrc + (size_t)kb * 64);
        async_copy16((char*)&sK[1][0] + tid * 16, ksrc + (size_t)(kb + 32) * 64);
        async_copy16((char*)&sV[0][0] + tid * 16, vsrc + kb);
        async_copy16((char*)&sV[1][0] + tid * 16, vsrc + kb + 32);
        // compute tile t from registers (covers the staging latency)
        process32(t * 64,      q0, q_abs, lo16, hi, R0, qB0, qB1, qrel_lo, qrel_hi,
                  sQrel[w], sBand[w], ctx, lsum, lov, hiv);
        process32(t * 64 + 32, q0, q_abs, lo16, hi, R1, qB0, qB1, qrel_lo, qrel_hi,
                  sQrel[w], sBand[w], ctx, lsum, lov, hiv);
        __syncthreads();   // barrier 2: staging (vmcnt) complete for all waves
    }

    // band rel_v contribution: ctx^T += relvT-frag x sBand-frag (unnormalized)
#pragma unroll
    for (int ks = 0; ks < 4; ++ks) {
        s16x8 bB = *(const s16x8*)&sBand[w][lo16][ks * 32 + hi * 8];
#pragma unroll
        for (int df = 0; df < 4; ++df) {
            s16x8 rA = *(const s16x8*)(relvTb + (size_t)(df * 16 + lo16) * 128 + ks * 32 + hi * 8);
            ctx[df] = MFMA(rA, bB, ctx[df]);
        }
    }

    // reduce per-q stats across the 4 hi-groups
    lsum += __shfl_xor(lsum, 16); lsum += __shfl_xor(lsum, 32);
    lov  += __shfl_xor(lov, 16);  lov  += __shfl_xor(lov, 32);
    hiv  += __shfl_xor(hiv, 16);  hiv  += __shfl_xor(hiv, 32);
    const float inv = 1.0f / lsum;

    // tails (clipped buckets 0 / 128) + normalize + store bf16 ctx
#pragma unroll
    for (int df = 0; df < 4; ++df) {
        s16x4 pk;
#pragma unroll
        for (int r = 0; r < 4; ++r) {
            int d = df * 16 + hi * 4 + r;
            float t = ctx[df][r] + lov * relv_f32[d] + hiv * relv_f32[128 * 64 + d];
            pk[r] = f2bf(t * inv);
        }
        *(s16x4*)(CTXb + ((size_t)(b * 1024) + q_abs) * 1024 + h * 64 + df * 16 + hi * 4) = pk;
    }
}

// ---------------------------------------------------------------------------
// Output GEMM: 128x64 tile, 512 blocks (2/CU co-residency), XCD-swizzled.
// ---------------------------------------------------------------------------
__global__ __launch_bounds__(256, 4)
void gemm_out(const short* __restrict__ Ab, const short* __restrict__ Wto,
              const float* __restrict__ bo, float* __restrict__ out)
{
    __shared__ __align__(16) short As[128 * 64];
    __shared__ __align__(16) short Bs[64 * 64];
    const int tid = threadIdx.x;
    const int w = tid >> 6, lane = tid & 63;
    const int lo16 = lane & 15, hi = lane >> 4;
    // XCD swizzle: 512 % 8 == 0 -> bijective
    const int pb = blockIdx.x;
    const int wg = (pb & 7) * 64 + (pb >> 3);
    const int n0 = (wg & 15) * 64;     // 16 n-tiles
    const int m0 = (wg >> 4) * 128;    // 32 m-tiles
    const int wr = w;

    f32x4 acc[2][4] = {};

    for (int t = 0; t < 16; ++t) {
        const int k0 = t * 64;
        __syncthreads();
#pragma unroll
        for (int i = 0; i < 4; ++i) {
            int o = i * 4096 + tid * 16;
            int row = o >> 7;
            int cb = o & 127;
            int sc = cb ^ ((row & 7) << 4);
            async_copy16((char*)As + o, Ab + (size_t)(m0 + row) * 1024 + k0 + (sc >> 1));
        }
#pragma unroll
        for (int i = 0; i < 2; ++i) {
            int o = i * 4096 + tid * 16;
            int row = o >> 7;
            int cb = o & 127;
            int sc = cb ^ ((row & 7) << 4);
            async_copy16((char*)Bs + o, Wto + (size_t)(n0 + row) * 1024 + k0 + (sc >> 1));
        }
        __syncthreads();
#pragma unroll
        for (int ks = 0; ks < 2; ++ks) {
            s16x8 aF[2], bF[4];
#pragma unroll
            for (int mi = 0; mi < 2; ++mi) {
                int row = wr * 32 + mi * 16 + lo16;
                int cb = ks * 64 + hi * 16;
                aF[mi] = *(const s16x8*)((const char*)As + row * 128 + (cb ^ ((row & 7) << 4)));
            }
#pragma unroll
            for (int ni = 0; ni < 4; ++ni) {
                int row = ni * 16 + lo16;
                int cb = ks * 64 + hi * 16;
                bF[ni] = *(const s16x8*)((const char*)Bs + row * 128 + (cb ^ ((row & 7) << 4)));
            }
#pragma unroll
            for (int mi = 0; mi < 2; ++mi)
#pragma unroll
                for (int ni = 0; ni < 4; ++ni)
                    acc[mi][ni] = MFMA(aF[mi], bF[ni], acc[mi][ni]);
        }
    }

    float bv4[4];
#pragma unroll
    for (int ni = 0; ni < 4; ++ni) bv4[ni] = bo[n0 + ni * 16 + lo16];
#pragma unroll
    for (int mi = 0; mi < 2; ++mi)
#pragma unroll
        for (int ni = 0; ni < 4; ++ni)
#pragma unroll
            for (int r = 0; r < 4; ++r) {
                int m = m0 + wr * 32 + mi * 16 + hi * 4 + r;
                out[(size_t)m * 1024 + n0 + ni * 16 + lo16] = acc[mi][ni][r] + bv4[ni];
            }
}

// ---------------------------------------------------------------------------
extern "C" void kernel_launch(void* const* d_in, const int* in_sizes, int n_in,
                              void* d_out, int out_size, void* d_ws, size_t ws_size,
                              hipStream_t stream)
{
    (void)in_sizes; (void)n_in; (void)out_size; (void)ws_size;
    const float* x    = (const float*)d_in[0];
    const float* mask = (const float*)d_in[1];
    const float* wq   = (const float*)d_in[2];
    const float* bq   = (const float*)d_in[3];
    const float* wk   = (const float*)d_in[4];
    const float* bk   = (const float*)d_in[5];
    const float* wv   = (const float*)d_in[6];
    const float* bv   = (const float*)d_in[7];
    const float* wo   = (const float*)d_in[8];
    const float* bo   = (const float*)d_in[9];
    const float* relk = (const float*)d_in[10];
    const float* relv = (const float*)d_in[11];
    float* out = (float*)d_out;

    char* p = (char*)d_ws;
    short* xb    = (short*)p; p += (size_t)4096 * 1024 * 2;     // 8 MB
    short* Wtqkv = (short*)p; p += (size_t)3072 * 1024 * 2;     // 6 MB
    short* Wto   = (short*)p; p += (size_t)1024 * 1024 * 2;     // 2 MB
    short* Qb    = (short*)p; p += (size_t)4096 * 1024 * 2;     // 8 MB
    short* Kb    = (short*)p; p += (size_t)4096 * 1024 * 2;     // 8 MB
    short* Vtb   = (short*)p; p += (size_t)4096 * 1024 * 2;     // 8 MB
    short* CTXb  = (short*)p; p += (size_t)4096 * 1024 * 2;     // 8 MB
    short* relkb = (short*)p; p += (size_t)144 * 64 * 2;
    short* relvT = (short*)p; p += (size_t)64 * 128 * 2;

    prep_all  <<<3080, 256, 0, stream>>>(x, xb, wq, wk, wv, wo, Wtqkv, Wto,
                                         relk, relv, relkb, relvT);
    gemm_qkv  <<<768, 256, 0, stream>>>(xb, Wtqkv, bq, bk, bv, Qb, Kb, Vtb);
    attn_mfma <<<1024, 256, 0, stream>>>(Qb, Kb, Vtb, relkb, relvT, relv, mask, CTXb);
    gemm_out  <<<512, 256, 0, stream>>>(CTXb, Wto, bo, out);
}

// Round 15
// 116.808 us; speedup vs baseline: 1.6886x; 1.0089x over previous
//
#include <hip/hip_runtime.h>
#include <hip/hip_bf16.h>
#include <cstdint>
#include <cstddef>

typedef unsigned int u32;
typedef __attribute__((ext_vector_type(8))) short s16x8;   // 8 bf16 (4 VGPR) MFMA A/B frag
typedef __attribute__((ext_vector_type(4))) short s16x4;   // 4 bf16, 8B pack
typedef __attribute__((ext_vector_type(4))) float f32x4;   // MFMA C/D frag
typedef __attribute__((ext_vector_type(2))) u32   u32x2;

#define MFMA(a,b,c) __builtin_amdgcn_mfma_f32_16x16x32_bf16(a,b,c,0,0,0)

#if __has_builtin(__builtin_amdgcn_mfma_f32_16x16x16bf16_1k)
#define MFMA16(a,b,c) __builtin_amdgcn_mfma_f32_16x16x16bf16_1k(a,b,c,0,0,0)
#else
static __device__ __forceinline__ f32x4 MFMA16(s16x4 a, s16x4 b, f32x4 c){
    f32x4 d;
    asm("v_mfma_f32_16x16x16_bf16 %0, %1, %2, %3"
        : "=v"(d) : "v"(a), "v"(b), "v"(c));
    return d;
}
#endif

__device__ __forceinline__ short f2bf(float f) {
    u32 u = __builtin_bit_cast(u32, f);
    u32 r = (u + 0x7fffu + ((u >> 16) & 1u)) >> 16;   // RNE
    return (short)r;
}
__device__ __forceinline__ float bf2f(short s) {
    return __builtin_bit_cast(float, ((u32)(unsigned short)s) << 16);
}
__device__ __forceinline__ u32 cvtpk(float lo, float hi) {
    u32 r;
    asm("v_cvt_pk_bf16_f32 %0, %1, %2" : "=v"(r) : "v"(lo), "v"(hi));
    return r;
}
__device__ __forceinline__ void async_copy16(void* lds, const void* g) {
    __builtin_amdgcn_global_load_lds((const __attribute__((address_space(1))) u32*)g,
                                     (__attribute__((address_space(3))) u32*)lds, 16, 0, 0);
}

// ---------------------------------------------------------------------------
// prep_all: fused {cast_x | transpose_w | prep_tables}
// ---------------------------------------------------------------------------
__global__ __launch_bounds__(256)
void prep_all(const float* __restrict__ x, short* __restrict__ xb,
              const float* __restrict__ wq, const float* __restrict__ wk,
              const float* __restrict__ wv, const float* __restrict__ wo,
              short* __restrict__ Wtqkv, short* __restrict__ Wto,
              const float* __restrict__ relk, const float* __restrict__ relv,
              short* __restrict__ relkb, short* __restrict__ relvT)
{
    __shared__ float sT[64][68];
    const int bid = blockIdx.x;
    const int tid = threadIdx.x;

    if (bid < 2048) {
        int i = (bid * 256 + tid) * 8;
        float4 a = *(const float4*)&x[i];
        float4 b = *(const float4*)&x[i + 4];
        s16x8 v = { f2bf(a.x), f2bf(a.y), f2bf(a.z), f2bf(a.w),
                    f2bf(b.x), f2bf(b.y), f2bf(b.z), f2bf(b.w) };
        *(s16x8*)&xb[i] = v;
    } else if (bid < 3072) {
        const int wid = bid - 2048;
        const int kt = wid & 15, nt = (wid >> 4) & 15, seg = wid >> 8;
        const float* src = seg == 0 ? wq : seg == 1 ? wk : seg == 2 ? wv : wo;
        const int k0 = kt * 64, n0 = nt * 64;
#pragma unroll
        for (int i = 0; i < 4; ++i) {
            int t2 = tid + i * 256;
            int r = t2 >> 4, c4 = t2 & 15;
            *(float4*)&sT[r][c4 * 4] = *(const float4*)&src[(size_t)(k0 + r) * 1024 + n0 + c4 * 4];
        }
        __syncthreads();
#pragma unroll
        for (int i = 0; i < 2; ++i) {
            int t2 = tid + i * 256;
            int rn = t2 >> 3, ch = t2 & 7;
            s16x8 v;
#pragma unroll
            for (int j = 0; j < 8; ++j) v[j] = f2bf(sT[ch * 8 + j][rn]);
            if (seg < 3)
                *(s16x8*)&Wtqkv[(size_t)(seg * 1024 + n0 + rn) * 1024 + k0 + ch * 8] = v;
            else
                *(s16x8*)&Wto[(size_t)(n0 + rn) * 1024 + k0 + ch * 8] = v;
        }
    } else {
        int gt = (bid - 3072) * 256 + tid;
        for (int i = gt; i < 144 * 64; i += 256 * 8) {
            int r = i >> 6, d = i & 63;
            relkb[i] = (r < 129) ? f2bf(relk[r * 64 + d]) : (short)0;
        }
        for (int i = gt; i < 64 * 128; i += 256 * 8) {
            int d = i >> 7, r = i & 127;
            relvT[i] = f2bf(relv[r * 64 + d]);
        }
    }
}

// ---------------------------------------------------------------------------
// Fused QKV GEMM (unchanged from round 14)
// ---------------------------------------------------------------------------
__global__ __launch_bounds__(256, 4)
void gemm_qkv(const short* __restrict__ Ab, const short* __restrict__ Wt,
              const float* __restrict__ bq, const float* __restrict__ bk,
              const float* __restrict__ bv,
              short* __restrict__ Qb, short* __restrict__ Kb, short* __restrict__ Vtb)
{
    __shared__ __align__(16) short As[128 * 64];
    __shared__ __align__(16) short Bs[128 * 64];
    const int tid = threadIdx.x;
    const int w = tid >> 6, lane = tid & 63;
    const int lo16 = lane & 15, hi = lane >> 4;
    const int pb = blockIdx.x;
    const int wg = (pb & 7) * 96 + (pb >> 3);
    const int n0g = (wg % 24) * 128;
    const int m0 = (wg / 24) * 128;
    const int wr = w >> 1, wc = w & 1;

    f32x4 acc[4][4] = {};

    for (int t = 0; t < 16; ++t) {
        const int k0 = t * 64;
        __syncthreads();
#pragma unroll
        for (int i = 0; i < 4; ++i) {
            int o = i * 4096 + tid * 16;
            int row = o >> 7;
            int cb = o & 127;
            int sc = cb ^ ((row & 7) << 4);
            async_copy16((char*)As + o, Ab + (size_t)(m0 + row) * 1024 + k0 + (sc >> 1));
            async_copy16((char*)Bs + o, Wt + (size_t)(n0g + row) * 1024 + k0 + (sc >> 1));
        }
        __syncthreads();
#pragma unroll
        for (int ks = 0; ks < 2; ++ks) {
            s16x8 aF[4], bF[4];
#pragma unroll
            for (int mi = 0; mi < 4; ++mi) {
                int row = wr * 64 + mi * 16 + lo16;
                int cb = ks * 64 + hi * 16;
                aF[mi] = *(const s16x8*)((const char*)As + row * 128 + (cb ^ ((row & 7) << 4)));
            }
#pragma unroll
            for (int ni = 0; ni < 4; ++ni) {
                int row = wc * 64 + ni * 16 + lo16;
                int cb = ks * 64 + hi * 16;
                bF[ni] = *(const s16x8*)((const char*)Bs + row * 128 + (cb ^ ((row & 7) << 4)));
            }
#pragma unroll
            for (int mi = 0; mi < 4; ++mi)
#pragma unroll
                for (int ni = 0; ni < 4; ++ni)
                    acc[mi][ni] = MFMA(aF[mi], bF[ni], acc[mi][ni]);
        }
    }

    const int seg = n0g >> 10;
    const int nn = n0g & 1023;
    const float* bias = seg == 0 ? bq : seg == 1 ? bk : bv;
    float bv4[4];
#pragma unroll
    for (int ni = 0; ni < 4; ++ni) bv4[ni] = bias[nn + wc * 64 + ni * 16 + lo16];

    if (seg == 2) {
#pragma unroll
        for (int mi = 0; mi < 4; ++mi)
#pragma unroll
            for (int ni = 0; ni < 4; ++ni) {
                int nl = nn + wc * 64 + ni * 16 + lo16;
                int hh = nl >> 6, d = nl & 63;
                int mbase = m0 + wr * 64 + mi * 16 + hi * 4;
                int bb = mbase >> 10, l0 = mbase & 1023;
                int j0 = l0 & 31;
                int col = (l0 >> 5) * 32 + (((j0 >> 4) & 1) << 2) + (((j0 >> 2) & 3) << 3);
                s16x4 pk = { f2bf(acc[mi][ni][0] + bv4[ni]),
                             f2bf(acc[mi][ni][1] + bv4[ni]),
                             f2bf(acc[mi][ni][2] + bv4[ni]),
                             f2bf(acc[mi][ni][3] + bv4[ni]) };
                *(s16x4*)&Vtb[((size_t)(bb * 16 + hh) * 64 + d) * 1024 + col] = pk;
            }
    } else {
        short* out = seg == 0 ? Qb : Kb;
#pragma unroll
        for (int mi = 0; mi < 4; ++mi)
#pragma unroll
            for (int ni = 0; ni < 4; ++ni) {
                int nl = nn + wc * 64 + ni * 16 + lo16;
                int hh = nl >> 6, d = nl & 63;
#pragma unroll
                for (int r = 0; r < 4; ++r) {
                    int m = m0 + wr * 64 + mi * 16 + hi * 4 + r;
                    int bb = m >> 10, l = m & 1023;
                    out[(((size_t)bb * 16 + hh) * 1024 + l) * 64 + d] = f2bf(acc[mi][ni][r] + bv4[ni]);
                }
            }
    }
}

// ---------------------------------------------------------------------------
// Flash attention v10: same sync structure as v9 (passing), but the two
// 32-k chunks are PHASE-SPLIT: all 8 QK MFMAs -> both softmaxes -> all 16
// PV MFMAs. Pure register-level reorder; QK pairs chained via C-operand.
// ---------------------------------------------------------------------------
struct TileRegs {
    s16x8 k0, k1, k2, k3;    // K frags (QK A-operand)
    s16x8 v0, v1, v2, v3;    // V frags (two 8B PV A-frags packed per 16B)
    s16x4 m0, m1;            // mask bias
};

__device__ __forceinline__ void prefetch_tile(
    const short* __restrict__ sKc, const short* __restrict__ sVc,
    const short* __restrict__ sMaskP, int kfm, int lo16, int hi, TileRegs& R)
{
    const int km = lo16 & 7;
    R.k0 = *(const s16x8*)(sKc + lo16 * 64 + ((hi ^ km) << 3));
    R.k1 = *(const s16x8*)(sKc + lo16 * 64 + (((hi + 4) ^ km) << 3));
    R.k2 = *(const s16x8*)(sKc + (lo16 + 16) * 64 + ((hi ^ km) << 3));
    R.k3 = *(const s16x8*)(sKc + (lo16 + 16) * 64 + (((hi + 4) ^ km) << 3));
    R.v0 = *(const s16x8*)(sVc + lo16 * 32 + hi * 8);
    R.v1 = *(const s16x8*)(sVc + (16 + lo16) * 32 + hi * 8);
    R.v2 = *(const s16x8*)(sVc + (32 + lo16) * 32 + hi * 8);
    R.v3 = *(const s16x8*)(sVc + (48 + lo16) * 32 + hi * 8);
    R.m0 = *(const s16x4*)&sMaskP[kfm + hi * 4];
    R.m1 = *(const s16x4*)&sMaskP[kfm + 16 + hi * 4];
}

__device__ __forceinline__ void softmax32(
    int kf, int q0, int q_abs, int lo16, int hi,
    const f32x4& s0, const f32x4& s1, const s16x4& m0, const s16x4& m1,
    float qrel_lo, float qrel_hi,
    const short (*sQrelw)[144], short (*sBandw)[128],
    float& lsum, float& lov, float& hiv, s16x4& pf0, s16x4& pf1)
{
    float p[8];
    if (kf + 95 <= q0 || kf >= q0 + 79) {
        // whole block out of band: rel uniform 0 or 128
        const float qc = (kf < q0) ? qrel_lo : qrel_hi;
        float bs = 0.f;
#pragma unroll
        for (int r = 0; r < 4; ++r) {
            p[r]     = __expf(s0[r] + qc + bf2f(m0[r]));
            p[4 + r] = __expf(s1[r] + qc + bf2f(m1[r]));
        }
#pragma unroll
        for (int r = 0; r < 8; ++r) bs += p[r];
        lsum += bs;
        if (kf < q0) lov += bs; else hiv += bs;
    } else {
#pragma unroll
        for (int f = 0; f < 2; ++f)
#pragma unroll
            for (int r = 0; r < 4; ++r) {
                int k_abs = kf + f * 16 + hi * 4 + r;
                int dd = k_abs - q_abs;
                dd = dd < -64 ? -64 : (dd > 64 ? 64 : dd);
                int rel = dd + 64;
                float sv = f ? s1[r] : s0[r];
                float mv = bf2f(f ? m1[r] : m0[r]);
                float pex = __expf(sv + bf2f(sQrelw[lo16][rel]) + mv);
                p[f * 4 + r] = pex;
                lsum += pex;
                if (rel >= 1 && rel <= 127) sBandw[lo16][rel] = f2bf(pex);
                else if (rel == 0) lov += pex;
                else hiv += pex;
            }
    }
    u32x2 w0 = { cvtpk(p[0], p[1]), cvtpk(p[2], p[3]) };
    u32x2 w1 = { cvtpk(p[4], p[5]), cvtpk(p[6], p[7]) };
    pf0 = __builtin_bit_cast(s16x4, w0);
    pf1 = __builtin_bit_cast(s16x4, w1);
}

__device__ __forceinline__ void pv32(const TileRegs& R, const s16x4& pf0,
                                     const s16x4& pf1, f32x4* ctx)
{
    s16x4 a0 = __builtin_shufflevector(R.v0, R.v0, 0, 1, 2, 3);
    s16x4 b0 = __builtin_shufflevector(R.v0, R.v0, 4, 5, 6, 7);
    s16x4 a1 = __builtin_shufflevector(R.v1, R.v1, 0, 1, 2, 3);
    s16x4 b1 = __builtin_shufflevector(R.v1, R.v1, 4, 5, 6, 7);
    s16x4 a2 = __builtin_shufflevector(R.v2, R.v2, 0, 1, 2, 3);
    s16x4 b2 = __builtin_shufflevector(R.v2, R.v2, 4, 5, 6, 7);
    s16x4 a3 = __builtin_shufflevector(R.v3, R.v3, 0, 1, 2, 3);
    s16x4 b3 = __builtin_shufflevector(R.v3, R.v3, 4, 5, 6, 7);
    ctx[0] = MFMA16(a0, pf0, ctx[0]);
    ctx[1] = MFMA16(a1, pf0, ctx[1]);
    ctx[2] = MFMA16(a2, pf0, ctx[2]);
    ctx[3] = MFMA16(a3, pf0, ctx[3]);
    ctx[0] = MFMA16(b0, pf1, ctx[0]);
    ctx[1] = MFMA16(b1, pf1, ctx[1]);
    ctx[2] = MFMA16(b2, pf1, ctx[2]);
    ctx[3] = MFMA16(b3, pf1, ctx[3]);
}

__global__ __launch_bounds__(256, 3)
void attn_mfma(const short* __restrict__ Qb, const short* __restrict__ Kb,
               const short* __restrict__ Vtb, const short* __restrict__ relkb,
               const short* __restrict__ relvTb, const float* __restrict__ relv_f32,
               const float* __restrict__ mask, short* __restrict__ CTXb)
{
    __shared__ __align__(16) short sK[2][32 * 64];     // [sub], single tile, swizzled (8KB)
    __shared__ __align__(16) short sV[2][64 * 32];     // [sub], k-interleaved (8KB)
    __shared__ __align__(16) short sMaskP[1024 + 32];  // bf16 mask * -1e9 (2.1KB)
    __shared__ __align__(16) short sQrel[4][16][144];  // bf16 Qrel[q][r] (18.4KB)
    __shared__ __align__(16) short sBand[4][16][128];  // bf16 band weights (16KB)

    const int tid = threadIdx.x;
    const int w = tid >> 6, lane = tid & 63;
    const int lo16 = lane & 15, hi = lane >> 4;

    const int p = blockIdx.x;
    const int bid = (p & 7) * 128 + (p >> 3);
    const int bh = bid >> 4;
    const int qt = bid & 15;
    const int b = bh >> 4, h = bh & 15;
    const int q0 = qt * 64 + w * 16;
    const int q_abs = q0 + lo16;

    const short* Kbase = Kb + (size_t)bh * 65536;
    const short* Vtbase = Vtb + (size_t)bh * 65536;

    const int skr = tid >> 3, skc = tid & 7;
    const int svd = tid >> 2, svc = tid & 3;
    const short* ksrc = Kbase + (size_t)skr * 64 + ((skc ^ (skr & 7)) << 3);
    const short* vsrc = Vtbase + (size_t)svd * 1024 + svc * 8;

    async_copy16((char*)&sK[0][0] + tid * 16, ksrc);
    async_copy16((char*)&sK[1][0] + tid * 16, ksrc + 32 * 64);
    async_copy16((char*)&sV[0][0] + tid * 16, vsrc);
    async_copy16((char*)&sV[1][0] + tid * 16, vsrc + 32);

    const short* qptr = Qb + ((size_t)bh * 1024 + q_abs) * 64 + hi * 8;
    const s16x8 qB0 = *(const s16x8*)qptr;
    const s16x8 qB1 = *(const s16x8*)(qptr + 32);

    {
        float4 mv = *(const float4*)&mask[b * 1024 + tid * 4];
        s16x4 mp = { f2bf(mv.x * -1e9f), f2bf(mv.y * -1e9f),
                     f2bf(mv.z * -1e9f), f2bf(mv.w * -1e9f) };
        *(s16x4*)&sMaskP[tid * 4] = mp;
        if (tid < 8) *(s16x4*)&sMaskP[1024 + tid * 4] = s16x4{0, 0, 0, 0};
    }
    {
        u32* bz = (u32*)&sBand[w][0][0];
#pragma unroll
        for (int i = 0; i < 16; ++i) bz[lane + i * 64] = 0u;
    }

#pragma unroll
    for (int rf = 0; rf < 9; ++rf) {
        const short* rp = relkb + (size_t)(rf * 16 + lo16) * 64 + hi * 8;
        s16x8 rA0 = *(const s16x8*)rp;
        s16x8 rA1 = *(const s16x8*)(rp + 32);
        f32x4 dq = {0.f, 0.f, 0.f, 0.f};
        dq = MFMA(rA0, qB0, dq);
        dq = MFMA(rA1, qB1, dq);
        s16x4 pk = { f2bf(dq[0]), f2bf(dq[1]), f2bf(dq[2]), f2bf(dq[3]) };
        *(s16x4*)&sQrel[w][lo16][rf * 16 + hi * 4] = pk;
    }
    __syncthreads();   // drains tile-0 staging; fences sMaskP/sQrel

    const float qrel_lo = bf2f(sQrel[w][lo16][0]);
    const float qrel_hi = bf2f(sQrel[w][lo16][128]);

    f32x4 ctx[4] = {};
    float lsum = 0.f, lov = 0.f, hiv = 0.f;
    const f32x4 z = {0.f, 0.f, 0.f, 0.f};

    TileRegs R0, R1;
    for (int t = 0; t < 16; ++t) {
        // phase A: whole tile t LDS -> regs
        prefetch_tile(sK[0], sV[0], sMaskP, t * 64,      lo16, hi, R0);
        prefetch_tile(sK[1], sV[1], sMaskP, t * 64 + 32, lo16, hi, R1);
        __syncthreads();   // barrier 1: all waves done reading the buffer
        // stage tile t+1 into the same buffer; drains at barrier 2
        const int kb = ((t + 1) & 15) * 64;
        async_copy16((char*)&sK[0][0] + tid * 16, ksrc + (size_t)kb * 64);
        async_copy16((char*)&sK[1][0] + tid * 16, ksrc + (size_t)(kb + 32) * 64);
        async_copy16((char*)&sV[0][0] + tid * 16, vsrc + kb);
        async_copy16((char*)&sV[1][0] + tid * 16, vsrc + kb + 32);

        // ---- phase 1: all 8 QK MFMAs (4 independent 2-deep chains) ----
        __builtin_amdgcn_s_setprio(1);
        f32x4 sA0 = MFMA(R0.k0, qB0, z);
        f32x4 sA1 = MFMA(R0.k2, qB0, z);
        f32x4 sB0 = MFMA(R1.k0, qB0, z);
        f32x4 sB1 = MFMA(R1.k2, qB0, z);
        sA0 = MFMA(R0.k1, qB1, sA0);
        sA1 = MFMA(R0.k3, qB1, sA1);
        sB0 = MFMA(R1.k1, qB1, sB0);
        sB1 = MFMA(R1.k3, qB1, sB1);
        __builtin_amdgcn_s_setprio(0);

        // ---- phase 2: both softmaxes (independent VALU streams) ----
        s16x4 pa0, pa1, pb0, pb1;
        softmax32(t * 64,      q0, q_abs, lo16, hi, sA0, sA1, R0.m0, R0.m1,
                  qrel_lo, qrel_hi, sQrel[w], sBand[w], lsum, lov, hiv, pa0, pa1);
        softmax32(t * 64 + 32, q0, q_abs, lo16, hi, sB0, sB1, R1.m0, R1.m1,
                  qrel_lo, qrel_hi, sQrel[w], sBand[w], lsum, lov, hiv, pb0, pb1);

        // ---- phase 3: all 16 PV MFMAs ----
        __builtin_amdgcn_s_setprio(1);
        pv32(R0, pa0, pa1, ctx);
        pv32(R1, pb0, pb1, ctx);
        __builtin_amdgcn_s_setprio(0);

        __syncthreads();   // barrier 2: staging complete for all waves
    }

    // band rel_v contribution: ctx^T += relvT-frag x sBand-frag (unnormalized)
#pragma unroll
    for (int ks = 0; ks < 4; ++ks) {
        s16x8 bB = *(const s16x8*)&sBand[w][lo16][ks * 32 + hi * 8];
#pragma unroll
        for (int df = 0; df < 4; ++df) {
            s16x8 rA = *(const s16x8*)(relvTb + (size_t)(df * 16 + lo16) * 128 + ks * 32 + hi * 8);
            ctx[df] = MFMA(rA, bB, ctx[df]);
        }
    }

    // reduce per-q stats across the 4 hi-groups
    lsum += __shfl_xor(lsum, 16); lsum += __shfl_xor(lsum, 32);
    lov  += __shfl_xor(lov, 16);  lov  += __shfl_xor(lov, 32);
    hiv  += __shfl_xor(hiv, 16);  hiv  += __shfl_xor(hiv, 32);
    const float inv = 1.0f / lsum;

    // tails (clipped buckets 0 / 128) + normalize + store bf16 ctx
#pragma unroll
    for (int df = 0; df < 4; ++df) {
        s16x4 pk;
#pragma unroll
        for (int r = 0; r < 4; ++r) {
            int d = df * 16 + hi * 4 + r;
            float t = ctx[df][r] + lov * relv_f32[d] + hiv * relv_f32[128 * 64 + d];
            pk[r] = f2bf(t * inv);
        }
        *(s16x4*)(CTXb + ((size_t)(b * 1024) + q_abs) * 1024 + h * 64 + df * 16 + hi * 4) = pk;
    }
}

// ---------------------------------------------------------------------------
// Output GEMM (unchanged from round 14): 128x64 tile, 512 blocks, XCD-swizzled.
// ---------------------------------------------------------------------------
__global__ __launch_bounds__(256, 4)
void gemm_out(const short* __restrict__ Ab, const short* __restrict__ Wto,
              const float* __restrict__ bo, float* __restrict__ out)
{
    __shared__ __align__(16) short As[128 * 64];
    __shared__ __align__(16) short Bs[64 * 64];
    const int tid = threadIdx.x;
    const int w = tid >> 6, lane = tid & 63;
    const int lo16 = lane & 15, hi = lane >> 4;
    const int pb = blockIdx.x;
    const int wg = (pb & 7) * 64 + (pb >> 3);
    const int n0 = (wg & 15) * 64;
    const int m0 = (wg >> 4) * 128;
    const int wr = w;

    f32x4 acc[2][4] = {};

    for (int t = 0; t < 16; ++t) {
        const int k0 = t * 64;
        __syncthreads();
#pragma unroll
        for (int i = 0; i < 4; ++i) {
            int o = i * 4096 + tid * 16;
            int row = o >> 7;
            int cb = o & 127;
            int sc = cb ^ ((row & 7) << 4);
            async_copy16((char*)As + o, Ab + (size_t)(m0 + row) * 1024 + k0 + (sc >> 1));
        }
#pragma unroll
        for (int i = 0; i < 2; ++i) {
            int o = i * 4096 + tid * 16;
            int row = o >> 7;
            int cb = o & 127;
            int sc = cb ^ ((row & 7) << 4);
            async_copy16((char*)Bs + o, Wto + (size_t)(n0 + row) * 1024 + k0 + (sc >> 1));
        }
        __syncthreads();
#pragma unroll
        for (int ks = 0; ks < 2; ++ks) {
            s16x8 aF[2], bF[4];
#pragma unroll
            for (int mi = 0; mi < 2; ++mi) {
                int row = wr * 32 + mi * 16 + lo16;
                int cb = ks * 64 + hi * 16;
                aF[mi] = *(const s16x8*)((const char*)As + row * 128 + (cb ^ ((row & 7) << 4)));
            }
#pragma unroll
            for (int ni = 0; ni < 4; ++ni) {
                int row = ni * 16 + lo16;
                int cb = ks * 64 + hi * 16;
                bF[ni] = *(const s16x8*)((const char*)Bs + row * 128 + (cb ^ ((row & 7) << 4)));
            }
#pragma unroll
            for (int mi = 0; mi < 2; ++mi)
#pragma unroll
                for (int ni = 0; ni < 4; ++ni)
                    acc[mi][ni] = MFMA(aF[mi], bF[ni], acc[mi][ni]);
        }
    }

    float bv4[4];
#pragma unroll
    for (int ni = 0; ni < 4; ++ni) bv4[ni] = bo[n0 + ni * 16 + lo16];
#pragma unroll
    for (int mi = 0; mi < 2; ++mi)
#pragma unroll
        for (int ni = 0; ni < 4; ++ni)
#pragma unroll
            for (int r = 0; r < 4; ++r) {
                int m = m0 + wr * 32 + mi * 16 + hi * 4 + r;
                out[(size_t)m * 1024 + n0 + ni * 16 + lo16] = acc[mi][ni][r] + bv4[ni];
            }
}

// ---------------------------------------------------------------------------
extern "C" void kernel_launch(void* const* d_in, const int* in_sizes, int n_in,
                              void* d_out, int out_size, void* d_ws, size_t ws_size,
                              hipStream_t stream)
{
    (void)in_sizes; (void)n_in; (void)out_size; (void)ws_size;
    const float* x    = (const float*)d_in[0];
    const float* mask = (const float*)d_in[1];
    const float* wq   = (const float*)d_in[2];
    const float* bq   = (const float*)d_in[3];
    const float* wk   = (const float*)d_in[4];
    const float* bk   = (const float*)d_in[5];
    const float* wv   = (const float*)d_in[6];
    const float* bv   = (const float*)d_in[7];
    const float* wo   = (const float*)d_in[8];
    const float* bo   = (const float*)d_in[9];
    const float* relk = (const float*)d_in[10];
    const float* relv = (const float*)d_in[11];
    float* out = (float*)d_out;

    char* p = (char*)d_ws;
    short* xb    = (short*)p; p += (size_t)4096 * 1024 * 2;     // 8 MB
    short* Wtqkv = (short*)p; p += (size_t)3072 * 1024 * 2;     // 6 MB
    short* Wto   = (short*)p; p += (size_t)1024 * 1024 * 2;     // 2 MB
    short* Qb    = (short*)p; p += (size_t)4096 * 1024 * 2;     // 8 MB
    short* Kb    = (short*)p; p += (size_t)4096 * 1024 * 2;     // 8 MB
    short* Vtb   = (short*)p; p += (size_t)4096 * 1024 * 2;     // 8 MB
    short* CTXb  = (short*)p; p += (size_t)4096 * 1024 * 2;     // 8 MB
    short* relkb = (short*)p; p += (size_t)144 * 64 * 2;
    short* relvT = (short*)p; p += (size_t)64 * 128 * 2;

    prep_all  <<<3080, 256, 0, stream>>>(x, xb, wq, wk, wv, wo, Wtqkv, Wto,
                                         relk, relv, relkb, relvT);
    gemm_qkv  <<<768, 256, 0, stream>>>(xb, Wtqkv, bq, bk, bv, Qb, Kb, Vtb);
    attn_mfma <<<1024, 256, 0, stream>>>(Qb, Kb, Vtb, relkb, relvT, relv, mask, CTXb);
    gemm_out  <<<512, 256, 0, stream>>>(CTXb, Wto, bo, out);
}

// Round 17
// 114.437 us; speedup vs baseline: 1.7236x; 1.0207x over previous
//
#include <hip/hip_runtime.h>
#include <hip/hip_bf16.h>
#include <cstdint>
#include <cstddef>

typedef unsigned int u32;
typedef __attribute__((ext_vector_type(8))) short s16x8;   // 8 bf16 (4 VGPR) MFMA A/B frag
typedef __attribute__((ext_vector_type(4))) short s16x4;   // 4 bf16, 8B pack
typedef __attribute__((ext_vector_type(4))) float f32x4;   // MFMA C/D frag
typedef __attribute__((ext_vector_type(2))) u32   u32x2;

#define MFMA(a,b,c) __builtin_amdgcn_mfma_f32_16x16x32_bf16(a,b,c,0,0,0)

#if __has_builtin(__builtin_amdgcn_mfma_f32_16x16x16bf16_1k)
#define MFMA16(a,b,c) __builtin_amdgcn_mfma_f32_16x16x16bf16_1k(a,b,c,0,0,0)
#else
static __device__ __forceinline__ f32x4 MFMA16(s16x4 a, s16x4 b, f32x4 c){
    f32x4 d;
    asm("v_mfma_f32_16x16x16_bf16 %0, %1, %2, %3"
        : "=v"(d) : "v"(a), "v"(b), "v"(c));
    return d;
}
#endif

__device__ __forceinline__ short f2bf(float f) {
    u32 u = __builtin_bit_cast(u32, f);
    u32 r = (u + 0x7fffu + ((u >> 16) & 1u)) >> 16;   // RNE
    return (short)r;
}
__device__ __forceinline__ float bf2f(short s) {
    return __builtin_bit_cast(float, ((u32)(unsigned short)s) << 16);
}
__device__ __forceinline__ u32 cvtpk(float lo, float hi) {
    u32 r;
    asm("v_cvt_pk_bf16_f32 %0, %1, %2" : "=v"(r) : "v"(lo), "v"(hi));
    return r;
}
__device__ __forceinline__ void async_copy16(void* lds, const void* g) {
    __builtin_amdgcn_global_load_lds((const __attribute__((address_space(1))) u32*)g,
                                     (__attribute__((address_space(3))) u32*)lds, 16, 0, 0);
}

// ---------------------------------------------------------------------------
// prep_all: fused {cast_x | transpose_w | tables + maskP}
// ---------------------------------------------------------------------------
__global__ __launch_bounds__(256)
void prep_all(const float* __restrict__ x, short* __restrict__ xb,
              const float* __restrict__ wq, const float* __restrict__ wk,
              const float* __restrict__ wv, const float* __restrict__ wo,
              short* __restrict__ Wtqkv, short* __restrict__ Wto,
              const float* __restrict__ relk, const float* __restrict__ relv,
              short* __restrict__ relkb, short* __restrict__ relvT,
              const float* __restrict__ mask, short* __restrict__ maskPb)
{
    __shared__ float sT[64][68];
    const int bid = blockIdx.x;
    const int tid = threadIdx.x;

    if (bid < 2048) {
        int i = (bid * 256 + tid) * 8;
        float4 a = *(const float4*)&x[i];
        float4 b = *(const float4*)&x[i + 4];
        s16x8 v = { f2bf(a.x), f2bf(a.y), f2bf(a.z), f2bf(a.w),
                    f2bf(b.x), f2bf(b.y), f2bf(b.z), f2bf(b.w) };
        *(s16x8*)&xb[i] = v;
    } else if (bid < 3072) {
        const int wid = bid - 2048;
        const int kt = wid & 15, nt = (wid >> 4) & 15, seg = wid >> 8;
        const float* src = seg == 0 ? wq : seg == 1 ? wk : seg == 2 ? wv : wo;
        const int k0 = kt * 64, n0 = nt * 64;
#pragma unroll
        for (int i = 0; i < 4; ++i) {
            int t2 = tid + i * 256;
            int r = t2 >> 4, c4 = t2 & 15;
            *(float4*)&sT[r][c4 * 4] = *(const float4*)&src[(size_t)(k0 + r) * 1024 + n0 + c4 * 4];
        }
        __syncthreads();
#pragma unroll
        for (int i = 0; i < 2; ++i) {
            int t2 = tid + i * 256;
            int rn = t2 >> 3, ch = t2 & 7;
            s16x8 v;
#pragma unroll
            for (int j = 0; j < 8; ++j) v[j] = f2bf(sT[ch * 8 + j][rn]);
            if (seg < 3)
                *(s16x8*)&Wtqkv[(size_t)(seg * 1024 + n0 + rn) * 1024 + k0 + ch * 8] = v;
            else
                *(s16x8*)&Wto[(size_t)(n0 + rn) * 1024 + k0 + ch * 8] = v;
        }
    } else {
        int gt = (bid - 3072) * 256 + tid;
        for (int i = gt; i < 144 * 64; i += 256 * 8) {
            int r = i >> 6, d = i & 63;
            relkb[i] = (r < 129) ? f2bf(relk[r * 64 + d]) : (short)0;
        }
        for (int i = gt; i < 64 * 128; i += 256 * 8) {
            int d = i >> 7, r = i & 127;
            relvT[i] = f2bf(relv[r * 64 + d]);
        }
        for (int i = gt; i < 4096; i += 256 * 8)
            maskPb[i] = f2bf(mask[i] * -1e9f);
    }
}

// ---------------------------------------------------------------------------
// Fused QKV GEMM (unchanged)
// ---------------------------------------------------------------------------
__global__ __launch_bounds__(256, 4)
void gemm_qkv(const short* __restrict__ Ab, const short* __restrict__ Wt,
              const float* __restrict__ bq, const float* __restrict__ bk,
              const float* __restrict__ bv,
              short* __restrict__ Qb, short* __restrict__ Kb, short* __restrict__ Vtb)
{
    __shared__ __align__(16) short As[128 * 64];
    __shared__ __align__(16) short Bs[128 * 64];
    const int tid = threadIdx.x;
    const int w = tid >> 6, lane = tid & 63;
    const int lo16 = lane & 15, hi = lane >> 4;
    const int pb = blockIdx.x;
    const int wg = (pb & 7) * 96 + (pb >> 3);
    const int n0g = (wg % 24) * 128;
    const int m0 = (wg / 24) * 128;
    const int wr = w >> 1, wc = w & 1;

    f32x4 acc[4][4] = {};

    for (int t = 0; t < 16; ++t) {
        const int k0 = t * 64;
        __syncthreads();
#pragma unroll
        for (int i = 0; i < 4; ++i) {
            int o = i * 4096 + tid * 16;
            int row = o >> 7;
            int cb = o & 127;
            int sc = cb ^ ((row & 7) << 4);
            async_copy16((char*)As + o, Ab + (size_t)(m0 + row) * 1024 + k0 + (sc >> 1));
            async_copy16((char*)Bs + o, Wt + (size_t)(n0g + row) * 1024 + k0 + (sc >> 1));
        }
        __syncthreads();
#pragma unroll
        for (int ks = 0; ks < 2; ++ks) {
            s16x8 aF[4], bF[4];
#pragma unroll
            for (int mi = 0; mi < 4; ++mi) {
                int row = wr * 64 + mi * 16 + lo16;
                int cb = ks * 64 + hi * 16;
                aF[mi] = *(const s16x8*)((const char*)As + row * 128 + (cb ^ ((row & 7) << 4)));
            }
#pragma unroll
            for (int ni = 0; ni < 4; ++ni) {
                int row = wc * 64 + ni * 16 + lo16;
                int cb = ks * 64 + hi * 16;
                bF[ni] = *(const s16x8*)((const char*)Bs + row * 128 + (cb ^ ((row & 7) << 4)));
            }
#pragma unroll
            for (int mi = 0; mi < 4; ++mi)
#pragma unroll
                for (int ni = 0; ni < 4; ++ni)
                    acc[mi][ni] = MFMA(aF[mi], bF[ni], acc[mi][ni]);
        }
    }

    const int seg = n0g >> 10;
    const int nn = n0g & 1023;
    const float* bias = seg == 0 ? bq : seg == 1 ? bk : bv;
    float bv4[4];
#pragma unroll
    for (int ni = 0; ni < 4; ++ni) bv4[ni] = bias[nn + wc * 64 + ni * 16 + lo16];

    if (seg == 2) {
#pragma unroll
        for (int mi = 0; mi < 4; ++mi)
#pragma unroll
            for (int ni = 0; ni < 4; ++ni) {
                int nl = nn + wc * 64 + ni * 16 + lo16;
                int hh = nl >> 6, d = nl & 63;
                int mbase = m0 + wr * 64 + mi * 16 + hi * 4;
                int bb = mbase >> 10, l0 = mbase & 1023;
                int j0 = l0 & 31;
                int col = (l0 >> 5) * 32 + (((j0 >> 4) & 1) << 2) + (((j0 >> 2) & 3) << 3);
                s16x4 pk = { f2bf(acc[mi][ni][0] + bv4[ni]),
                             f2bf(acc[mi][ni][1] + bv4[ni]),
                             f2bf(acc[mi][ni][2] + bv4[ni]),
                             f2bf(acc[mi][ni][3] + bv4[ni]) };
                *(s16x4*)&Vtb[((size_t)(bb * 16 + hh) * 64 + d) * 1024 + col] = pk;
            }
    } else {
        short* out = seg == 0 ? Qb : Kb;
#pragma unroll
        for (int mi = 0; mi < 4; ++mi)
#pragma unroll
            for (int ni = 0; ni < 4; ++ni) {
                int nl = nn + wc * 64 + ni * 16 + lo16;
                int hh = nl >> 6, d = nl & 63;
#pragma unroll
                for (int r = 0; r < 4; ++r) {
                    int m = m0 + wr * 64 + mi * 16 + hi * 4 + r;
                    int bb = m >> 10, l = m & 1023;
                    out[(((size_t)bb * 16 + hh) * 1024 + l) * 64 + d] = f2bf(acc[mi][ni][r] + bv4[ni]);
                }
            }
    }
}

// ---------------------------------------------------------------------------
// Flash attention v11b: 40960B LDS -> 4 blocks/CU. Qrel[128] broadcast via
// __shfl (NOT the round-16 LDS smuggle, which hit per-thread store-to-load
// forwarding: cross-lane LDS hand-off without a barrier is UB).
// ---------------------------------------------------------------------------
__global__ __launch_bounds__(256, 4)
void attn_mfma(const short* __restrict__ Qb, const short* __restrict__ Kb,
               const short* __restrict__ Vtb, const short* __restrict__ relkb,
               const short* __restrict__ relvTb, const float* __restrict__ relv_f32,
               const short* __restrict__ maskPb, short* __restrict__ CTXb)
{
    __shared__ __align__(16) short sK[32 * 64];        // 4096B, swizzled chunks
    __shared__ __align__(16) short sV[64 * 32];        // 4096B, k-interleaved
    __shared__ __align__(16) short sQrel[4][16][128];  // 16384B (rel 0..127)
    __shared__ __align__(16) short sBand[4][16][128];  // 16384B
    // total = 40960B exactly -> 4 blocks/CU

    const int tid = threadIdx.x;
    const int w = tid >> 6, lane = tid & 63;
    const int lo16 = lane & 15, hi = lane >> 4;

    const int p = blockIdx.x;
    const int bid = (p & 7) * 128 + (p >> 3);
    const int bh = bid >> 4;
    const int qt = bid & 15;
    const int b = bh >> 4, h = bh & 15;
    const int q0 = qt * 64 + w * 16;
    const int q_abs = q0 + lo16;

    const short* Kbase = Kb + (size_t)bh * 65536;
    const short* Vtbase = Vtb + (size_t)bh * 65536;
    const short* mbase = maskPb + b * 1024;

    const int skr = tid >> 3, skc = tid & 7;             // K: row 0..31, chunk 0..7
    const int svd = tid >> 2, svc = tid & 3;             // V: row d 0..63, chunk 0..3
    const short* ksrc = Kbase + (size_t)skr * 64 + ((skc ^ (skr & 7)) << 3);
    const short* vsrc = Vtbase + (size_t)svd * 1024 + svc * 8;

    // stage chunk 0
    async_copy16((char*)&sK[0] + tid * 16, ksrc);
    async_copy16((char*)&sV[0] + tid * 16, vsrc);

    const short* qptr = Qb + ((size_t)bh * 1024 + q_abs) * 64 + hi * 8;
    const s16x8 qB0 = *(const s16x8*)qptr;
    const s16x8 qB1 = *(const s16x8*)(qptr + 32);

    // sBand zero (per-wave region)
    {
        u32* bz = (u32*)&sBand[w][0][0];
#pragma unroll
        for (int i = 0; i < 16; ++i) bz[lane + i * 64] = 0u;
    }

    // Qrel: rf 0..7 -> sQrel[w][q][0..127]; rf=8 kept in regs
    f32x4 dq8 = {0.f, 0.f, 0.f, 0.f};
#pragma unroll
    for (int rf = 0; rf < 9; ++rf) {
        const short* rp = relkb + (size_t)(rf * 16 + lo16) * 64 + hi * 8;
        s16x8 rA0 = *(const s16x8*)rp;
        s16x8 rA1 = *(const s16x8*)(rp + 32);
        f32x4 dq = {0.f, 0.f, 0.f, 0.f};
        dq = MFMA(rA0, qB0, dq);
        dq = MFMA(rA1, qB1, dq);
        if (rf < 8) {
            s16x4 pk = { f2bf(dq[0]), f2bf(dq[1]), f2bf(dq[2]), f2bf(dq[3]) };
            *(s16x4*)&sQrel[w][lo16][rf * 16 + hi * 4] = pk;
        } else {
            dq8 = dq;
        }
    }
    // Qrel[q][0] from LDS slot 0 (stays valid forever); Qrel[q][128] via wave
    // shuffle from lane q (hi==0 holder of dq8[0]) — no LDS hand-off.
    const float qrel_lo = bf2f(sQrel[w][lo16][0]);
    const float qrel_hi = __shfl(f2bf(dq8[0]) != 0 ? bf2f(f2bf(dq8[0])) : 0.0f, lo16);

    __syncthreads();   // drains chunk-0 staging; fences sBand/sQrel

    f32x4 ctx[4] = {};
    float lsum = 0.f, lov = 0.f, hiv = 0.f;
    const f32x4 z = {0.f, 0.f, 0.f, 0.f};
    const int km = lo16 & 7;

    for (int t = 0; t < 32; ++t) {
        const int kf = t * 32;
        // ---- phase A: chunk t LDS -> regs; mask from global (L1) ----
        s16x8 kr0 = *(const s16x8*)(sK + lo16 * 64 + ((hi ^ km) << 3));
        s16x8 kr1 = *(const s16x8*)(sK + lo16 * 64 + (((hi + 4) ^ km) << 3));
        s16x8 kr2 = *(const s16x8*)(sK + (lo16 + 16) * 64 + ((hi ^ km) << 3));
        s16x8 kr3 = *(const s16x8*)(sK + (lo16 + 16) * 64 + (((hi + 4) ^ km) << 3));
        s16x8 vr0 = *(const s16x8*)(sV + lo16 * 32 + hi * 8);
        s16x8 vr1 = *(const s16x8*)(sV + (16 + lo16) * 32 + hi * 8);
        s16x8 vr2 = *(const s16x8*)(sV + (32 + lo16) * 32 + hi * 8);
        s16x8 vr3 = *(const s16x8*)(sV + (48 + lo16) * 32 + hi * 8);
        s16x4 m0 = *(const s16x4*)&mbase[kf + hi * 4];
        s16x4 m1 = *(const s16x4*)&mbase[kf + 16 + hi * 4];
        __syncthreads();   // barrier 1: all waves done reading the buffer
        // ---- stage chunk t+1 into the same buffer (drains at barrier 2) ----
        const int kfn = ((t + 1) & 31) * 32;
        async_copy16((char*)&sK[0] + tid * 16, ksrc + (size_t)kfn * 64);
        async_copy16((char*)&sV[0] + tid * 16, vsrc + kfn);

        // ---- QK (4 MFMAs, 2 chains) ----
        __builtin_amdgcn_s_setprio(1);
        f32x4 s0 = MFMA(kr0, qB0, z);
        f32x4 s1 = MFMA(kr2, qB0, z);
        s0 = MFMA(kr1, qB1, s0);
        s1 = MFMA(kr3, qB1, s1);
        __builtin_amdgcn_s_setprio(0);

        // ---- softmax ----
        float pr[8];
        if (kf + 95 <= q0 || kf >= q0 + 79) {
            const float qc = (kf < q0) ? qrel_lo : qrel_hi;
            float bs = 0.f;
#pragma unroll
            for (int r = 0; r < 4; ++r) {
                pr[r]     = __expf(s0[r] + qc + bf2f(m0[r]));
                pr[4 + r] = __expf(s1[r] + qc + bf2f(m1[r]));
            }
#pragma unroll
            for (int r = 0; r < 8; ++r) bs += pr[r];
            lsum += bs;
            if (kf < q0) lov += bs; else hiv += bs;
        } else {
#pragma unroll
            for (int f = 0; f < 2; ++f)
#pragma unroll
                for (int r = 0; r < 4; ++r) {
                    int k_abs = kf + f * 16 + hi * 4 + r;
                    int dd = k_abs - q_abs;
                    dd = dd < -64 ? -64 : (dd > 64 ? 64 : dd);
                    int rel = dd + 64;
                    int relc = rel > 127 ? 127 : rel;   // slot 0 valid (= Qrel[0])
                    float qv = bf2f(sQrel[w][lo16][relc]);
                    if (rel == 128) qv = qrel_hi;
                    float sv = f ? s1[r] : s0[r];
                    float mv = bf2f(f ? m1[r] : m0[r]);
                    float pex = __expf(sv + qv + mv);
                    pr[f * 4 + r] = pex;
                    lsum += pex;
                    if (rel >= 1 && rel <= 127) sBand[w][lo16][rel] = f2bf(pex);
                    else if (rel == 0) lov += pex;
                    else hiv += pex;
                }
        }
        u32x2 w0 = { cvtpk(pr[0], pr[1]), cvtpk(pr[2], pr[3]) };
        u32x2 w1 = { cvtpk(pr[4], pr[5]), cvtpk(pr[6], pr[7]) };
        s16x4 pf0 = __builtin_bit_cast(s16x4, w0);
        s16x4 pf1 = __builtin_bit_cast(s16x4, w1);

        // ---- PV (8 MFMAs) ----
        s16x4 a0 = __builtin_shufflevector(vr0, vr0, 0, 1, 2, 3);
        s16x4 b0 = __builtin_shufflevector(vr0, vr0, 4, 5, 6, 7);
        s16x4 a1 = __builtin_shufflevector(vr1, vr1, 0, 1, 2, 3);
        s16x4 b1 = __builtin_shufflevector(vr1, vr1, 4, 5, 6, 7);
        s16x4 a2 = __builtin_shufflevector(vr2, vr2, 0, 1, 2, 3);
        s16x4 b2 = __builtin_shufflevector(vr2, vr2, 4, 5, 6, 7);
        s16x4 a3 = __builtin_shufflevector(vr3, vr3, 0, 1, 2, 3);
        s16x4 b3 = __builtin_shufflevector(vr3, vr3, 4, 5, 6, 7);
        __builtin_amdgcn_s_setprio(1);
        ctx[0] = MFMA16(a0, pf0, ctx[0]);
        ctx[1] = MFMA16(a1, pf0, ctx[1]);
        ctx[2] = MFMA16(a2, pf0, ctx[2]);
        ctx[3] = MFMA16(a3, pf0, ctx[3]);
        ctx[0] = MFMA16(b0, pf1, ctx[0]);
        ctx[1] = MFMA16(b1, pf1, ctx[1]);
        ctx[2] = MFMA16(b2, pf1, ctx[2]);
        ctx[3] = MFMA16(b3, pf1, ctx[3]);
        __builtin_amdgcn_s_setprio(0);

        __syncthreads();   // barrier 2: staging complete for all waves
    }

    // band rel_v contribution: ctx^T += relvT-frag x sBand-frag (unnormalized)
#pragma unroll
    for (int ks = 0; ks < 4; ++ks) {
        s16x8 bB = *(const s16x8*)&sBand[w][lo16][ks * 32 + hi * 8];
#pragma unroll
        for (int df = 0; df < 4; ++df) {
            s16x8 rA = *(const s16x8*)(relvTb + (size_t)(df * 16 + lo16) * 128 + ks * 32 + hi * 8);
            ctx[df] = MFMA(rA, bB, ctx[df]);
        }
    }

    // reduce per-q stats across the 4 hi-groups
    lsum += __shfl_xor(lsum, 16); lsum += __shfl_xor(lsum, 32);
    lov  += __shfl_xor(lov, 16);  lov  += __shfl_xor(lov, 32);
    hiv  += __shfl_xor(hiv, 16);  hiv  += __shfl_xor(hiv, 32);
    const float inv = 1.0f / lsum;

    // tails (clipped buckets 0 / 128) + normalize + store bf16 ctx
#pragma unroll
    for (int df = 0; df < 4; ++df) {
        s16x4 pk;
#pragma unroll
        for (int r = 0; r < 4; ++r) {
            int d = df * 16 + hi * 4 + r;
            float t = ctx[df][r] + lov * relv_f32[d] + hiv * relv_f32[128 * 64 + d];
            pk[r] = f2bf(t * inv);
        }
        *(s16x4*)(CTXb + ((size_t)(b * 1024) + q_abs) * 1024 + h * 64 + df * 16 + hi * 4) = pk;
    }
}

// ---------------------------------------------------------------------------
// Output GEMM (unchanged): 128x64 tile, 512 blocks, XCD-swizzled.
// ---------------------------------------------------------------------------
__global__ __launch_bounds__(256, 4)
void gemm_out(const short* __restrict__ Ab, const short* __restrict__ Wto,
              const float* __restrict__ bo, float* __restrict__ out)
{
    __shared__ __align__(16) short As[128 * 64];
    __shared__ __align__(16) short Bs[64 * 64];
    const int tid = threadIdx.x;
    const int w = tid >> 6, lane = tid & 63;
    const int lo16 = lane & 15, hi = lane >> 4;
    const int pb = blockIdx.x;
    const int wg = (pb & 7) * 64 + (pb >> 3);
    const int n0 = (wg & 15) * 64;
    const int m0 = (wg >> 4) * 128;
    const int wr = w;

    f32x4 acc[2][4] = {};

    for (int t = 0; t < 16; ++t) {
        const int k0 = t * 64;
        __syncthreads();
#pragma unroll
        for (int i = 0; i < 4; ++i) {
            int o = i * 4096 + tid * 16;
            int row = o >> 7;
            int cb = o & 127;
            int sc = cb ^ ((row & 7) << 4);
            async_copy16((char*)As + o, Ab + (size_t)(m0 + row) * 1024 + k0 + (sc >> 1));
        }
#pragma unroll
        for (int i = 0; i < 2; ++i) {
            int o = i * 4096 + tid * 16;
            int row = o >> 7;
            int cb = o & 127;
            int sc = cb ^ ((row & 7) << 4);
            async_copy16((char*)Bs + o, Wto + (size_t)(n0 + row) * 1024 + k0 + (sc >> 1));
        }
        __syncthreads();
#pragma unroll
        for (int ks = 0; ks < 2; ++ks) {
            s16x8 aF[2], bF[4];
#pragma unroll
            for (int mi = 0; mi < 2; ++mi) {
                int row = wr * 32 + mi * 16 + lo16;
                int cb = ks * 64 + hi * 16;
                aF[mi] = *(const s16x8*)((const char*)As + row * 128 + (cb ^ ((row & 7) << 4)));
            }
#pragma unroll
            for (int ni = 0; ni < 4; ++ni) {
                int row = ni * 16 + lo16;
                int cb = ks * 64 + hi * 16;
                bF[ni] = *(const s16x8*)((const char*)Bs + row * 128 + (cb ^ ((row & 7) << 4)));
            }
#pragma unroll
            for (int mi = 0; mi < 2; ++mi)
#pragma unroll
                for (int ni = 0; ni < 4; ++ni)
                    acc[mi][ni] = MFMA(aF[mi], bF[ni], acc[mi][ni]);
        }
    }

    float bv4[4];
#pragma unroll
    for (int ni = 0; ni < 4; ++ni) bv4[ni] = bo[n0 + ni * 16 + lo16];
#pragma unroll
    for (int mi = 0; mi < 2; ++mi)
#pragma unroll
        for (int ni = 0; ni < 4; ++ni)
#pragma unroll
            for (int r = 0; r < 4; ++r) {
                int m = m0 + wr * 32 + mi * 16 + hi * 4 + r;
                out[(size_t)m * 1024 + n0 + ni * 16 + lo16] = acc[mi][ni][r] + bv4[ni];
            }
}

// ---------------------------------------------------------------------------
extern "C" void kernel_launch(void* const* d_in, const int* in_sizes, int n_in,
                              void* d_out, int out_size, void* d_ws, size_t ws_size,
                              hipStream_t stream)
{
    (void)in_sizes; (void)n_in; (void)out_size; (void)ws_size;
    const float* x    = (const float*)d_in[0];
    const float* mask = (const float*)d_in[1];
    const float* wq   = (const float*)d_in[2];
    const float* bq   = (const float*)d_in[3];
    const float* wk   = (const float*)d_in[4];
    const float* bk   = (const float*)d_in[5];
    const float* wv   = (const float*)d_in[6];
    const float* bv   = (const float*)d_in[7];
    const float* wo   = (const float*)d_in[8];
    const float* bo   = (const float*)d_in[9];
    const float* relk = (const float*)d_in[10];
    const float* relv = (const float*)d_in[11];
    float* out = (float*)d_out;

    char* p = (char*)d_ws;
    short* xb     = (short*)p; p += (size_t)4096 * 1024 * 2;     // 8 MB
    short* Wtqkv  = (short*)p; p += (size_t)3072 * 1024 * 2;     // 6 MB
    short* Wto    = (short*)p; p += (size_t)1024 * 1024 * 2;     // 2 MB
    short* Qb     = (short*)p; p += (size_t)4096 * 1024 * 2;     // 8 MB
    short* Kb     = (short*)p; p += (size_t)4096 * 1024 * 2;     // 8 MB
    short* Vtb    = (short*)p; p += (size_t)4096 * 1024 * 2;     // 8 MB
    short* CTXb   = (short*)p; p += (size_t)4096 * 1024 * 2;     // 8 MB
    short* relkb  = (short*)p; p += (size_t)144 * 64 * 2;
    short* relvT  = (short*)p; p += (size_t)64 * 128 * 2;
    short* maskPb = (short*)p; p += (size_t)4096 * 2;

    prep_all  <<<3080, 256, 0, stream>>>(x, xb, wq, wk, wv, wo, Wtqkv, Wto,
                                         relk, relv, relkb, relvT, mask, maskPb);
    gemm_qkv  <<<768, 256, 0, stream>>>(xb, Wtqkv, bq, bk, bv, Qb, Kb, Vtb);
    attn_mfma <<<1024, 256, 0, stream>>>(Qb, Kb, Vtb, relkb, relvT, relv, maskPb, CTXb);
    gemm_out  <<<512, 256, 0, stream>>>(CTXb, Wto, bo, out);
}

// Round 18
// 114.084 us; speedup vs baseline: 1.7289x; 1.0031x over previous
//
#include <hip/hip_runtime.h>
#include <hip/hip_bf16.h>
#include <cstdint>
#include <cstddef>

typedef unsigned int u32;
typedef __attribute__((ext_vector_type(8))) short s16x8;   // 8 bf16 (4 VGPR) MFMA A/B frag
typedef __attribute__((ext_vector_type(4))) short s16x4;   // 4 bf16, 8B pack
typedef __attribute__((ext_vector_type(4))) float f32x4;   // MFMA C/D frag
typedef __attribute__((ext_vector_type(2))) u32   u32x2;

#define MFMA(a,b,c) __builtin_amdgcn_mfma_f32_16x16x32_bf16(a,b,c,0,0,0)

#if __has_builtin(__builtin_amdgcn_mfma_f32_16x16x16bf16_1k)
#define MFMA16(a,b,c) __builtin_amdgcn_mfma_f32_16x16x16bf16_1k(a,b,c,0,0,0)
#else
static __device__ __forceinline__ f32x4 MFMA16(s16x4 a, s16x4 b, f32x4 c){
    f32x4 d;
    asm("v_mfma_f32_16x16x16_bf16 %0, %1, %2, %3"
        : "=v"(d) : "v"(a), "v"(b), "v"(c));
    return d;
}
#endif

__device__ __forceinline__ short f2bf(float f) {
    u32 u = __builtin_bit_cast(u32, f);
    u32 r = (u + 0x7fffu + ((u >> 16) & 1u)) >> 16;   // RNE
    return (short)r;
}
__device__ __forceinline__ float bf2f(short s) {
    return __builtin_bit_cast(float, ((u32)(unsigned short)s) << 16);
}
__device__ __forceinline__ u32 cvtpk(float lo, float hi) {
    u32 r;
    asm("v_cvt_pk_bf16_f32 %0, %1, %2" : "=v"(r) : "v"(lo), "v"(hi));
    return r;
}
__device__ __forceinline__ void async_copy16(void* lds, const void* g) {
    __builtin_amdgcn_global_load_lds((const __attribute__((address_space(1))) u32*)g,
                                     (__attribute__((address_space(3))) u32*)lds, 16, 0, 0);
}

// ---------------------------------------------------------------------------
// prep_all: fused {cast_x | transpose_w | tables + maskP}
// ---------------------------------------------------------------------------
__global__ __launch_bounds__(256)
void prep_all(const float* __restrict__ x, short* __restrict__ xb,
              const float* __restrict__ wq, const float* __restrict__ wk,
              const float* __restrict__ wv, const float* __restrict__ wo,
              short* __restrict__ Wtqkv, short* __restrict__ Wto,
              const float* __restrict__ relk, const float* __restrict__ relv,
              short* __restrict__ relkb, short* __restrict__ relvT,
              const float* __restrict__ mask, short* __restrict__ maskPb)
{
    __shared__ float sT[64][68];
    const int bid = blockIdx.x;
    const int tid = threadIdx.x;

    if (bid < 2048) {
        int i = (bid * 256 + tid) * 8;
        float4 a = *(const float4*)&x[i];
        float4 b = *(const float4*)&x[i + 4];
        s16x8 v = { f2bf(a.x), f2bf(a.y), f2bf(a.z), f2bf(a.w),
                    f2bf(b.x), f2bf(b.y), f2bf(b.z), f2bf(b.w) };
        *(s16x8*)&xb[i] = v;
    } else if (bid < 3072) {
        const int wid = bid - 2048;
        const int kt = wid & 15, nt = (wid >> 4) & 15, seg = wid >> 8;
        const float* src = seg == 0 ? wq : seg == 1 ? wk : seg == 2 ? wv : wo;
        const int k0 = kt * 64, n0 = nt * 64;
#pragma unroll
        for (int i = 0; i < 4; ++i) {
            int t2 = tid + i * 256;
            int r = t2 >> 4, c4 = t2 & 15;
            *(float4*)&sT[r][c4 * 4] = *(const float4*)&src[(size_t)(k0 + r) * 1024 + n0 + c4 * 4];
        }
        __syncthreads();
#pragma unroll
        for (int i = 0; i < 2; ++i) {
            int t2 = tid + i * 256;
            int rn = t2 >> 3, ch = t2 & 7;
            s16x8 v;
#pragma unroll
            for (int j = 0; j < 8; ++j) v[j] = f2bf(sT[ch * 8 + j][rn]);
            if (seg < 3)
                *(s16x8*)&Wtqkv[(size_t)(seg * 1024 + n0 + rn) * 1024 + k0 + ch * 8] = v;
            else
                *(s16x8*)&Wto[(size_t)(n0 + rn) * 1024 + k0 + ch * 8] = v;
        }
    } else {
        int gt = (bid - 3072) * 256 + tid;
        for (int i = gt; i < 144 * 64; i += 256 * 8) {
            int r = i >> 6, d = i & 63;
            relkb[i] = (r < 129) ? f2bf(relk[r * 64 + d]) : (short)0;
        }
        for (int i = gt; i < 64 * 128; i += 256 * 8) {
            int d = i >> 7, r = i & 127;
            relvT[i] = f2bf(relv[r * 64 + d]);
        }
        for (int i = gt; i < 4096; i += 256 * 8)
            maskPb[i] = f2bf(mask[i] * -1e9f);
    }
}

// ---------------------------------------------------------------------------
// Fused QKV GEMM (unchanged)
// ---------------------------------------------------------------------------
__global__ __launch_bounds__(256, 4)
void gemm_qkv(const short* __restrict__ Ab, const short* __restrict__ Wt,
              const float* __restrict__ bq, const float* __restrict__ bk,
              const float* __restrict__ bv,
              short* __restrict__ Qb, short* __restrict__ Kb, short* __restrict__ Vtb)
{
    __shared__ __align__(16) short As[128 * 64];
    __shared__ __align__(16) short Bs[128 * 64];
    const int tid = threadIdx.x;
    const int w = tid >> 6, lane = tid & 63;
    const int lo16 = lane & 15, hi = lane >> 4;
    const int pb = blockIdx.x;
    const int wg = (pb & 7) * 96 + (pb >> 3);
    const int n0g = (wg % 24) * 128;
    const int m0 = (wg / 24) * 128;
    const int wr = w >> 1, wc = w & 1;

    f32x4 acc[4][4] = {};

    for (int t = 0; t < 16; ++t) {
        const int k0 = t * 64;
        __syncthreads();
#pragma unroll
        for (int i = 0; i < 4; ++i) {
            int o = i * 4096 + tid * 16;
            int row = o >> 7;
            int cb = o & 127;
            int sc = cb ^ ((row & 7) << 4);
            async_copy16((char*)As + o, Ab + (size_t)(m0 + row) * 1024 + k0 + (sc >> 1));
            async_copy16((char*)Bs + o, Wt + (size_t)(n0g + row) * 1024 + k0 + (sc >> 1));
        }
        __syncthreads();
#pragma unroll
        for (int ks = 0; ks < 2; ++ks) {
            s16x8 aF[4], bF[4];
#pragma unroll
            for (int mi = 0; mi < 4; ++mi) {
                int row = wr * 64 + mi * 16 + lo16;
                int cb = ks * 64 + hi * 16;
                aF[mi] = *(const s16x8*)((const char*)As + row * 128 + (cb ^ ((row & 7) << 4)));
            }
#pragma unroll
            for (int ni = 0; ni < 4; ++ni) {
                int row = wc * 64 + ni * 16 + lo16;
                int cb = ks * 64 + hi * 16;
                bF[ni] = *(const s16x8*)((const char*)Bs + row * 128 + (cb ^ ((row & 7) << 4)));
            }
#pragma unroll
            for (int mi = 0; mi < 4; ++mi)
#pragma unroll
                for (int ni = 0; ni < 4; ++ni)
                    acc[mi][ni] = MFMA(aF[mi], bF[ni], acc[mi][ni]);
        }
    }

    const int seg = n0g >> 10;
    const int nn = n0g & 1023;
    const float* bias = seg == 0 ? bq : seg == 1 ? bk : bv;
    float bv4[4];
#pragma unroll
    for (int ni = 0; ni < 4; ++ni) bv4[ni] = bias[nn + wc * 64 + ni * 16 + lo16];

    if (seg == 2) {
#pragma unroll
        for (int mi = 0; mi < 4; ++mi)
#pragma unroll
            for (int ni = 0; ni < 4; ++ni) {
                int nl = nn + wc * 64 + ni * 16 + lo16;
                int hh = nl >> 6, d = nl & 63;
                int mbase = m0 + wr * 64 + mi * 16 + hi * 4;
                int bb = mbase >> 10, l0 = mbase & 1023;
                int j0 = l0 & 31;
                int col = (l0 >> 5) * 32 + (((j0 >> 4) & 1) << 2) + (((j0 >> 2) & 3) << 3);
                s16x4 pk = { f2bf(acc[mi][ni][0] + bv4[ni]),
                             f2bf(acc[mi][ni][1] + bv4[ni]),
                             f2bf(acc[mi][ni][2] + bv4[ni]),
                             f2bf(acc[mi][ni][3] + bv4[ni]) };
                *(s16x4*)&Vtb[((size_t)(bb * 16 + hh) * 64 + d) * 1024 + col] = pk;
            }
    } else {
        short* out = seg == 0 ? Qb : Kb;
#pragma unroll
        for (int mi = 0; mi < 4; ++mi)
#pragma unroll
            for (int ni = 0; ni < 4; ++ni) {
                int nl = nn + wc * 64 + ni * 16 + lo16;
                int hh = nl >> 6, d = nl & 63;
#pragma unroll
                for (int r = 0; r < 4; ++r) {
                    int m = m0 + wr * 64 + mi * 16 + hi * 4 + r;
                    int bb = m >> 10, l = m & 1023;
                    out[(((size_t)bb * 16 + hh) * 1024 + l) * 64 + d] = f2bf(acc[mi][ni][r] + bv4[ni]);
                }
            }
    }
}

// ---------------------------------------------------------------------------
// Flash attention v12: v11b + bank-conflict fixes.
// (1) sQrel/sBand element index XOR'd with qsw=(lo16&7)<<4 (256B-stride rows
//     were bank-aligned -> 16-way on gather/scatter; now <=4-way).
// (2) V LDS chunk placement XOR'd with (d>>1)&3 (8-way -> 2-way on vr reads).
// Same sync protocol, same 40960B LDS, 4 blocks/CU.
// ---------------------------------------------------------------------------
__global__ __launch_bounds__(256, 4)
void attn_mfma(const short* __restrict__ Qb, const short* __restrict__ Kb,
               const short* __restrict__ Vtb, const short* __restrict__ relkb,
               const short* __restrict__ relvTb, const float* __restrict__ relv_f32,
               const short* __restrict__ maskPb, short* __restrict__ CTXb)
{
    __shared__ __align__(16) short sK[32 * 64];        // 4096B, swizzled chunks
    __shared__ __align__(16) short sV[64 * 32];        // 4096B, interleaved + chunk-swizzled
    __shared__ __align__(16) short sQrel[4][16][128];  // 16384B, element idx ^ qsw
    __shared__ __align__(16) short sBand[4][16][128];  // 16384B, element idx ^ qsw
    // total = 40960B exactly -> 4 blocks/CU

    const int tid = threadIdx.x;
    const int w = tid >> 6, lane = tid & 63;
    const int lo16 = lane & 15, hi = lane >> 4;
    const int qsw = (lo16 & 7) << 4;         // bank swizzle for sQrel/sBand
    const int vm = (lo16 >> 1) & 3;          // V chunk swizzle (same for all df)

    const int p = blockIdx.x;
    const int bid = (p & 7) * 128 + (p >> 3);
    const int bh = bid >> 4;
    const int qt = bid & 15;
    const int b = bh >> 4, h = bh & 15;
    const int q0 = qt * 64 + w * 16;
    const int q_abs = q0 + lo16;

    const short* Kbase = Kb + (size_t)bh * 65536;
    const short* Vtbase = Vtb + (size_t)bh * 65536;
    const short* mbase = maskPb + b * 1024;

    const int skr = tid >> 3, skc = tid & 7;             // K: row 0..31, chunk 0..7
    const int svd = tid >> 2, svc = tid & 3;             // V: row d 0..63, chunk 0..3
    const short* ksrc = Kbase + (size_t)skr * 64 + ((skc ^ (skr & 7)) << 3);
    const short* vsrc = Vtbase + (size_t)svd * 1024 + ((svc ^ ((svd >> 1) & 3)) << 3);

    // stage chunk 0
    async_copy16((char*)&sK[0] + tid * 16, ksrc);
    async_copy16((char*)&sV[0] + tid * 16, vsrc);

    const short* qptr = Qb + ((size_t)bh * 1024 + q_abs) * 64 + hi * 8;
    const s16x8 qB0 = *(const s16x8*)qptr;
    const s16x8 qB1 = *(const s16x8*)(qptr + 32);

    // sBand zero (per-wave region; swizzle is a permutation so full clear ok)
    {
        u32* bz = (u32*)&sBand[w][0][0];
#pragma unroll
        for (int i = 0; i < 16; ++i) bz[lane + i * 64] = 0u;
    }

    // Qrel: rf 0..7 -> sQrel[w][q][(0..127)^qsw]; rf=8 kept in regs
    f32x4 dq8 = {0.f, 0.f, 0.f, 0.f};
#pragma unroll
    for (int rf = 0; rf < 9; ++rf) {
        const short* rp = relkb + (size_t)(rf * 16 + lo16) * 64 + hi * 8;
        s16x8 rA0 = *(const s16x8*)rp;
        s16x8 rA1 = *(const s16x8*)(rp + 32);
        f32x4 dq = {0.f, 0.f, 0.f, 0.f};
        dq = MFMA(rA0, qB0, dq);
        dq = MFMA(rA1, qB1, dq);
        if (rf < 8) {
            s16x4 pk = { f2bf(dq[0]), f2bf(dq[1]), f2bf(dq[2]), f2bf(dq[3]) };
            *(s16x4*)&sQrel[w][lo16][(rf * 16 + hi * 4) ^ qsw] = pk;
        } else {
            dq8 = dq;
        }
    }
    // Qrel[q][0] from LDS slot (valid forever); Qrel[q][128] via wave shuffle
    // from lane q (hi==0 holds it in dq8[0]); no cross-lane LDS hand-off.
    const float qrel_lo = bf2f(sQrel[w][lo16][0 ^ qsw]);
    const float qrel_hi = __shfl(bf2f(f2bf(dq8[0])), lo16);

    __syncthreads();   // drains chunk-0 staging; fences sBand/sQrel

    f32x4 ctx[4] = {};
    float lsum = 0.f, lov = 0.f, hiv = 0.f;
    const f32x4 z = {0.f, 0.f, 0.f, 0.f};
    const int km = lo16 & 7;

    for (int t = 0; t < 32; ++t) {
        const int kf = t * 32;
        // ---- phase A: chunk t LDS -> regs; mask from global (L1) ----
        s16x8 kr0 = *(const s16x8*)(sK + lo16 * 64 + ((hi ^ km) << 3));
        s16x8 kr1 = *(const s16x8*)(sK + lo16 * 64 + (((hi + 4) ^ km) << 3));
        s16x8 kr2 = *(const s16x8*)(sK + (lo16 + 16) * 64 + ((hi ^ km) << 3));
        s16x8 kr3 = *(const s16x8*)(sK + (lo16 + 16) * 64 + (((hi + 4) ^ km) << 3));
        s16x8 vr0 = *(const s16x8*)(sV + lo16 * 32 + ((hi ^ vm) << 3));
        s16x8 vr1 = *(const s16x8*)(sV + (16 + lo16) * 32 + ((hi ^ vm) << 3));
        s16x8 vr2 = *(const s16x8*)(sV + (32 + lo16) * 32 + ((hi ^ vm) << 3));
        s16x8 vr3 = *(const s16x8*)(sV + (48 + lo16) * 32 + ((hi ^ vm) << 3));
        s16x4 m0 = *(const s16x4*)&mbase[kf + hi * 4];
        s16x4 m1 = *(const s16x4*)&mbase[kf + 16 + hi * 4];
        __syncthreads();   // barrier 1: all waves done reading the buffer
        // ---- stage chunk t+1 into the same buffer (drains at barrier 2) ----
        const int kfn = ((t + 1) & 31) * 32;
        async_copy16((char*)&sK[0] + tid * 16, ksrc + (size_t)kfn * 64);
        async_copy16((char*)&sV[0] + tid * 16, vsrc + kfn);

        // ---- QK (4 MFMAs, 2 chains) ----
        __builtin_amdgcn_s_setprio(1);
        f32x4 s0 = MFMA(kr0, qB0, z);
        f32x4 s1 = MFMA(kr2, qB0, z);
        s0 = MFMA(kr1, qB1, s0);
        s1 = MFMA(kr3, qB1, s1);
        __builtin_amdgcn_s_setprio(0);

        // ---- softmax ----
        float pr[8];
        if (kf + 95 <= q0 || kf >= q0 + 79) {
            const float qc = (kf < q0) ? qrel_lo : qrel_hi;
            float bs = 0.f;
#pragma unroll
            for (int r = 0; r < 4; ++r) {
                pr[r]     = __expf(s0[r] + qc + bf2f(m0[r]));
                pr[4 + r] = __expf(s1[r] + qc + bf2f(m1[r]));
            }
#pragma unroll
            for (int r = 0; r < 8; ++r) bs += pr[r];
            lsum += bs;
            if (kf < q0) lov += bs; else hiv += bs;
        } else {
#pragma unroll
            for (int f = 0; f < 2; ++f)
#pragma unroll
                for (int r = 0; r < 4; ++r) {
                    int k_abs = kf + f * 16 + hi * 4 + r;
                    int dd = k_abs - q_abs;
                    dd = dd < -64 ? -64 : (dd > 64 ? 64 : dd);
                    int rel = dd + 64;
                    int relc = rel > 127 ? 127 : rel;
                    float qv = bf2f(sQrel[w][lo16][relc ^ qsw]);
                    if (rel == 128) qv = qrel_hi;
                    float sv = f ? s1[r] : s0[r];
                    float mv = bf2f(f ? m1[r] : m0[r]);
                    float pex = __expf(sv + qv + mv);
                    pr[f * 4 + r] = pex;
                    lsum += pex;
                    if (rel >= 1 && rel <= 127) sBand[w][lo16][rel ^ qsw] = f2bf(pex);
                    else if (rel == 0) lov += pex;
                    else hiv += pex;
                }
        }
        u32x2 w0 = { cvtpk(pr[0], pr[1]), cvtpk(pr[2], pr[3]) };
        u32x2 w1 = { cvtpk(pr[4], pr[5]), cvtpk(pr[6], pr[7]) };
        s16x4 pf0 = __builtin_bit_cast(s16x4, w0);
        s16x4 pf1 = __builtin_bit_cast(s16x4, w1);

        // ---- PV (8 MFMAs) ----
        s16x4 a0 = __builtin_shufflevector(vr0, vr0, 0, 1, 2, 3);
        s16x4 b0 = __builtin_shufflevector(vr0, vr0, 4, 5, 6, 7);
        s16x4 a1 = __builtin_shufflevector(vr1, vr1, 0, 1, 2, 3);
        s16x4 b1 = __builtin_shufflevector(vr1, vr1, 4, 5, 6, 7);
        s16x4 a2 = __builtin_shufflevector(vr2, vr2, 0, 1, 2, 3);
        s16x4 b2 = __builtin_shufflevector(vr2, vr2, 4, 5, 6, 7);
        s16x4 a3 = __builtin_shufflevector(vr3, vr3, 0, 1, 2, 3);
        s16x4 b3 = __builtin_shufflevector(vr3, vr3, 4, 5, 6, 7);
        __builtin_amdgcn_s_setprio(1);
        ctx[0] = MFMA16(a0, pf0, ctx[0]);
        ctx[1] = MFMA16(a1, pf0, ctx[1]);
        ctx[2] = MFMA16(a2, pf0, ctx[2]);
        ctx[3] = MFMA16(a3, pf0, ctx[3]);
        ctx[0] = MFMA16(b0, pf1, ctx[0]);
        ctx[1] = MFMA16(b1, pf1, ctx[1]);
        ctx[2] = MFMA16(b2, pf1, ctx[2]);
        ctx[3] = MFMA16(b3, pf1, ctx[3]);
        __builtin_amdgcn_s_setprio(0);

        __syncthreads();   // barrier 2: staging complete for all waves
    }

    // band rel_v contribution: ctx^T += relvT-frag x sBand-frag (unnormalized)
#pragma unroll
    for (int ks = 0; ks < 4; ++ks) {
        s16x8 bB = *(const s16x8*)&sBand[w][lo16][(ks * 32 + hi * 8) ^ qsw];
#pragma unroll
        for (int df = 0; df < 4; ++df) {
            s16x8 rA = *(const s16x8*)(relvTb + (size_t)(df * 16 + lo16) * 128 + ks * 32 + hi * 8);
            ctx[df] = MFMA(rA, bB, ctx[df]);
        }
    }

    // reduce per-q stats across the 4 hi-groups
    lsum += __shfl_xor(lsum, 16); lsum += __shfl_xor(lsum, 32);
    lov  += __shfl_xor(lov, 16);  lov  += __shfl_xor(lov, 32);
    hiv  += __shfl_xor(hiv, 16);  hiv  += __shfl_xor(hiv, 32);
    const float inv = 1.0f / lsum;

    // tails (clipped buckets 0 / 128) + normalize + store bf16 ctx
#pragma unroll
    for (int df = 0; df < 4; ++df) {
        s16x4 pk;
#pragma unroll
        for (int r = 0; r < 4; ++r) {
            int d = df * 16 + hi * 4 + r;
            float t = ctx[df][r] + lov * relv_f32[d] + hiv * relv_f32[128 * 64 + d];
            pk[r] = f2bf(t * inv);
        }
        *(s16x4*)(CTXb + ((size_t)(b * 1024) + q_abs) * 1024 + h * 64 + df * 16 + hi * 4) = pk;
    }
}

// ---------------------------------------------------------------------------
// Output GEMM (unchanged): 128x64 tile, 512 blocks, XCD-swizzled.
// ---------------------------------------------------------------------------
__global__ __launch_bounds__(256, 4)
void gemm_out(const short* __restrict__ Ab, const short* __restrict__ Wto,
              const float* __restrict__ bo, float* __restrict__ out)
{
    __shared__ __align__(16) short As[128 * 64];
    __shared__ __align__(16) short Bs[64 * 64];
    const int tid = threadIdx.x;
    const int w = tid >> 6, lane = tid & 63;
    const int lo16 = lane & 15, hi = lane >> 4;
    const int pb = blockIdx.x;
    const int wg = (pb & 7) * 64 + (pb >> 3);
    const int n0 = (wg & 15) * 64;
    const int m0 = (wg >> 4) * 128;
    const int wr = w;

    f32x4 acc[2][4] = {};

    for (int t = 0; t < 16; ++t) {
        const int k0 = t * 64;
        __syncthreads();
#pragma unroll
        for (int i = 0; i < 4; ++i) {
            int o = i * 4096 + tid * 16;
            int row = o >> 7;
            int cb = o & 127;
            int sc = cb ^ ((row & 7) << 4);
            async_copy16((char*)As + o, Ab + (size_t)(m0 + row) * 1024 + k0 + (sc >> 1));
        }
#pragma unroll
        for (int i = 0; i < 2; ++i) {
            int o = i * 4096 + tid * 16;
            int row = o >> 7;
            int cb = o & 127;
            int sc = cb ^ ((row & 7) << 4);
            async_copy16((char*)Bs + o, Wto + (size_t)(n0 + row) * 1024 + k0 + (sc >> 1));
        }
        __syncthreads();
#pragma unroll
        for (int ks = 0; ks < 2; ++ks) {
            s16x8 aF[2], bF[4];
#pragma unroll
            for (int mi = 0; mi < 2; ++mi) {
                int row = wr * 32 + mi * 16 + lo16;
                int cb = ks * 64 + hi * 16;
                aF[mi] = *(const s16x8*)((const char*)As + row * 128 + (cb ^ ((row & 7) << 4)));
            }
#pragma unroll
            for (int ni = 0; ni < 4; ++ni) {
                int row = ni * 16 + lo16;
                int cb = ks * 64 + hi * 16;
                bF[ni] = *(const s16x8*)((const char*)Bs + row * 128 + (cb ^ ((row & 7) << 4)));
            }
#pragma unroll
            for (int mi = 0; mi < 2; ++mi)
#pragma unroll
                for (int ni = 0; ni < 4; ++ni)
                    acc[mi][ni] = MFMA(aF[mi], bF[ni], acc[mi][ni]);
        }
    }

    float bv4[4];
#pragma unroll
    for (int ni = 0; ni < 4; ++ni) bv4[ni] = bo[n0 + ni * 16 + lo16];
#pragma unroll
    for (int mi = 0; mi < 2; ++mi)
#pragma unroll
        for (int ni = 0; ni < 4; ++ni)
#pragma unroll
            for (int r = 0; r < 4; ++r) {
                int m = m0 + wr * 32 + mi * 16 + hi * 4 + r;
                out[(size_t)m * 1024 + n0 + ni * 16 + lo16] = acc[mi][ni][r] + bv4[ni];
            }
}

// ---------------------------------------------------------------------------
extern "C" void kernel_launch(void* const* d_in, const int* in_sizes, int n_in,
                              void* d_out, int out_size, void* d_ws, size_t ws_size,
                              hipStream_t stream)
{
    (void)in_sizes; (void)n_in; (void)out_size; (void)ws_size;
    const float* x    = (const float*)d_in[0];
    const float* mask = (const float*)d_in[1];
    const float* wq   = (const float*)d_in[2];
    const float* bq   = (const float*)d_in[3];
    const float* wk   = (const float*)d_in[4];
    const float* bk   = (const float*)d_in[5];
    const float* wv   = (const float*)d_in[6];
    const float* bv   = (const float*)d_in[7];
    const float* wo   = (const float*)d_in[8];
    const float* bo   = (const float*)d_in[9];
    const float* relk = (const float*)d_in[10];
    const float* relv = (const float*)d_in[11];
    float* out = (float*)d_out;

    char* p = (char*)d_ws;
    short* xb     = (short*)p; p += (size_t)4096 * 1024 * 2;     // 8 MB
    short* Wtqkv  = (short*)p; p += (size_t)3072 * 1024 * 2;     // 6 MB
    short* Wto    = (short*)p; p += (size_t)1024 * 1024 * 2;     // 2 MB
    short* Qb     = (short*)p; p += (size_t)4096 * 1024 * 2;     // 8 MB
    short* Kb     = (short*)p; p += (size_t)4096 * 1024 * 2;     // 8 MB
    short* Vtb    = (short*)p; p += (size_t)4096 * 1024 * 2;     // 8 MB
    short* CTXb   = (short*)p; p += (size_t)4096 * 1024 * 2;     // 8 MB
    short* relkb  = (short*)p; p += (size_t)144 * 64 * 2;
    short* relvT  = (short*)p; p += (size_t)64 * 128 * 2;
    short* maskPb = (short*)p; p += (size_t)4096 * 2;

    prep_all  <<<3080, 256, 0, stream>>>(x, xb, wq, wk, wv, wo, Wtqkv, Wto,
                                         relk, relv, relkb, relvT, mask, maskPb);
    gemm_qkv  <<<768, 256, 0, stream>>>(xb, Wtqkv, bq, bk, bv, Qb, Kb, Vtb);
    attn_mfma <<<1024, 256, 0, stream>>>(Qb, Kb, Vtb, relkb, relvT, relv, maskPb, CTXb);
    gemm_out  <<<512, 256, 0, stream>>>(CTXb, Wto, bo, out);
}